// Round 14
// baseline (295.029 us; speedup 1.0000x reference)
//
#include <hip/hip_runtime.h>
#include <math.h>

#define EPS 1e-5f

typedef __attribute__((ext_vector_type(8))) short short8;
typedef __attribute__((ext_vector_type(4))) float f32x4;

namespace {

constexpr int Bn = 2, Sn = 2048, Cn = 768;
constexpr float INV_BS = 1.0f / 4096.0f;     // B*S
constexpr float INV_PAIR = 1.0f / 32768.0f;  // B*SP*SP
constexpr float LOG2E = 1.4426950408889634f;

__device__ __forceinline__ ushort f2bf(float f) {
  uint u = __float_as_uint(f);
  u = (u + 0x7fffu + ((u >> 16) & 1u)) >> 16;
  return (ushort)u;
}
__device__ __forceinline__ float bf2f(ushort u) {
  return __uint_as_float(((uint)u) << 16);
}
__device__ __forceinline__ uint cvt_pk_bf16(float lo, float hi) {
  uint r;
  asm("v_cvt_pk_bf16_f32 %0, %1, %2" : "=v"(r) : "v"(lo), "v"(hi));
  return r;
}
// async global->LDS, 16B per lane; LDS dest is wave-uniform base (+lane*16 by HW)
__device__ __forceinline__ void gl16(const ushort* g, ushort* l) {
  __builtin_amdgcn_global_load_lds(
      (const __attribute__((address_space(1))) unsigned int*)(unsigned long long)(size_t)g,
      (__attribute__((address_space(3))) unsigned int*)(unsigned int)(size_t)l, 16, 0, 0);
}

// swizzled LDS index helpers (ushort units; XOR swaps 16B slots within a row)
#define KSW(r, c) ((((r) * 128) + (c)) ^ (((r) & 7) * 8))
#define VTW(d, t) ((((d) * 64) + (t)) ^ (((d) & 7) * 8))
#define PSW2(w, q, c) ((w) * 2048 + ((((q) * 64) + (c)) ^ (((q) & 7) * 8)))

// ---- all six weight casts in one launch; dst regions contiguous: wq|wk|wv|wo|w1|w2 ----
__global__ void castall_k(const float* __restrict__ wq, const float* __restrict__ wk,
                          const float* __restrict__ wv, const float* __restrict__ wo,
                          const float* __restrict__ w1, const float* __restrict__ w2,
                          ushort* __restrict__ dst) {
  int u = blockIdx.x * 256 + threadIdx.x;  // unit = 8 floats; 589824 units total
  const float* src; int local;
  if (u < 98304)       { src = wq; local = u; }
  else if (u < 147456) { src = wk; local = u - 98304; }
  else if (u < 196608) { src = wv; local = u - 147456; }
  else if (u < 294912) { src = wo; local = u - 196608; }
  else if (u < 442368) { src = w1; local = u - 294912; }
  else                 { src = w2; local = u - 442368; }
  int i = local * 8;
  float4 a = *(const float4*)&src[i];
  float4 b = *(const float4*)&src[i + 4];
  union { short8 s8; ushort us[8]; } o;
  o.us[0] = f2bf(a.x); o.us[1] = f2bf(a.y); o.us[2] = f2bf(a.z); o.us[3] = f2bf(a.w);
  o.us[4] = f2bf(b.x); o.us[5] = f2bf(b.y); o.us[6] = f2bf(b.z); o.us[7] = f2bf(b.w);
  *(short8*)&dst[u * 8] = o.s8;
}

// ---- RoPE cos/sin table: tab[s][i] for i in [0,64) ----
__global__ void rope_tab_k(float2* __restrict__ tab) {
  int idx = blockIdx.x * 256 + threadIdx.x;  // 131072
  int s = idx >> 6, i = idx & 63;
  const float kGeo = logf(1985.0f) * (1.0f / 63.0f);
  float inv = 1.0f / ((float)i + expf((float)i * kGeo));
  float th = (float)s * inv;
  tab[idx] = make_float2(cosf(th), sinf(th));
}

// ---- rms_bn scale + bf16 cast ----
__global__ void scale_cast_k(const float* __restrict__ a, const float* __restrict__ sums,
                             const float* __restrict__ g, ushort* __restrict__ o) {
  int idx = blockIdx.x * 256 + threadIdx.x;
  int c0 = (idx % 96) * 8;
  int base = idx * 8;
  float4 v0 = *(const float4*)&a[base];
  float4 v1 = *(const float4*)&a[base + 4];
  union { short8 s8; ushort us[8]; } r;
  float vv[8] = {v0.x, v0.y, v0.z, v0.w, v1.x, v1.y, v1.z, v1.w};
#pragma unroll
  for (int j = 0; j < 8; ++j) {
    float sc = rsqrtf(sums[c0 + j] * INV_BS + EPS) * g[c0 + j];
    r.us[j] = f2bf(vv[j] * sc);
  }
  *(short8*)&o[base] = r.s8;
}

// ---- per-channel sum of squares, 128-ch (pair_x) ----
__global__ void pair_sumsq_k(const float* __restrict__ p, float* __restrict__ out) {
  int r0 = blockIdx.x * 128;
  float acc = 0.f;
  for (int r = 0; r < 128; ++r) {
    float v = p[(size_t)(r0 + r) * 128 + threadIdx.x];
    acc += v * v;
  }
  atomicAdd(&out[threadIdx.x], acc);
}

// ---- per-channel sum of squares, 768-ch ----
__global__ void ch_sumsq768_k(const float* __restrict__ a, float* __restrict__ out) {
  int r0 = blockIdx.x * 16;
  int c = threadIdx.x;
  float acc = 0.f;
  for (int r = 0; r < 16; ++r) {
    float v = a[(size_t)(r0 + r) * 768 + c];
    acc += v * v;
  }
  atomicAdd(&out[c], acc);
}

// ---- pair bias -> pb2, pre-scaled by 0.4*log2e; 256 blocks x 128 thd ----
__global__ void pair_bias_k(const float* __restrict__ p, const float* __restrict__ ps,
                            const float* __restrict__ g, const float* __restrict__ w,
                            float* __restrict__ pb2) {
  int idx = blockIdx.x * 128 + threadIdx.x;  // 32768 total
  const float* row = p + (size_t)idx * 128;
  float a0 = 0.f, a1 = 0.f;
  for (int c = 0; c < 128; ++c) {
    float sc = rsqrtf(ps[c] * INV_PAIR + EPS) * g[c];
    float v = row[c] * sc;
    float ge = 0.5f * v * (1.f + erff(v * 0.70710678118654752f));
    a0 += ge * w[c];
    a1 += ge * w[128 + c];
  }
  pb2[(size_t)idx * 2 + 0] = a0 * (0.4f * LOG2E);
  pb2[(size_t)idx * 2 + 1] = a1 * (0.4f * LOG2E);
}

// ---- bf16 NT MFMA GEMM, 128x128 tile: gload_lds staging, linear LDS + XOR swizzle ----
template <bool RELU, bool OUT_BF16>
__global__ __launch_bounds__(256) void gemm_bf16_k(
    const ushort* __restrict__ A, const ushort* __restrict__ B,
    void* __restrict__ Cv, int M, int N, int K,
    const float* __restrict__ bias) {
  __shared__ __align__(16) ushort As[128 * 64];
  __shared__ __align__(16) ushort Bs[128 * 64];
  const int m0 = blockIdx.y * 128, n0 = blockIdx.x * 128;
  const int tid = threadIdx.x;
  const int lane = tid & 63;
  const int wid = tid >> 6;
  const int l15 = lane & 15, l4 = lane >> 4;
  const int wm = (wid >> 1) * 64, wn = (wid & 1) * 64;
  const ushort* asrc[4]; const ushort* bsrc[4];
  ushort* adst[4]; ushort* bdst[4];
#pragma unroll
  for (int u = 0; u < 4; ++u) {
    int ci = u * 256 + tid;
    int r = ci >> 3, s = ci & 7, g = s ^ (r & 7);
    asrc[u] = A + (size_t)(m0 + r) * K + g * 8;
    bsrc[u] = B + (size_t)(n0 + r) * K + g * 8;
    adst[u] = &As[(u * 256 + wid * 64) * 8];  // wave-uniform base
    bdst[u] = &Bs[(u * 256 + wid * 64) * 8];
  }
  f32x4 acc[4][4];
#pragma unroll
  for (int i = 0; i < 4; ++i)
#pragma unroll
    for (int j = 0; j < 4; ++j) acc[i][j] = (f32x4){0.f, 0.f, 0.f, 0.f};
  for (int k0 = 0; k0 < K; k0 += 64) {
#pragma unroll
    for (int u = 0; u < 4; ++u) {
      gl16(asrc[u] + k0, adst[u]);
      gl16(bsrc[u] + k0, bdst[u]);
    }
    __syncthreads();
#pragma unroll
    for (int ks = 0; ks < 2; ++ks) {
      const int sw = ((ks * 4 + l4) ^ (l15 & 7)) * 8;
      short8 af[4], bf[4];
#pragma unroll
      for (int i = 0; i < 4; ++i) af[i] = *(const short8*)&As[(wm + i * 16 + l15) * 64 + sw];
#pragma unroll
      for (int j = 0; j < 4; ++j) bf[j] = *(const short8*)&Bs[(wn + j * 16 + l15) * 64 + sw];
#pragma unroll
      for (int i = 0; i < 4; ++i)
#pragma unroll
        for (int j = 0; j < 4; ++j)
          acc[i][j] = __builtin_amdgcn_mfma_f32_16x16x32_bf16(af[i], bf[j], acc[i][j], 0, 0, 0);
    }
    __syncthreads();
  }
  float* Cf = (float*)Cv;
  ushort* Cb = (ushort*)Cv;
#pragma unroll
  for (int j = 0; j < 4; ++j) {
    int col = n0 + wn + j * 16 + l15;
    float bv = bias ? bias[col] : 0.f;
#pragma unroll
    for (int i = 0; i < 4; ++i) {
      int row = m0 + wm + i * 16 + l4 * 4;
#pragma unroll
      for (int r = 0; r < 4; ++r) {
        float v = acc[i][j][r] + bv;
        if (RELU) v = fmaxf(v, 0.f);
        if (OUT_BF16) Cb[(size_t)(row + r) * N + col] = f2bf(v);
        else Cf[(size_t)(row + r) * N + col] = v;
      }
    }
  }
}

// ---- bf16 NT MFMA GEMM, 64x128 tile (skinny N: wo, w2); optional column-sumsq. ----
template <bool SUMSQ>
__global__ __launch_bounds__(256) void gemm64_bf16_k(
    const ushort* __restrict__ A, const ushort* __restrict__ B,
    float* __restrict__ Cf, int M, int N, int K,
    const float* __restrict__ bias, float* __restrict__ ssq) {
  __shared__ __align__(16) ushort As[64 * 64];
  __shared__ __align__(16) ushort Bs[128 * 64];
  const int m0 = blockIdx.y * 64, n0 = blockIdx.x * 128;
  const int tid = threadIdx.x;
  const int lane = tid & 63;
  const int wid = tid >> 6;
  const int l15 = lane & 15, l4 = lane >> 4;
  const int wn = wid * 32;
  const ushort* asrc[2]; ushort* adst[2];
  const ushort* bsrc[4]; ushort* bdst[4];
#pragma unroll
  for (int u = 0; u < 2; ++u) {
    int ci = u * 256 + tid;
    int r = ci >> 3, s = ci & 7, g = s ^ (r & 7);
    asrc[u] = A + (size_t)(m0 + r) * K + g * 8;
    adst[u] = &As[(u * 256 + wid * 64) * 8];
  }
#pragma unroll
  for (int u = 0; u < 4; ++u) {
    int ci = u * 256 + tid;
    int r = ci >> 3, s = ci & 7, g = s ^ (r & 7);
    bsrc[u] = B + (size_t)(n0 + r) * K + g * 8;
    bdst[u] = &Bs[(u * 256 + wid * 64) * 8];
  }
  f32x4 acc[4][2];
#pragma unroll
  for (int i = 0; i < 4; ++i)
#pragma unroll
    for (int j = 0; j < 2; ++j) acc[i][j] = (f32x4){0.f, 0.f, 0.f, 0.f};
  for (int k0 = 0; k0 < K; k0 += 64) {
#pragma unroll
    for (int u = 0; u < 2; ++u) gl16(asrc[u] + k0, adst[u]);
#pragma unroll
    for (int u = 0; u < 4; ++u) gl16(bsrc[u] + k0, bdst[u]);
    __syncthreads();
#pragma unroll
    for (int ks = 0; ks < 2; ++ks) {
      const int sw = ((ks * 4 + l4) ^ (l15 & 7)) * 8;
      short8 af[4], bf[2];
#pragma unroll
      for (int i = 0; i < 4; ++i) af[i] = *(const short8*)&As[(i * 16 + l15) * 64 + sw];
#pragma unroll
      for (int j = 0; j < 2; ++j) bf[j] = *(const short8*)&Bs[(wn + j * 16 + l15) * 64 + sw];
#pragma unroll
      for (int i = 0; i < 4; ++i)
#pragma unroll
        for (int j = 0; j < 2; ++j)
          acc[i][j] = __builtin_amdgcn_mfma_f32_16x16x32_bf16(af[i], bf[j], acc[i][j], 0, 0, 0);
    }
    __syncthreads();
  }
#pragma unroll
  for (int j = 0; j < 2; ++j) {
    int col = n0 + wn + j * 16 + l15;
    float bv = bias ? bias[col] : 0.f;
    float sq = 0.f;
#pragma unroll
    for (int i = 0; i < 4; ++i) {
      int row = m0 + i * 16 + l4 * 4;
#pragma unroll
      for (int r = 0; r < 4; ++r) {
        float v = acc[i][j][r] + bv;
        if (SUMSQ) sq += v * v;
        Cf[(size_t)(row + r) * N + col] = v;
      }
    }
    if (SUMSQ) {
      sq += __shfl_xor(sq, 16);
      sq += __shfl_xor(sq, 32);
      if (l4 == 0) atomicAdd(&ssq[col], sq);
    }
  }
}

// ---- per-head LayerNorm + RoPE (table-driven); 256 thd = 2 rows ----
__global__ __launch_bounds__(256) void ln_rope_k(
    const float* __restrict__ qkv, const float2* __restrict__ rtab,
    const float* __restrict__ qg, const float* __restrict__ qb,
    const float* __restrict__ kg, const float* __restrict__ kb,
    const float* __restrict__ vg, const float* __restrict__ vb,
    ushort* __restrict__ q_b, ushort* __restrict__ k_b, ushort* __restrict__ v_b) {
  const int half = threadIdx.x >> 7;
  const int tid = threadIdx.x & 127;
  const int bs = blockIdx.x * 2 + half;
  const int slot = blockIdx.y;
  const int s = bs & (Sn - 1);
  const int b = bs >> 11;
  const float* src; const float* g; const float* be; ushort* dst; bool dorope; bool isq = false;
  if (slot < 8) {
    src = qkv + (size_t)bs * 2048 + slot * 128;
    g = qg; be = qb;
    dst = q_b + ((size_t)(b * 8 + slot) * Sn + s) * 128;
    dorope = true; isq = true;
  } else if (slot < 12) {
    int h = slot - 8;
    src = qkv + (size_t)bs * 2048 + 1024 + h * 128;
    g = kg; be = kb;
    dst = k_b + ((size_t)(b * 4 + h) * Sn + s) * 128;
    dorope = true;
  } else {
    int h = slot - 12;
    src = qkv + (size_t)bs * 2048 + 1536 + h * 128;
    g = vg; be = vb;
    dst = v_b + ((size_t)(b * 4 + h) * Sn + s) * 128;
    dorope = false;
  }
  __shared__ float sh[2][128];
  __shared__ float red[2][4];
  float v = src[tid];
  float sum = v;
#pragma unroll
  for (int o = 32; o >= 1; o >>= 1) sum += __shfl_xor(sum, o);
  if ((tid & 63) == 0) red[half][tid >> 6] = sum;
  __syncthreads();
  float mean = (red[half][0] + red[half][1]) * (1.f / 128.f);
  float d = v - mean;
  float s2 = d * d;
#pragma unroll
  for (int o = 32; o >= 1; o >>= 1) s2 += __shfl_xor(s2, o);
  if ((tid & 63) == 0) red[half][2 + (tid >> 6)] = s2;
  __syncthreads();
  float var = (red[half][2] + red[half][3]) * (1.f / 128.f);
  float val = d * rsqrtf(var + EPS) * g[tid] + be[tid];
  if (dorope) {
    sh[half][tid] = val;
    __syncthreads();
    float2 cssn = rtab[(s << 6) | (tid >> 1)];
    float rot = (tid & 1) ? sh[half][tid - 1] : -sh[half][tid + 1];
    val = val * cssn.x + rot * cssn.y;
  }
  if (isq) val *= 0.035355339059327376f * LOG2E;  // 0.4/sqrt(128)*log2e fold
  dst[tid] = f2bf(val);
}

// ---- transpose V: [hv][2048][128] bf16 -> [hv][128][2048] bf16 ----
__global__ __launch_bounds__(256) void vtrans_k(const ushort* __restrict__ vb,
                                                ushort* __restrict__ vtt) {
  __shared__ __align__(16) ushort T[64][136];
  const int hv = blockIdx.y, s0 = blockIdx.x * 64;
  const int tid = threadIdx.x;
  const ushort* src = vb + ((size_t)hv * Sn + s0) * 128;
#pragma unroll
  for (int u = 0; u < 4; ++u) {
    int fi = u * 256 + tid;
    int r = fi >> 4, c = (fi & 15) * 8;
    *(float4*)&T[r][c] = *(const float4*)&src[(size_t)r * 128 + c];
  }
  __syncthreads();
  ushort* dst = vtt + (size_t)hv * 128 * Sn + s0;
#pragma unroll
  for (int u = 0; u < 4; ++u) {
    int fi = u * 256 + tid;
    int d = fi >> 3, t8 = (fi & 7) * 8;
    union { float4 f4; ushort us[8]; } o;
#pragma unroll
    for (int j = 0; j < 8; ++j) o.us[j] = T[t8 + j][d];
    *(float4*)&dst[(size_t)d * Sn + t8] = o.f4;
  }
}

// ---- flash v11: 32KB LDS (P aliased into Ks; extra barrier after QK^T),
//      4 blocks/CU (128KB budget), even split-KV(4) = 1024 blocks packed round. ----
__global__ __launch_bounds__(256, 2) void flash_v11_k(
    const ushort* __restrict__ qb, const ushort* __restrict__ kb,
    const ushort* __restrict__ vtt, const float* __restrict__ pb2,
    ushort* __restrict__ part_y, float* __restrict__ part_l) {
  __shared__ __align__(16) ushort Ks[64 * 128];    // K tile; after QK^T holds P (16KB)
  __shared__ __align__(16) ushort Vt[128 * 64];    // [d][t] swizzled, 16KB
  const int s0 = blockIdx.x * 128;
  const int bh = blockIdx.y;
  const int half = blockIdx.z;
  const int b = bh >> 3, h = bh & 7;
  const int kv = h & 3, grp = h >> 2;
  const int tid = threadIdx.x;
  const int wid = tid >> 6, lane = tid & 63;
  const int l15 = lane & 15, l4 = lane >> 4;
  const ushort* kbase = kb + (size_t)(b * 4 + kv) * Sn * 128;
  const ushort* vbase = vtt + (size_t)(b * 4 + kv) * 128 * Sn;
  const int qr0 = s0 + wid * 32;
  short8 qf[2][4];
#pragma unroll
  for (int rg = 0; rg < 2; ++rg)
#pragma unroll
    for (int kc = 0; kc < 4; ++kc)
      qf[rg][kc] = *(const short8*)&qb[((size_t)bh * Sn + qr0 + rg * 16 + l15) * 128 + kc * 32 + l4 * 8];
  // staging geometry (pre-swizzled global source, linear LDS dest)
  const ushort* ksrc[4]; const ushort* vsrc[4];
  ushort* kdst[4]; ushort* vdst[4];
#pragma unroll
  for (int u = 0; u < 4; ++u) {
    int ci = u * 256 + tid;
    int kr = ci >> 4, kg = (ci & 15) ^ (kr & 7);
    ksrc[u] = kbase + (size_t)kr * 128 + kg * 8;
    kdst[u] = &Ks[(u * 256 + wid * 64) * 8];
    int vd = ci >> 3, vg = (ci & 7) ^ (vd & 7);
    vsrc[u] = vbase + (size_t)vd * Sn + vg * 8;
    vdst[u] = &Vt[(u * 256 + wid * 64) * 8];
  }
  f32x4 y[2][8];
#pragma unroll
  for (int rg = 0; rg < 2; ++rg)
#pragma unroll
    for (int i = 0; i < 8; ++i) y[rg][i] = (f32x4){0.f, 0.f, 0.f, 0.f};
  float lsum[2] = {0.f, 0.f};  // q = l15 uniform per lane (S^T layout)
  const float C2 = -10.f * LOG2E;
  const int tbeg = half * 512;
  for (int t0 = tbeg; t0 < tbeg + 512; t0 += 64) {
    __syncthreads();  // prev tile's P/V readers done before restaging
#pragma unroll
    for (int u = 0; u < 4; ++u) {
      gl16(ksrc[u] + (size_t)t0 * 128, kdst[u]);
      gl16(vsrc[u] + t0, vdst[u]);
    }
    __syncthreads();  // vmcnt drained by compiler before barrier
    // --- swapped QK^T: K frag read ONCE, used for both row-groups ---
    f32x4 acc[2][4];
#pragma unroll
    for (int rg = 0; rg < 2; ++rg)
#pragma unroll
      for (int nb = 0; nb < 4; ++nb) acc[rg][nb] = (f32x4){0.f, 0.f, 0.f, 0.f};
    __builtin_amdgcn_s_setprio(1);
#pragma unroll
    for (int kc = 0; kc < 4; ++kc)
#pragma unroll
      for (int nb = 0; nb < 4; ++nb) {
        short8 kf = *(const short8*)&Ks[KSW(nb * 16 + l15, kc * 32 + l4 * 8)];
        acc[0][nb] = __builtin_amdgcn_mfma_f32_16x16x32_bf16(kf, qf[0][kc], acc[0][nb], 0, 0, 0);
        acc[1][nb] = __builtin_amdgcn_mfma_f32_16x16x32_bf16(kf, qf[1][kc], acc[1][nb], 0, 0, 0);
      }
    __builtin_amdgcn_s_setprio(0);
    __syncthreads();  // all waves done reading K before P overwrites Ks
    // --- softcap + fixed-shift softmax (base-2); cvt_pk pack; P -> Ks region ---
#pragma unroll
    for (int rg = 0; rg < 2; ++rg)
#pragma unroll
      for (int nb = 0; nb < 4; ++nb) {
        float bias = pb2[(((size_t)b * 128 + (s0 >> 4) + wid * 2 + rg) * 128 + (t0 >> 4) + nb) * 2 + grp];
        float p[4];
#pragma unroll
        for (int r = 0; r < 4; ++r) {
          float e = exp2f(acc[rg][nb][r] + bias);
          p[r] = exp2f(C2 * __builtin_amdgcn_rcpf(e + 1.f));
        }
        lsum[rg] += (p[0] + p[1]) + (p[2] + p[3]);
        uint2 pk;
        pk.x = cvt_pk_bf16(p[0], p[1]);
        pk.y = cvt_pk_bf16(p[2], p[3]);
        *(uint2*)&Ks[PSW2(wid, rg * 16 + l15, nb * 16 + l4 * 4)] = pk;
      }
    // --- PV: V frag read ONCE, used for both row-groups; P region per-wave private ---
    __builtin_amdgcn_s_setprio(1);
#pragma unroll
    for (int ks = 0; ks < 2; ++ks) {
      short8 pa0 = *(const short8*)&Ks[PSW2(wid, l15, ks * 32 + l4 * 8)];
      short8 pa1 = *(const short8*)&Ks[PSW2(wid, 16 + l15, ks * 32 + l4 * 8)];
#pragma unroll
      for (int nbd = 0; nbd < 8; ++nbd) {
        short8 vf = *(const short8*)&Vt[VTW(nbd * 16 + l15, ks * 32 + l4 * 8)];
        y[0][nbd] = __builtin_amdgcn_mfma_f32_16x16x32_bf16(pa0, vf, y[0][nbd], 0, 0, 0);
        y[1][nbd] = __builtin_amdgcn_mfma_f32_16x16x32_bf16(pa1, vf, y[1][nbd], 0, 0, 0);
      }
    }
    __builtin_amdgcn_s_setprio(0);
  }
  // --- partial row sums + unnormalized y out ---
#pragma unroll
  for (int rg = 0; rg < 2; ++rg) {
    float ls = lsum[rg];
    ls += __shfl_xor(ls, 16);
    ls += __shfl_xor(ls, 32);
    if (l4 == 0) part_l[(size_t)(half * 16 + bh) * Sn + qr0 + rg * 16 + l15] = ls;
    ushort* pybase = part_y + ((size_t)(half * 16 + bh) * Sn + qr0 + rg * 16) * 128;
#pragma unroll
    for (int nbd = 0; nbd < 8; ++nbd)
#pragma unroll
      for (int r = 0; r < 4; ++r)
        pybase[(size_t)(l4 * 4 + r) * 128 + nbd * 16 + l15] = f2bf(y[rg][nbd][r]);
  }
}

// ---- combine: attn = (y0+y1+y2+y3) / (l0+l1+l2+l3), bf16 ----
__global__ void combine_k(const ushort* __restrict__ part_y, const float* __restrict__ part_l,
                          ushort* __restrict__ attn_b) {
  int t = blockIdx.x * 256 + threadIdx.x;  // 524288 threads, 8 d each
  int row = t >> 4;                        // bh*2048 + s
  size_t o0 = (size_t)row * 128 + (t & 15) * 8;
  float acc[8] = {};
#pragma unroll
  for (int hf = 0; hf < 4; ++hf) {
    union { short8 s8; ushort us[8]; } u;
    u.s8 = *(const short8*)&part_y[o0 + (size_t)hf * 4194304];
#pragma unroll
    for (int j = 0; j < 8; ++j) acc[j] += bf2f(u.us[j]);
  }
  float rcp = 1.f / (part_l[row] + part_l[row + 32768] + part_l[row + 65536] + part_l[row + 98304]);
  union { short8 s8; ushort us[8]; } o;
#pragma unroll
  for (int j = 0; j < 8; ++j) o.us[j] = f2bf(acc[j] * rcp);
  *(short8*)&attn_b[o0] = o.s8;
}

// ---- out = base + delta*rsqrt(sums/4096+eps)*g ; optional out-sumsq accumulate ----
template <bool SUMSQ>
__global__ void add_scale_k(const float* __restrict__ base, const float* __restrict__ delta,
                            const float* __restrict__ sums, const float* __restrict__ g,
                            float* __restrict__ out, float* __restrict__ ssq) {
  const int c = threadIdx.x;
  const float sc = rsqrtf(sums[c] * INV_BS + EPS) * g[c];
  const int r0 = blockIdx.x * 16;
  float sq = 0.f;
  for (int r = 0; r < 16; ++r) {
    size_t idx = (size_t)(r0 + r) * 768 + c;
    float v = base[idx] + delta[idx] * sc;
    out[idx] = v;
    if (SUMSQ) sq += v * v;
  }
  if (SUMSQ) atomicAdd(&ssq[c], sq);
}

}  // namespace

extern "C" void kernel_launch(void* const* d_in, const int* in_sizes, int n_in,
                              void* d_out, int out_size, void* d_ws, size_t ws_size,
                              hipStream_t stream) {
  const float* x       = (const float*)d_in[0];
  const float* pair_x  = (const float*)d_in[1];
  const float* ab_bn_g = (const float*)d_in[2];
  const float* ab_fc_w = (const float*)d_in[3];
  const float* bn1_g   = (const float*)d_in[4];
  const float* wq      = (const float*)d_in[5];
  const float* wk      = (const float*)d_in[6];
  const float* wv      = (const float*)d_in[7];
  const float* qn_g    = (const float*)d_in[8];
  const float* qn_b    = (const float*)d_in[9];
  const float* kn_g    = (const float*)d_in[10];
  const float* kn_b    = (const float*)d_in[11];
  const float* vn_g    = (const float*)d_in[12];
  const float* vn_b    = (const float*)d_in[13];
  const float* wo      = (const float*)d_in[14];
  const float* bo      = (const float*)d_in[15];
  const float* bn2_g   = (const float*)d_in[16];
  const float* mbn1_g  = (const float*)d_in[17];
  const float* w1      = (const float*)d_in[18];
  const float* b1      = (const float*)d_in[19];
  const float* w2      = (const float*)d_in[20];
  const float* b2      = (const float*)d_in[21];
  const float* mbn2_g  = (const float*)d_in[22];
  float* out = (float*)d_out;
  float* ws = (float*)d_ws;

  // ws layout (f32 units), liveness-verified (round-12 proven offsets)
  float* ps    = ws + 0;
  float* xs    = ws + 256;
  float* es    = ws + 1024;
  float* x2s   = ws + 2048;
  float* fs    = ws + 3072;
  float* pb2   = ws + 4096;                   // 65,536
  ushort* wall_b = (ushort*)(ws + 69632);     // wq|wk|wv|wo|w1|w2 bf16 -> 2428928
  ushort* wo_b = (ushort*)(ws + 856064);
  ushort* w1_b = (ushort*)(ws + 1249280);
  ushort* w2_b = (ushort*)(ws + 1839104);
  ushort* xn_b = (ushort*)(ws + 2428928);     // 1,572,864 f (dead after qkv gemm)
  float* qkvtmp = ws + 4001792;               // 8,388,608 f (dead after ln_rope)
  ushort* q_b  = (ushort*)(ws + 12390400);    // 2,097,152 f (dead after flash)
  ushort* k_b  = (ushort*)(ws + 14487552);    // 1,048,576 f (dead after flash)
  ushort* v_b  = (ushort*)(ws + 15536128);    // 1,048,576 f (dead after vtrans)
  float2* rtab = (float2*)(ws + 16584704);    // 262,144 f (cos/sin table, live thru ln_rope)
  // overlays:
  ushort* v_tt = (ushort*)(ws + 2428928);     // 1,048,576 f over dead xn_b
  ushort* part_y = (ushort*)(ws + 3477504);   // 8,388,608 f over dead qkvtmp (4 x 4M shorts)
  float* part_l = ws + 11866112;              // 131,072 f over dead qkvtmp tail
  ushort* attn_b = (ushort*)(ws + 11997184);  // 2,097,152 f over dead qkvtmp/q_b (post-flash)
  float* proj  = ws + 3477504;                // 3,145,728 f over dead part_y (post-combine)
  float* x2    = ws + 6623232;                // 3,145,728 f over dead part_y
  ushort* x2n_b = (ushort*)(ws + 9768960);    // 1,572,864 f over dead part_y
  ushort* hbuf_b = (ushort*)(ws + 3477504);   // 3,145,728 f over dead proj (post add_scale)
  float* proj2 = ws + 11341824;               // 3,145,728 f over dead attn_b/q_b tail

  (void)hipMemsetAsync(ws, 0, 4096 * sizeof(float), stream);

  castall_k<<<2304, 256, 0, stream>>>(wq, wk, wv, wo, w1, w2, wall_b);
  rope_tab_k<<<512, 256, 0, stream>>>(rtab);

  pair_sumsq_k<<<256, 128, 0, stream>>>(pair_x, ps);
  pair_bias_k<<<256, 128, 0, stream>>>(pair_x, ps, ab_bn_g, ab_fc_w, pb2);
  ch_sumsq768_k<<<256, 768, 0, stream>>>(x, xs);
  scale_cast_k<<<1536, 256, 0, stream>>>(x, xs, bn1_g, xn_b);
  gemm_bf16_k<false, false><<<dim3(16, 32), 256, 0, stream>>>(xn_b, wall_b, qkvtmp, 4096, 2048, 768, nullptr);
  ln_rope_k<<<dim3(2048, 16), 256, 0, stream>>>(qkvtmp, rtab, qn_g, qn_b, kn_g, kn_b,
                                                vn_g, vn_b, q_b, k_b, v_b);
  vtrans_k<<<dim3(32, 8), 256, 0, stream>>>(v_b, v_tt);
  flash_v11_k<<<dim3(16, 16, 4), 256, 0, stream>>>(q_b, k_b, v_tt, pb2, part_y, part_l);
  combine_k<<<2048, 256, 0, stream>>>(part_y, part_l, attn_b);
  gemm64_bf16_k<true><<<dim3(6, 64), 256, 0, stream>>>(attn_b, wo_b, proj, 4096, 768, 1024, bo, es);
  add_scale_k<true><<<256, 768, 0, stream>>>(x, proj, es, bn2_g, x2, x2s);
  scale_cast_k<<<1536, 256, 0, stream>>>(x2, x2s, mbn1_g, x2n_b);
  gemm_bf16_k<true, true><<<dim3(12, 32), 256, 0, stream>>>(x2n_b, w1_b, hbuf_b, 4096, 1536, 768, b1);
  gemm64_bf16_k<true><<<dim3(6, 64), 256, 0, stream>>>(hbuf_b, w2_b, proj2, 4096, 768, 1536, b2, fs);
  add_scale_k<false><<<256, 768, 0, stream>>>(x2, proj2, fs, mbn2_g, out, nullptr);

  (void)hipMemcpyAsync(out + 3145728, pair_x, (size_t)4194304 * sizeof(float),
                       hipMemcpyDeviceToDevice, stream);
}

// Round 15
// 291.029 us; speedup vs baseline: 1.0137x; 1.0137x over previous
//
#include <hip/hip_runtime.h>
#include <math.h>

#define EPS 1e-5f

typedef __attribute__((ext_vector_type(8))) short short8;
typedef __attribute__((ext_vector_type(4))) float f32x4;

namespace {

constexpr int Bn = 2, Sn = 2048, Cn = 768;
constexpr float INV_BS = 1.0f / 4096.0f;     // B*S
constexpr float INV_PAIR = 1.0f / 32768.0f;  // B*SP*SP
constexpr float LOG2E = 1.4426950408889634f;

__device__ __forceinline__ ushort f2bf(float f) {
  uint u = __float_as_uint(f);
  u = (u + 0x7fffu + ((u >> 16) & 1u)) >> 16;
  return (ushort)u;
}
__device__ __forceinline__ float bf2f(ushort u) {
  return __uint_as_float(((uint)u) << 16);
}
__device__ __forceinline__ uint cvt_pk_bf16(float lo, float hi) {
  uint r;
  asm("v_cvt_pk_bf16_f32 %0, %1, %2" : "=v"(r) : "v"(lo), "v"(hi));
  return r;
}
// async global->LDS, 16B per lane; LDS dest is wave-uniform base (+lane*16 by HW)
__device__ __forceinline__ void gl16(const ushort* g, ushort* l) {
  __builtin_amdgcn_global_load_lds(
      (const __attribute__((address_space(1))) unsigned int*)(unsigned long long)(size_t)g,
      (__attribute__((address_space(3))) unsigned int*)(unsigned int)(size_t)l, 16, 0, 0);
}

// swizzled LDS index helpers (ushort units; XOR swaps 16B slots within a row)
#define KSW(r, c) ((((r) * 128) + (c)) ^ (((r) & 7) * 8))
#define VTW(d, t) ((((d) * 64) + (t)) ^ (((d) & 7) * 8))
#define PSW2(w, q, c) ((w) * 2048 + ((((q) * 64) + (c)) ^ (((q) & 7) * 8)))

// ---- all six weight casts in one launch; dst regions contiguous: wq|wk|wv|wo|w1|w2 ----
__global__ void castall_k(const float* __restrict__ wq, const float* __restrict__ wk,
                          const float* __restrict__ wv, const float* __restrict__ wo,
                          const float* __restrict__ w1, const float* __restrict__ w2,
                          ushort* __restrict__ dst) {
  int u = blockIdx.x * 256 + threadIdx.x;  // unit = 8 floats; 589824 units total
  const float* src; int local;
  if (u < 98304)       { src = wq; local = u; }
  else if (u < 147456) { src = wk; local = u - 98304; }
  else if (u < 196608) { src = wv; local = u - 147456; }
  else if (u < 294912) { src = wo; local = u - 196608; }
  else if (u < 442368) { src = w1; local = u - 294912; }
  else                 { src = w2; local = u - 442368; }
  int i = local * 8;
  float4 a = *(const float4*)&src[i];
  float4 b = *(const float4*)&src[i + 4];
  union { short8 s8; ushort us[8]; } o;
  o.us[0] = f2bf(a.x); o.us[1] = f2bf(a.y); o.us[2] = f2bf(a.z); o.us[3] = f2bf(a.w);
  o.us[4] = f2bf(b.x); o.us[5] = f2bf(b.y); o.us[6] = f2bf(b.z); o.us[7] = f2bf(b.w);
  *(short8*)&dst[u * 8] = o.s8;
}

// ---- RoPE cos/sin table: tab[s][i] for i in [0,64) ----
__global__ void rope_tab_k(float2* __restrict__ tab) {
  int idx = blockIdx.x * 256 + threadIdx.x;  // 131072
  int s = idx >> 6, i = idx & 63;
  const float kGeo = logf(1985.0f) * (1.0f / 63.0f);
  float inv = 1.0f / ((float)i + expf((float)i * kGeo));
  float th = (float)s * inv;
  tab[idx] = make_float2(cosf(th), sinf(th));
}

// ---- rms_bn scale + bf16 cast ----
__global__ void scale_cast_k(const float* __restrict__ a, const float* __restrict__ sums,
                             const float* __restrict__ g, ushort* __restrict__ o) {
  int idx = blockIdx.x * 256 + threadIdx.x;
  int c0 = (idx % 96) * 8;
  int base = idx * 8;
  float4 v0 = *(const float4*)&a[base];
  float4 v1 = *(const float4*)&a[base + 4];
  union { short8 s8; ushort us[8]; } r;
  float vv[8] = {v0.x, v0.y, v0.z, v0.w, v1.x, v1.y, v1.z, v1.w};
#pragma unroll
  for (int j = 0; j < 8; ++j) {
    float sc = rsqrtf(sums[c0 + j] * INV_BS + EPS) * g[c0 + j];
    r.us[j] = f2bf(vv[j] * sc);
  }
  *(short8*)&o[base] = r.s8;
}

// ---- per-channel sum of squares, 128-ch (pair_x) ----
__global__ void pair_sumsq_k(const float* __restrict__ p, float* __restrict__ out) {
  int r0 = blockIdx.x * 128;
  float acc = 0.f;
  for (int r = 0; r < 128; ++r) {
    float v = p[(size_t)(r0 + r) * 128 + threadIdx.x];
    acc += v * v;
  }
  atomicAdd(&out[threadIdx.x], acc);
}

// ---- per-channel sum of squares, 768-ch ----
__global__ void ch_sumsq768_k(const float* __restrict__ a, float* __restrict__ out) {
  int r0 = blockIdx.x * 16;
  int c = threadIdx.x;
  float acc = 0.f;
  for (int r = 0; r < 16; ++r) {
    float v = a[(size_t)(r0 + r) * 768 + c];
    acc += v * v;
  }
  atomicAdd(&out[c], acc);
}

// ---- pair bias -> pb2, pre-scaled by 0.4*log2e; 256 blocks x 128 thd ----
__global__ void pair_bias_k(const float* __restrict__ p, const float* __restrict__ ps,
                            const float* __restrict__ g, const float* __restrict__ w,
                            float* __restrict__ pb2) {
  int idx = blockIdx.x * 128 + threadIdx.x;  // 32768 total
  const float* row = p + (size_t)idx * 128;
  float a0 = 0.f, a1 = 0.f;
  for (int c = 0; c < 128; ++c) {
    float sc = rsqrtf(ps[c] * INV_PAIR + EPS) * g[c];
    float v = row[c] * sc;
    float ge = 0.5f * v * (1.f + erff(v * 0.70710678118654752f));
    a0 += ge * w[c];
    a1 += ge * w[128 + c];
  }
  pb2[(size_t)idx * 2 + 0] = a0 * (0.4f * LOG2E);
  pb2[(size_t)idx * 2 + 1] = a1 * (0.4f * LOG2E);
}

// ---- bf16 NT MFMA GEMM, 128x128 tile: gload_lds staging, linear LDS + XOR swizzle ----
template <bool RELU, bool OUT_BF16>
__global__ __launch_bounds__(256) void gemm_bf16_k(
    const ushort* __restrict__ A, const ushort* __restrict__ B,
    void* __restrict__ Cv, int M, int N, int K,
    const float* __restrict__ bias) {
  __shared__ __align__(16) ushort As[128 * 64];
  __shared__ __align__(16) ushort Bs[128 * 64];
  const int m0 = blockIdx.y * 128, n0 = blockIdx.x * 128;
  const int tid = threadIdx.x;
  const int lane = tid & 63;
  const int wid = tid >> 6;
  const int l15 = lane & 15, l4 = lane >> 4;
  const int wm = (wid >> 1) * 64, wn = (wid & 1) * 64;
  const ushort* asrc[4]; const ushort* bsrc[4];
  ushort* adst[4]; ushort* bdst[4];
#pragma unroll
  for (int u = 0; u < 4; ++u) {
    int ci = u * 256 + tid;
    int r = ci >> 3, s = ci & 7, g = s ^ (r & 7);
    asrc[u] = A + (size_t)(m0 + r) * K + g * 8;
    bsrc[u] = B + (size_t)(n0 + r) * K + g * 8;
    adst[u] = &As[(u * 256 + wid * 64) * 8];  // wave-uniform base
    bdst[u] = &Bs[(u * 256 + wid * 64) * 8];
  }
  f32x4 acc[4][4];
#pragma unroll
  for (int i = 0; i < 4; ++i)
#pragma unroll
    for (int j = 0; j < 4; ++j) acc[i][j] = (f32x4){0.f, 0.f, 0.f, 0.f};
  for (int k0 = 0; k0 < K; k0 += 64) {
#pragma unroll
    for (int u = 0; u < 4; ++u) {
      gl16(asrc[u] + k0, adst[u]);
      gl16(bsrc[u] + k0, bdst[u]);
    }
    __syncthreads();
#pragma unroll
    for (int ks = 0; ks < 2; ++ks) {
      const int sw = ((ks * 4 + l4) ^ (l15 & 7)) * 8;
      short8 af[4], bf[4];
#pragma unroll
      for (int i = 0; i < 4; ++i) af[i] = *(const short8*)&As[(wm + i * 16 + l15) * 64 + sw];
#pragma unroll
      for (int j = 0; j < 4; ++j) bf[j] = *(const short8*)&Bs[(wn + j * 16 + l15) * 64 + sw];
#pragma unroll
      for (int i = 0; i < 4; ++i)
#pragma unroll
        for (int j = 0; j < 4; ++j)
          acc[i][j] = __builtin_amdgcn_mfma_f32_16x16x32_bf16(af[i], bf[j], acc[i][j], 0, 0, 0);
    }
    __syncthreads();
  }
  float* Cf = (float*)Cv;
  ushort* Cb = (ushort*)Cv;
#pragma unroll
  for (int j = 0; j < 4; ++j) {
    int col = n0 + wn + j * 16 + l15;
    float bv = bias ? bias[col] : 0.f;
#pragma unroll
    for (int i = 0; i < 4; ++i) {
      int row = m0 + wm + i * 16 + l4 * 4;
#pragma unroll
      for (int r = 0; r < 4; ++r) {
        float v = acc[i][j][r] + bv;
        if (RELU) v = fmaxf(v, 0.f);
        if (OUT_BF16) Cb[(size_t)(row + r) * N + col] = f2bf(v);
        else Cf[(size_t)(row + r) * N + col] = v;
      }
    }
  }
}

// ---- bf16 NT MFMA GEMM, 64x128 tile (skinny N: wo, w2); optional column-sumsq. ----
template <bool SUMSQ>
__global__ __launch_bounds__(256) void gemm64_bf16_k(
    const ushort* __restrict__ A, const ushort* __restrict__ B,
    float* __restrict__ Cf, int M, int N, int K,
    const float* __restrict__ bias, float* __restrict__ ssq) {
  __shared__ __align__(16) ushort As[64 * 64];
  __shared__ __align__(16) ushort Bs[128 * 64];
  const int m0 = blockIdx.y * 64, n0 = blockIdx.x * 128;
  const int tid = threadIdx.x;
  const int lane = tid & 63;
  const int wid = tid >> 6;
  const int l15 = lane & 15, l4 = lane >> 4;
  const int wn = wid * 32;
  const ushort* asrc[2]; ushort* adst[2];
  const ushort* bsrc[4]; ushort* bdst[4];
#pragma unroll
  for (int u = 0; u < 2; ++u) {
    int ci = u * 256 + tid;
    int r = ci >> 3, s = ci & 7, g = s ^ (r & 7);
    asrc[u] = A + (size_t)(m0 + r) * K + g * 8;
    adst[u] = &As[(u * 256 + wid * 64) * 8];
  }
#pragma unroll
  for (int u = 0; u < 4; ++u) {
    int ci = u * 256 + tid;
    int r = ci >> 3, s = ci & 7, g = s ^ (r & 7);
    bsrc[u] = B + (size_t)(n0 + r) * K + g * 8;
    bdst[u] = &Bs[(u * 256 + wid * 64) * 8];
  }
  f32x4 acc[4][2];
#pragma unroll
  for (int i = 0; i < 4; ++i)
#pragma unroll
    for (int j = 0; j < 2; ++j) acc[i][j] = (f32x4){0.f, 0.f, 0.f, 0.f};
  for (int k0 = 0; k0 < K; k0 += 64) {
#pragma unroll
    for (int u = 0; u < 2; ++u) gl16(asrc[u] + k0, adst[u]);
#pragma unroll
    for (int u = 0; u < 4; ++u) gl16(bsrc[u] + k0, bdst[u]);
    __syncthreads();
#pragma unroll
    for (int ks = 0; ks < 2; ++ks) {
      const int sw = ((ks * 4 + l4) ^ (l15 & 7)) * 8;
      short8 af[4], bf[2];
#pragma unroll
      for (int i = 0; i < 4; ++i) af[i] = *(const short8*)&As[(i * 16 + l15) * 64 + sw];
#pragma unroll
      for (int j = 0; j < 2; ++j) bf[j] = *(const short8*)&Bs[(wn + j * 16 + l15) * 64 + sw];
#pragma unroll
      for (int i = 0; i < 4; ++i)
#pragma unroll
        for (int j = 0; j < 2; ++j)
          acc[i][j] = __builtin_amdgcn_mfma_f32_16x16x32_bf16(af[i], bf[j], acc[i][j], 0, 0, 0);
    }
    __syncthreads();
  }
#pragma unroll
  for (int j = 0; j < 2; ++j) {
    int col = n0 + wn + j * 16 + l15;
    float bv = bias ? bias[col] : 0.f;
    float sq = 0.f;
#pragma unroll
    for (int i = 0; i < 4; ++i) {
      int row = m0 + i * 16 + l4 * 4;
#pragma unroll
      for (int r = 0; r < 4; ++r) {
        float v = acc[i][j][r] + bv;
        if (SUMSQ) sq += v * v;
        Cf[(size_t)(row + r) * N + col] = v;
      }
    }
    if (SUMSQ) {
      sq += __shfl_xor(sq, 16);
      sq += __shfl_xor(sq, 32);
      if (l4 == 0) atomicAdd(&ssq[col], sq);
    }
  }
}

// ---- per-head LayerNorm + RoPE (table-driven); 256 thd = 2 rows ----
__global__ __launch_bounds__(256) void ln_rope_k(
    const float* __restrict__ qkv, const float2* __restrict__ rtab,
    const float* __restrict__ qg, const float* __restrict__ qb,
    const float* __restrict__ kg, const float* __restrict__ kb,
    const float* __restrict__ vg, const float* __restrict__ vb,
    ushort* __restrict__ q_b, ushort* __restrict__ k_b, ushort* __restrict__ v_b) {
  const int half = threadIdx.x >> 7;
  const int tid = threadIdx.x & 127;
  const int bs = blockIdx.x * 2 + half;
  const int slot = blockIdx.y;
  const int s = bs & (Sn - 1);
  const int b = bs >> 11;
  const float* src; const float* g; const float* be; ushort* dst; bool dorope; bool isq = false;
  if (slot < 8) {
    src = qkv + (size_t)bs * 2048 + slot * 128;
    g = qg; be = qb;
    dst = q_b + ((size_t)(b * 8 + slot) * Sn + s) * 128;
    dorope = true; isq = true;
  } else if (slot < 12) {
    int h = slot - 8;
    src = qkv + (size_t)bs * 2048 + 1024 + h * 128;
    g = kg; be = kb;
    dst = k_b + ((size_t)(b * 4 + h) * Sn + s) * 128;
    dorope = true;
  } else {
    int h = slot - 12;
    src = qkv + (size_t)bs * 2048 + 1536 + h * 128;
    g = vg; be = vb;
    dst = v_b + ((size_t)(b * 4 + h) * Sn + s) * 128;
    dorope = false;
  }
  __shared__ float sh[2][128];
  __shared__ float red[2][4];
  float v = src[tid];
  float sum = v;
#pragma unroll
  for (int o = 32; o >= 1; o >>= 1) sum += __shfl_xor(sum, o);
  if ((tid & 63) == 0) red[half][tid >> 6] = sum;
  __syncthreads();
  float mean = (red[half][0] + red[half][1]) * (1.f / 128.f);
  float d = v - mean;
  float s2 = d * d;
#pragma unroll
  for (int o = 32; o >= 1; o >>= 1) s2 += __shfl_xor(s2, o);
  if ((tid & 63) == 0) red[half][2 + (tid >> 6)] = s2;
  __syncthreads();
  float var = (red[half][2] + red[half][3]) * (1.f / 128.f);
  float val = d * rsqrtf(var + EPS) * g[tid] + be[tid];
  if (dorope) {
    sh[half][tid] = val;
    __syncthreads();
    float2 cssn = rtab[(s << 6) | (tid >> 1)];
    float rot = (tid & 1) ? sh[half][tid - 1] : -sh[half][tid + 1];
    val = val * cssn.x + rot * cssn.y;
  }
  if (isq) val *= 0.035355339059327376f * LOG2E;  // 0.4/sqrt(128)*log2e fold
  dst[tid] = f2bf(val);
}

// ---- transpose V: [hv][2048][128] bf16 -> [hv][128][2048] bf16 ----
__global__ __launch_bounds__(256) void vtrans_k(const ushort* __restrict__ vb,
                                                ushort* __restrict__ vtt) {
  __shared__ __align__(16) ushort T[64][136];
  const int hv = blockIdx.y, s0 = blockIdx.x * 64;
  const int tid = threadIdx.x;
  const ushort* src = vb + ((size_t)hv * Sn + s0) * 128;
#pragma unroll
  for (int u = 0; u < 4; ++u) {
    int fi = u * 256 + tid;
    int r = fi >> 4, c = (fi & 15) * 8;
    *(float4*)&T[r][c] = *(const float4*)&src[(size_t)r * 128 + c];
  }
  __syncthreads();
  ushort* dst = vtt + (size_t)hv * 128 * Sn + s0;
#pragma unroll
  for (int u = 0; u < 4; ++u) {
    int fi = u * 256 + tid;
    int d = fi >> 3, t8 = (fi & 7) * 8;
    union { float4 f4; ushort us[8]; } o;
#pragma unroll
    for (int j = 0; j < 8; ++j) o.us[j] = T[t8 + j][d];
    *(float4*)&dst[(size_t)d * Sn + t8] = o.f4;
  }
}

// ---- flash v12: double-buffered K/V (2-phase pipeline, 1 barrier/tile),
//      4 waves x 32 q-rows, split-KV(4); drain hidden under compute. ----
__global__ __launch_bounds__(256, 2) void flash_v12_k(
    const ushort* __restrict__ qb, const ushort* __restrict__ kb,
    const ushort* __restrict__ vtt, const float* __restrict__ pb2,
    ushort* __restrict__ part_y, float* __restrict__ part_l) {
  __shared__ __align__(16) ushort Ks[2 * 64 * 128];  // double-buffered K, 32KB
  __shared__ __align__(16) ushort Vt[2 * 128 * 64];  // double-buffered V^T, 32KB
  __shared__ __align__(16) ushort Ps[4 * 32 * 64];   // per-wave P, 16KB
  const int s0 = blockIdx.x * 128;
  const int bh = blockIdx.y;
  const int half = blockIdx.z;
  const int b = bh >> 3, h = bh & 7;
  const int kv = h & 3, grp = h >> 2;
  const int tid = threadIdx.x;
  const int wid = tid >> 6, lane = tid & 63;
  const int l15 = lane & 15, l4 = lane >> 4;
  const ushort* kbase = kb + (size_t)(b * 4 + kv) * Sn * 128;
  const ushort* vbase = vtt + (size_t)(b * 4 + kv) * 128 * Sn;
  const int qr0 = s0 + wid * 32;
  short8 qf[2][4];
#pragma unroll
  for (int rg = 0; rg < 2; ++rg)
#pragma unroll
    for (int kc = 0; kc < 4; ++kc)
      qf[rg][kc] = *(const short8*)&qb[((size_t)bh * Sn + qr0 + rg * 16 + l15) * 128 + kc * 32 + l4 * 8];
  // staging geometry (pre-swizzled global source, linear LDS dest)
  const ushort* ksrc[4]; const ushort* vsrc[4];
#pragma unroll
  for (int u = 0; u < 4; ++u) {
    int ci = u * 256 + tid;
    int kr = ci >> 4, kg = (ci & 15) ^ (kr & 7);
    ksrc[u] = kbase + (size_t)kr * 128 + kg * 8;
    int vd = ci >> 3, vg = (ci & 7) ^ (vd & 7);
    vsrc[u] = vbase + (size_t)vd * Sn + vg * 8;
  }
  f32x4 y[2][8];
#pragma unroll
  for (int rg = 0; rg < 2; ++rg)
#pragma unroll
    for (int i = 0; i < 8; ++i) y[rg][i] = (f32x4){0.f, 0.f, 0.f, 0.f};
  float lsum[2] = {0.f, 0.f};  // q = l15 uniform per lane (S^T layout)
  const float C2 = -10.f * LOG2E;
  const int tbeg = half * 512;
  // prologue: stage tile 0 into buf 0
#pragma unroll
  for (int u = 0; u < 4; ++u) {
    gl16(ksrc[u] + (size_t)tbeg * 128, &Ks[(u * 256 + wid * 64) * 8]);
    gl16(vsrc[u] + tbeg, &Vt[(u * 256 + wid * 64) * 8]);
  }
  __syncthreads();
  int cur = 0;
  for (int it = 0; it < 8; ++it) {
    const int t0 = tbeg + it * 64;
    // issue next tile's loads into buf^1 BEFORE compute; latency hides under it
    if (it < 7) {
      const int nb_off = (cur ^ 1) * 8192;
#pragma unroll
      for (int u = 0; u < 4; ++u) {
        gl16(ksrc[u] + (size_t)(t0 + 64) * 128, &Ks[nb_off + (u * 256 + wid * 64) * 8]);
        gl16(vsrc[u] + t0 + 64, &Vt[nb_off + (u * 256 + wid * 64) * 8]);
      }
    }
    const int cb = cur * 8192;
    // --- swapped QK^T: K frag read ONCE, used for both row-groups ---
    f32x4 acc[2][4];
#pragma unroll
    for (int rg = 0; rg < 2; ++rg)
#pragma unroll
      for (int nb = 0; nb < 4; ++nb) acc[rg][nb] = (f32x4){0.f, 0.f, 0.f, 0.f};
    __builtin_amdgcn_s_setprio(1);
#pragma unroll
    for (int kc = 0; kc < 4; ++kc)
#pragma unroll
      for (int nb = 0; nb < 4; ++nb) {
        short8 kf = *(const short8*)&Ks[cb + KSW(nb * 16 + l15, kc * 32 + l4 * 8)];
        acc[0][nb] = __builtin_amdgcn_mfma_f32_16x16x32_bf16(kf, qf[0][kc], acc[0][nb], 0, 0, 0);
        acc[1][nb] = __builtin_amdgcn_mfma_f32_16x16x32_bf16(kf, qf[1][kc], acc[1][nb], 0, 0, 0);
      }
    __builtin_amdgcn_s_setprio(0);
    // --- softcap + fixed-shift softmax (base-2); cvt_pk pack ---
#pragma unroll
    for (int rg = 0; rg < 2; ++rg)
#pragma unroll
      for (int nb = 0; nb < 4; ++nb) {
        float bias = pb2[(((size_t)b * 128 + (s0 >> 4) + wid * 2 + rg) * 128 + (t0 >> 4) + nb) * 2 + grp];
        float p[4];
#pragma unroll
        for (int r = 0; r < 4; ++r) {
          float e = exp2f(acc[rg][nb][r] + bias);
          p[r] = exp2f(C2 * __builtin_amdgcn_rcpf(e + 1.f));
        }
        lsum[rg] += (p[0] + p[1]) + (p[2] + p[3]);
        uint2 pk;
        pk.x = cvt_pk_bf16(p[0], p[1]);
        pk.y = cvt_pk_bf16(p[2], p[3]);
        *(uint2*)&Ps[PSW2(wid, rg * 16 + l15, nb * 16 + l4 * 4)] = pk;
      }
    // --- PV: V frag read ONCE, used for both row-groups ---
    __builtin_amdgcn_s_setprio(1);
#pragma unroll
    for (int ks = 0; ks < 2; ++ks) {
      short8 pa0 = *(const short8*)&Ps[PSW2(wid, l15, ks * 32 + l4 * 8)];
      short8 pa1 = *(const short8*)&Ps[PSW2(wid, 16 + l15, ks * 32 + l4 * 8)];
#pragma unroll
      for (int nbd = 0; nbd < 8; ++nbd) {
        short8 vf = *(const short8*)&Vt[cb + VTW(nbd * 16 + l15, ks * 32 + l4 * 8)];
        y[0][nbd] = __builtin_amdgcn_mfma_f32_16x16x32_bf16(pa0, vf, y[0][nbd], 0, 0, 0);
        y[1][nbd] = __builtin_amdgcn_mfma_f32_16x16x32_bf16(pa1, vf, y[1][nbd], 0, 0, 0);
      }
    }
    __builtin_amdgcn_s_setprio(0);
    __syncthreads();  // drains next-tile loads (issued pre-compute) + readers done
    cur ^= 1;
  }
  // --- partial row sums + unnormalized y out ---
#pragma unroll
  for (int rg = 0; rg < 2; ++rg) {
    float ls = lsum[rg];
    ls += __shfl_xor(ls, 16);
    ls += __shfl_xor(ls, 32);
    if (l4 == 0) part_l[(size_t)(half * 16 + bh) * Sn + qr0 + rg * 16 + l15] = ls;
    ushort* pybase = part_y + ((size_t)(half * 16 + bh) * Sn + qr0 + rg * 16) * 128;
#pragma unroll
    for (int nbd = 0; nbd < 8; ++nbd)
#pragma unroll
      for (int r = 0; r < 4; ++r)
        pybase[(size_t)(l4 * 4 + r) * 128 + nbd * 16 + l15] = f2bf(y[rg][nbd][r]);
  }
}

// ---- combine: attn = (y0+y1+y2+y3) / (l0+l1+l2+l3), bf16 ----
__global__ void combine_k(const ushort* __restrict__ part_y, const float* __restrict__ part_l,
                          ushort* __restrict__ attn_b) {
  int t = blockIdx.x * 256 + threadIdx.x;  // 524288 threads, 8 d each
  int row = t >> 4;                        // bh*2048 + s
  size_t o0 = (size_t)row * 128 + (t & 15) * 8;
  float acc[8] = {};
#pragma unroll
  for (int hf = 0; hf < 4; ++hf) {
    union { short8 s8; ushort us[8]; } u;
    u.s8 = *(const short8*)&part_y[o0 + (size_t)hf * 4194304];
#pragma unroll
    for (int j = 0; j < 8; ++j) acc[j] += bf2f(u.us[j]);
  }
  float rcp = 1.f / (part_l[row] + part_l[row + 32768] + part_l[row + 65536] + part_l[row + 98304]);
  union { short8 s8; ushort us[8]; } o;
#pragma unroll
  for (int j = 0; j < 8; ++j) o.us[j] = f2bf(acc[j] * rcp);
  *(short8*)&attn_b[o0] = o.s8;
}

// ---- out = base + delta*rsqrt(sums/4096+eps)*g ; optional out-sumsq accumulate ----
template <bool SUMSQ>
__global__ void add_scale_k(const float* __restrict__ base, const float* __restrict__ delta,
                            const float* __restrict__ sums, const float* __restrict__ g,
                            float* __restrict__ out, float* __restrict__ ssq) {
  const int c = threadIdx.x;
  const float sc = rsqrtf(sums[c] * INV_BS + EPS) * g[c];
  const int r0 = blockIdx.x * 16;
  float sq = 0.f;
  for (int r = 0; r < 16; ++r) {
    size_t idx = (size_t)(r0 + r) * 768 + c;
    float v = base[idx] + delta[idx] * sc;
    out[idx] = v;
    if (SUMSQ) sq += v * v;
  }
  if (SUMSQ) atomicAdd(&ssq[c], sq);
}

}  // namespace

extern "C" void kernel_launch(void* const* d_in, const int* in_sizes, int n_in,
                              void* d_out, int out_size, void* d_ws, size_t ws_size,
                              hipStream_t stream) {
  const float* x       = (const float*)d_in[0];
  const float* pair_x  = (const float*)d_in[1];
  const float* ab_bn_g = (const float*)d_in[2];
  const float* ab_fc_w = (const float*)d_in[3];
  const float* bn1_g   = (const float*)d_in[4];
  const float* wq      = (const float*)d_in[5];
  const float* wk      = (const float*)d_in[6];
  const float* wv      = (const float*)d_in[7];
  const float* qn_g    = (const float*)d_in[8];
  const float* qn_b    = (const float*)d_in[9];
  const float* kn_g    = (const float*)d_in[10];
  const float* kn_b    = (const float*)d_in[11];
  const float* vn_g    = (const float*)d_in[12];
  const float* vn_b    = (const float*)d_in[13];
  const float* wo      = (const float*)d_in[14];
  const float* bo      = (const float*)d_in[15];
  const float* bn2_g   = (const float*)d_in[16];
  const float* mbn1_g  = (const float*)d_in[17];
  const float* w1      = (const float*)d_in[18];
  const float* b1      = (const float*)d_in[19];
  const float* w2      = (const float*)d_in[20];
  const float* b2      = (const float*)d_in[21];
  const float* mbn2_g  = (const float*)d_in[22];
  float* out = (float*)d_out;
  float* ws = (float*)d_ws;

  // ws layout (f32 units), liveness-verified (round-12 proven offsets)
  float* ps    = ws + 0;
  float* xs    = ws + 256;
  float* es    = ws + 1024;
  float* x2s   = ws + 2048;
  float* fs    = ws + 3072;
  float* pb2   = ws + 4096;                   // 65,536
  ushort* wall_b = (ushort*)(ws + 69632);     // wq|wk|wv|wo|w1|w2 bf16 -> 2428928
  ushort* wo_b = (ushort*)(ws + 856064);
  ushort* w1_b = (ushort*)(ws + 1249280);
  ushort* w2_b = (ushort*)(ws + 1839104);
  ushort* xn_b = (ushort*)(ws + 2428928);     // 1,572,864 f (dead after qkv gemm)
  float* qkvtmp = ws + 4001792;               // 8,388,608 f (dead after ln_rope)
  ushort* q_b  = (ushort*)(ws + 12390400);    // 2,097,152 f (dead after flash)
  ushort* k_b  = (ushort*)(ws + 14487552);    // 1,048,576 f (dead after flash)
  ushort* v_b  = (ushort*)(ws + 15536128);    // 1,048,576 f (dead after vtrans)
  float2* rtab = (float2*)(ws + 16584704);    // 262,144 f (cos/sin table, live thru ln_rope)
  // overlays:
  ushort* v_tt = (ushort*)(ws + 2428928);     // 1,048,576 f over dead xn_b
  ushort* part_y = (ushort*)(ws + 3477504);   // 8,388,608 f over dead qkvtmp (4 x 4M shorts)
  float* part_l = ws + 11866112;              // 131,072 f over dead qkvtmp tail
  ushort* attn_b = (ushort*)(ws + 11997184);  // 2,097,152 f over dead qkvtmp/q_b (post-flash)
  float* proj  = ws + 3477504;                // 3,145,728 f over dead part_y (post-combine)
  float* x2    = ws + 6623232;                // 3,145,728 f over dead part_y
  ushort* x2n_b = (ushort*)(ws + 9768960);    // 1,572,864 f over dead part_y
  ushort* hbuf_b = (ushort*)(ws + 3477504);   // 3,145,728 f over dead proj (post add_scale)
  float* proj2 = ws + 11341824;               // 3,145,728 f over dead attn_b/q_b tail

  (void)hipMemsetAsync(ws, 0, 4096 * sizeof(float), stream);

  castall_k<<<2304, 256, 0, stream>>>(wq, wk, wv, wo, w1, w2, wall_b);
  rope_tab_k<<<512, 256, 0, stream>>>(rtab);

  pair_sumsq_k<<<256, 128, 0, stream>>>(pair_x, ps);
  pair_bias_k<<<256, 128, 0, stream>>>(pair_x, ps, ab_bn_g, ab_fc_w, pb2);
  ch_sumsq768_k<<<256, 768, 0, stream>>>(x, xs);
  scale_cast_k<<<1536, 256, 0, stream>>>(x, xs, bn1_g, xn_b);
  gemm_bf16_k<false, false><<<dim3(16, 32), 256, 0, stream>>>(xn_b, wall_b, qkvtmp, 4096, 2048, 768, nullptr);
  ln_rope_k<<<dim3(2048, 16), 256, 0, stream>>>(qkvtmp, rtab, qn_g, qn_b, kn_g, kn_b,
                                                vn_g, vn_b, q_b, k_b, v_b);
  vtrans_k<<<dim3(32, 8), 256, 0, stream>>>(v_b, v_tt);
  flash_v12_k<<<dim3(16, 16, 4), 256, 0, stream>>>(q_b, k_b, v_tt, pb2, part_y, part_l);
  combine_k<<<2048, 256, 0, stream>>>(part_y, part_l, attn_b);
  gemm64_bf16_k<true><<<dim3(6, 64), 256, 0, stream>>>(attn_b, wo_b, proj, 4096, 768, 1024, bo, es);
  add_scale_k<true><<<256, 768, 0, stream>>>(x, proj, es, bn2_g, x2, x2s);
  scale_cast_k<<<1536, 256, 0, stream>>>(x2, x2s, mbn1_g, x2n_b);
  gemm_bf16_k<true, true><<<dim3(12, 32), 256, 0, stream>>>(x2n_b, w1_b, hbuf_b, 4096, 1536, 768, b1);
  gemm64_bf16_k<true><<<dim3(6, 64), 256, 0, stream>>>(hbuf_b, w2_b, proj2, 4096, 768, 1536, b2, fs);
  add_scale_k<false><<<256, 768, 0, stream>>>(x2, proj2, fs, mbn2_g, out, nullptr);

  (void)hipMemcpyAsync(out + 3145728, pair_x, (size_t)4194304 * sizeof(float),
                       hipMemcpyDeviceToDevice, stream);
}

// Round 16
// 266.710 us; speedup vs baseline: 1.1062x; 1.0912x over previous
//
#include <hip/hip_runtime.h>
#include <math.h>

#define EPS 1e-5f

typedef __attribute__((ext_vector_type(8))) short short8;
typedef __attribute__((ext_vector_type(4))) float f32x4;

namespace {

constexpr int Bn = 2, Sn = 2048, Cn = 768;
constexpr float INV_BS = 1.0f / 4096.0f;     // B*S
constexpr float INV_PAIR = 1.0f / 32768.0f;  // B*SP*SP
constexpr float LOG2E = 1.4426950408889634f;

__device__ __forceinline__ ushort f2bf(float f) {
  uint u = __float_as_uint(f);
  u = (u + 0x7fffu + ((u >> 16) & 1u)) >> 16;
  return (ushort)u;
}
__device__ __forceinline__ float bf2f(ushort u) {
  return __uint_as_float(((uint)u) << 16);
}
__device__ __forceinline__ uint cvt_pk_bf16(float lo, float hi) {
  uint r;
  asm("v_cvt_pk_bf16_f32 %0, %1, %2" : "=v"(r) : "v"(lo), "v"(hi));
  return r;
}
// async global->LDS, 16B per lane; LDS dest is wave-uniform base (+lane*16 by HW)
__device__ __forceinline__ void gl16(const ushort* g, ushort* l) {
  __builtin_amdgcn_global_load_lds(
      (const __attribute__((address_space(1))) unsigned int*)(unsigned long long)(size_t)g,
      (__attribute__((address_space(3))) unsigned int*)(unsigned int)(size_t)l, 16, 0, 0);
}

// swizzled LDS index helpers (ushort units; XOR swaps 16B slots within a row)
#define KSW(r, c) ((((r) * 128) + (c)) ^ (((r) & 7) * 8))
#define VTW(d, t) ((((d) * 64) + (t)) ^ (((d) & 7) * 8))
#define PSW2(w, q, c) ((w) * 2048 + ((((q) * 64) + (c)) ^ (((q) & 7) * 8)))

// ---- all six weight casts in one launch; dst regions contiguous: wq|wk|wv|wo|w1|w2 ----
__global__ void castall_k(const float* __restrict__ wq, const float* __restrict__ wk,
                          const float* __restrict__ wv, const float* __restrict__ wo,
                          const float* __restrict__ w1, const float* __restrict__ w2,
                          ushort* __restrict__ dst) {
  int u = blockIdx.x * 256 + threadIdx.x;  // unit = 8 floats; 589824 units total
  const float* src; int local;
  if (u < 98304)       { src = wq; local = u; }
  else if (u < 147456) { src = wk; local = u - 98304; }
  else if (u < 196608) { src = wv; local = u - 147456; }
  else if (u < 294912) { src = wo; local = u - 196608; }
  else if (u < 442368) { src = w1; local = u - 294912; }
  else                 { src = w2; local = u - 442368; }
  int i = local * 8;
  float4 a = *(const float4*)&src[i];
  float4 b = *(const float4*)&src[i + 4];
  union { short8 s8; ushort us[8]; } o;
  o.us[0] = f2bf(a.x); o.us[1] = f2bf(a.y); o.us[2] = f2bf(a.z); o.us[3] = f2bf(a.w);
  o.us[4] = f2bf(b.x); o.us[5] = f2bf(b.y); o.us[6] = f2bf(b.z); o.us[7] = f2bf(b.w);
  *(short8*)&dst[u * 8] = o.s8;
}

// ---- RoPE cos/sin table: tab[s][i] for i in [0,64) ----
__global__ void rope_tab_k(float2* __restrict__ tab) {
  int idx = blockIdx.x * 256 + threadIdx.x;  // 131072
  int s = idx >> 6, i = idx & 63;
  const float kGeo = logf(1985.0f) * (1.0f / 63.0f);
  float inv = 1.0f / ((float)i + expf((float)i * kGeo));
  float th = (float)s * inv;
  tab[idx] = make_float2(cosf(th), sinf(th));
}

// ---- rms_bn scale + bf16 cast ----
__global__ void scale_cast_k(const float* __restrict__ a, const float* __restrict__ sums,
                             const float* __restrict__ g, ushort* __restrict__ o) {
  int idx = blockIdx.x * 256 + threadIdx.x;
  int c0 = (idx % 96) * 8;
  int base = idx * 8;
  float4 v0 = *(const float4*)&a[base];
  float4 v1 = *(const float4*)&a[base + 4];
  union { short8 s8; ushort us[8]; } r;
  float vv[8] = {v0.x, v0.y, v0.z, v0.w, v1.x, v1.y, v1.z, v1.w};
#pragma unroll
  for (int j = 0; j < 8; ++j) {
    float sc = rsqrtf(sums[c0 + j] * INV_BS + EPS) * g[c0 + j];
    r.us[j] = f2bf(vv[j] * sc);
  }
  *(short8*)&o[base] = r.s8;
}

// ---- per-channel sum of squares, 128-ch (pair_x) ----
__global__ void pair_sumsq_k(const float* __restrict__ p, float* __restrict__ out) {
  int r0 = blockIdx.x * 128;
  float acc = 0.f;
  for (int r = 0; r < 128; ++r) {
    float v = p[(size_t)(r0 + r) * 128 + threadIdx.x];
    acc += v * v;
  }
  atomicAdd(&out[threadIdx.x], acc);
}

// ---- per-channel sum of squares, 768-ch ----
__global__ void ch_sumsq768_k(const float* __restrict__ a, float* __restrict__ out) {
  int r0 = blockIdx.x * 16;
  int c = threadIdx.x;
  float acc = 0.f;
  for (int r = 0; r < 16; ++r) {
    float v = a[(size_t)(r0 + r) * 768 + c];
    acc += v * v;
  }
  atomicAdd(&out[c], acc);
}

// ---- pair bias v2: coalesced float4, half-wave per row, fused pair_x passthrough ----
// 256 thd = 8 rows/iter, 4 iters -> 32 rows/block; grid 1024.
__global__ __launch_bounds__(256) void pair_bias_k(
    const float* __restrict__ p, const float* __restrict__ ps,
    const float* __restrict__ g, const float* __restrict__ w,
    float* __restrict__ pb2, float* __restrict__ pcopy) {
  const int tid = threadIdx.x;
  const int lane32 = tid & 31;
  const int sub = tid >> 5;                 // 0..7 half-wave id
  const int c0 = lane32 * 4;
  // per-thread channel constants (row-independent)
  float4 gv = *(const float4*)&g[c0];
  float4 psv = *(const float4*)&ps[c0];
  float4 w0 = *(const float4*)&w[c0];
  float4 w1v = *(const float4*)&w[128 + c0];
  float sc[4] = {rsqrtf(psv.x * INV_PAIR + EPS) * gv.x,
                 rsqrtf(psv.y * INV_PAIR + EPS) * gv.y,
                 rsqrtf(psv.z * INV_PAIR + EPS) * gv.z,
                 rsqrtf(psv.w * INV_PAIR + EPS) * gv.w};
  float wa[4] = {w0.x, w0.y, w0.z, w0.w};
  float wb[4] = {w1v.x, w1v.y, w1v.z, w1v.w};
#pragma unroll
  for (int it = 0; it < 4; ++it) {
    int row = blockIdx.x * 32 + it * 8 + sub;
    float4 v = *(const float4*)&p[(size_t)row * 128 + c0];
    *(float4*)&pcopy[(size_t)row * 128 + c0] = v;  // passthrough output
    float vv[4] = {v.x, v.y, v.z, v.w};
    float a0 = 0.f, a1 = 0.f;
#pragma unroll
    for (int j = 0; j < 4; ++j) {
      float x = vv[j] * sc[j];
      float ge = 0.5f * x * (1.f + erff(x * 0.70710678118654752f));
      a0 += ge * wa[j];
      a1 += ge * wb[j];
    }
#pragma unroll
    for (int o = 1; o <= 16; o <<= 1) {
      a0 += __shfl_xor(a0, o);
      a1 += __shfl_xor(a1, o);
    }
    if (lane32 == 0) {
      pb2[(size_t)row * 2 + 0] = a0 * (0.4f * LOG2E);
      pb2[(size_t)row * 2 + 1] = a1 * (0.4f * LOG2E);
    }
  }
}

// ---- bf16 NT MFMA GEMM, 128x128 tile: gload_lds staging, linear LDS + XOR swizzle ----
template <bool RELU, bool OUT_BF16>
__global__ __launch_bounds__(256) void gemm_bf16_k(
    const ushort* __restrict__ A, const ushort* __restrict__ B,
    void* __restrict__ Cv, int M, int N, int K,
    const float* __restrict__ bias) {
  __shared__ __align__(16) ushort As[128 * 64];
  __shared__ __align__(16) ushort Bs[128 * 64];
  const int m0 = blockIdx.y * 128, n0 = blockIdx.x * 128;
  const int tid = threadIdx.x;
  const int lane = tid & 63;
  const int wid = tid >> 6;
  const int l15 = lane & 15, l4 = lane >> 4;
  const int wm = (wid >> 1) * 64, wn = (wid & 1) * 64;
  const ushort* asrc[4]; const ushort* bsrc[4];
  ushort* adst[4]; ushort* bdst[4];
#pragma unroll
  for (int u = 0; u < 4; ++u) {
    int ci = u * 256 + tid;
    int r = ci >> 3, s = ci & 7, g = s ^ (r & 7);
    asrc[u] = A + (size_t)(m0 + r) * K + g * 8;
    bsrc[u] = B + (size_t)(n0 + r) * K + g * 8;
    adst[u] = &As[(u * 256 + wid * 64) * 8];  // wave-uniform base
    bdst[u] = &Bs[(u * 256 + wid * 64) * 8];
  }
  f32x4 acc[4][4];
#pragma unroll
  for (int i = 0; i < 4; ++i)
#pragma unroll
    for (int j = 0; j < 4; ++j) acc[i][j] = (f32x4){0.f, 0.f, 0.f, 0.f};
  for (int k0 = 0; k0 < K; k0 += 64) {
#pragma unroll
    for (int u = 0; u < 4; ++u) {
      gl16(asrc[u] + k0, adst[u]);
      gl16(bsrc[u] + k0, bdst[u]);
    }
    __syncthreads();
#pragma unroll
    for (int ks = 0; ks < 2; ++ks) {
      const int sw = ((ks * 4 + l4) ^ (l15 & 7)) * 8;
      short8 af[4], bf[4];
#pragma unroll
      for (int i = 0; i < 4; ++i) af[i] = *(const short8*)&As[(wm + i * 16 + l15) * 64 + sw];
#pragma unroll
      for (int j = 0; j < 4; ++j) bf[j] = *(const short8*)&Bs[(wn + j * 16 + l15) * 64 + sw];
#pragma unroll
      for (int i = 0; i < 4; ++i)
#pragma unroll
        for (int j = 0; j < 4; ++j)
          acc[i][j] = __builtin_amdgcn_mfma_f32_16x16x32_bf16(af[i], bf[j], acc[i][j], 0, 0, 0);
    }
    __syncthreads();
  }
  float* Cf = (float*)Cv;
  ushort* Cb = (ushort*)Cv;
#pragma unroll
  for (int j = 0; j < 4; ++j) {
    int col = n0 + wn + j * 16 + l15;
    float bv = bias ? bias[col] : 0.f;
#pragma unroll
    for (int i = 0; i < 4; ++i) {
      int row = m0 + wm + i * 16 + l4 * 4;
#pragma unroll
      for (int r = 0; r < 4; ++r) {
        float v = acc[i][j][r] + bv;
        if (RELU) v = fmaxf(v, 0.f);
        if (OUT_BF16) Cb[(size_t)(row + r) * N + col] = f2bf(v);
        else Cf[(size_t)(row + r) * N + col] = v;
      }
    }
  }
}

// ---- bf16 NT MFMA GEMM, 64x128 tile (skinny N: wo, w2); optional column-sumsq. ----
template <bool SUMSQ>
__global__ __launch_bounds__(256) void gemm64_bf16_k(
    const ushort* __restrict__ A, const ushort* __restrict__ B,
    float* __restrict__ Cf, int M, int N, int K,
    const float* __restrict__ bias, float* __restrict__ ssq) {
  __shared__ __align__(16) ushort As[64 * 64];
  __shared__ __align__(16) ushort Bs[128 * 64];
  const int m0 = blockIdx.y * 64, n0 = blockIdx.x * 128;
  const int tid = threadIdx.x;
  const int lane = tid & 63;
  const int wid = tid >> 6;
  const int l15 = lane & 15, l4 = lane >> 4;
  const int wn = wid * 32;
  const ushort* asrc[2]; ushort* adst[2];
  const ushort* bsrc[4]; ushort* bdst[4];
#pragma unroll
  for (int u = 0; u < 2; ++u) {
    int ci = u * 256 + tid;
    int r = ci >> 3, s = ci & 7, g = s ^ (r & 7);
    asrc[u] = A + (size_t)(m0 + r) * K + g * 8;
    adst[u] = &As[(u * 256 + wid * 64) * 8];
  }
#pragma unroll
  for (int u = 0; u < 4; ++u) {
    int ci = u * 256 + tid;
    int r = ci >> 3, s = ci & 7, g = s ^ (r & 7);
    bsrc[u] = B + (size_t)(n0 + r) * K + g * 8;
    bdst[u] = &Bs[(u * 256 + wid * 64) * 8];
  }
  f32x4 acc[4][2];
#pragma unroll
  for (int i = 0; i < 4; ++i)
#pragma unroll
    for (int j = 0; j < 2; ++j) acc[i][j] = (f32x4){0.f, 0.f, 0.f, 0.f};
  for (int k0 = 0; k0 < K; k0 += 64) {
#pragma unroll
    for (int u = 0; u < 2; ++u) gl16(asrc[u] + k0, adst[u]);
#pragma unroll
    for (int u = 0; u < 4; ++u) gl16(bsrc[u] + k0, bdst[u]);
    __syncthreads();
#pragma unroll
    for (int ks = 0; ks < 2; ++ks) {
      const int sw = ((ks * 4 + l4) ^ (l15 & 7)) * 8;
      short8 af[4], bf[2];
#pragma unroll
      for (int i = 0; i < 4; ++i) af[i] = *(const short8*)&As[(i * 16 + l15) * 64 + sw];
#pragma unroll
      for (int j = 0; j < 2; ++j) bf[j] = *(const short8*)&Bs[(wn + j * 16 + l15) * 64 + sw];
#pragma unroll
      for (int i = 0; i < 4; ++i)
#pragma unroll
        for (int j = 0; j < 2; ++j)
          acc[i][j] = __builtin_amdgcn_mfma_f32_16x16x32_bf16(af[i], bf[j], acc[i][j], 0, 0, 0);
    }
    __syncthreads();
  }
#pragma unroll
  for (int j = 0; j < 2; ++j) {
    int col = n0 + wn + j * 16 + l15;
    float bv = bias ? bias[col] : 0.f;
    float sq = 0.f;
#pragma unroll
    for (int i = 0; i < 4; ++i) {
      int row = m0 + i * 16 + l4 * 4;
#pragma unroll
      for (int r = 0; r < 4; ++r) {
        float v = acc[i][j][r] + bv;
        if (SUMSQ) sq += v * v;
        Cf[(size_t)(row + r) * N + col] = v;
      }
    }
    if (SUMSQ) {
      sq += __shfl_xor(sq, 16);
      sq += __shfl_xor(sq, 32);
      if (l4 == 0) atomicAdd(&ssq[col], sq);
    }
  }
}

// ---- per-head LayerNorm + RoPE (table-driven); 256 thd = 2 rows ----
__global__ __launch_bounds__(256) void ln_rope_k(
    const float* __restrict__ qkv, const float2* __restrict__ rtab,
    const float* __restrict__ qg, const float* __restrict__ qb,
    const float* __restrict__ kg, const float* __restrict__ kb,
    const float* __restrict__ vg, const float* __restrict__ vb,
    ushort* __restrict__ q_b, ushort* __restrict__ k_b, ushort* __restrict__ v_b) {
  const int half = threadIdx.x >> 7;
  const int tid = threadIdx.x & 127;
  const int bs = blockIdx.x * 2 + half;
  const int slot = blockIdx.y;
  const int s = bs & (Sn - 1);
  const int b = bs >> 11;
  const float* src; const float* g; const float* be; ushort* dst; bool dorope; bool isq = false;
  if (slot < 8) {
    src = qkv + (size_t)bs * 2048 + slot * 128;
    g = qg; be = qb;
    dst = q_b + ((size_t)(b * 8 + slot) * Sn + s) * 128;
    dorope = true; isq = true;
  } else if (slot < 12) {
    int h = slot - 8;
    src = qkv + (size_t)bs * 2048 + 1024 + h * 128;
    g = kg; be = kb;
    dst = k_b + ((size_t)(b * 4 + h) * Sn + s) * 128;
    dorope = true;
  } else {
    int h = slot - 12;
    src = qkv + (size_t)bs * 2048 + 1536 + h * 128;
    g = vg; be = vb;
    dst = v_b + ((size_t)(b * 4 + h) * Sn + s) * 128;
    dorope = false;
  }
  __shared__ float sh[2][128];
  __shared__ float red[2][4];
  float v = src[tid];
  float sum = v;
#pragma unroll
  for (int o = 32; o >= 1; o >>= 1) sum += __shfl_xor(sum, o);
  if ((tid & 63) == 0) red[half][tid >> 6] = sum;
  __syncthreads();
  float mean = (red[half][0] + red[half][1]) * (1.f / 128.f);
  float d = v - mean;
  float s2 = d * d;
#pragma unroll
  for (int o = 32; o >= 1; o >>= 1) s2 += __shfl_xor(s2, o);
  if ((tid & 63) == 0) red[half][2 + (tid >> 6)] = s2;
  __syncthreads();
  float var = (red[half][2] + red[half][3]) * (1.f / 128.f);
  float val = d * rsqrtf(var + EPS) * g[tid] + be[tid];
  if (dorope) {
    sh[half][tid] = val;
    __syncthreads();
    float2 cssn = rtab[(s << 6) | (tid >> 1)];
    float rot = (tid & 1) ? sh[half][tid - 1] : -sh[half][tid + 1];
    val = val * cssn.x + rot * cssn.y;
  }
  if (isq) val *= 0.035355339059327376f * LOG2E;  // 0.4/sqrt(128)*log2e fold
  dst[tid] = f2bf(val);
}

// ---- transpose V: [hv][2048][128] bf16 -> [hv][128][2048] bf16 ----
__global__ __launch_bounds__(256) void vtrans_k(const ushort* __restrict__ vb,
                                                ushort* __restrict__ vtt) {
  __shared__ __align__(16) ushort T[64][136];
  const int hv = blockIdx.y, s0 = blockIdx.x * 64;
  const int tid = threadIdx.x;
  const ushort* src = vb + ((size_t)hv * Sn + s0) * 128;
#pragma unroll
  for (int u = 0; u < 4; ++u) {
    int fi = u * 256 + tid;
    int r = fi >> 4, c = (fi & 15) * 8;
    *(float4*)&T[r][c] = *(const float4*)&src[(size_t)r * 128 + c];
  }
  __syncthreads();
  ushort* dst = vtt + (size_t)hv * 128 * Sn + s0;
#pragma unroll
  for (int u = 0; u < 4; ++u) {
    int fi = u * 256 + tid;
    int d = fi >> 3, t8 = (fi & 7) * 8;
    union { float4 f4; ushort us[8]; } o;
#pragma unroll
    for (int j = 0; j < 8; ++j) o.us[j] = T[t8 + j][d];
    *(float4*)&dst[(size_t)d * Sn + t8] = o.f4;
  }
}

// ---- flash v13 (= proven v7, ~90us): 4 waves x 32 q-rows, split-KV(4),
//      swapped QK^T, no-max softcap softmax, gload_lds staging, (256,2). ----
__global__ __launch_bounds__(256, 2) void flash_v13_k(
    const ushort* __restrict__ qb, const ushort* __restrict__ kb,
    const ushort* __restrict__ vtt, const float* __restrict__ pb2,
    ushort* __restrict__ part_y, float* __restrict__ part_l) {
  __shared__ __align__(16) ushort Ks[64 * 128];    // [t][d] swizzled, 16KB
  __shared__ __align__(16) ushort Vt[128 * 64];    // [d][t] swizzled, 16KB
  __shared__ __align__(16) ushort Ps[4 * 32 * 64]; // per-wave P [q=32][t=64] swz, 16KB
  const int s0 = blockIdx.x * 128;
  const int bh = blockIdx.y;
  const int half = blockIdx.z;
  const int b = bh >> 3, h = bh & 7;
  const int kv = h & 3, grp = h >> 2;
  const int tid = threadIdx.x;
  const int wid = tid >> 6, lane = tid & 63;
  const int l15 = lane & 15, l4 = lane >> 4;
  const ushort* kbase = kb + (size_t)(b * 4 + kv) * Sn * 128;
  const ushort* vbase = vtt + (size_t)(b * 4 + kv) * 128 * Sn;
  const int qr0 = s0 + wid * 32;
  short8 qf[2][4];
#pragma unroll
  for (int rg = 0; rg < 2; ++rg)
#pragma unroll
    for (int kc = 0; kc < 4; ++kc)
      qf[rg][kc] = *(const short8*)&qb[((size_t)bh * Sn + qr0 + rg * 16 + l15) * 128 + kc * 32 + l4 * 8];
  // staging geometry (pre-swizzled global source, linear LDS dest)
  const ushort* ksrc[4]; const ushort* vsrc[4];
  ushort* kdst[4]; ushort* vdst[4];
#pragma unroll
  for (int u = 0; u < 4; ++u) {
    int ci = u * 256 + tid;
    int kr = ci >> 4, kg = (ci & 15) ^ (kr & 7);
    ksrc[u] = kbase + (size_t)kr * 128 + kg * 8;
    kdst[u] = &Ks[(u * 256 + wid * 64) * 8];
    int vd = ci >> 3, vg = (ci & 7) ^ (vd & 7);
    vsrc[u] = vbase + (size_t)vd * Sn + vg * 8;
    vdst[u] = &Vt[(u * 256 + wid * 64) * 8];
  }
  f32x4 y[2][8];
#pragma unroll
  for (int rg = 0; rg < 2; ++rg)
#pragma unroll
    for (int i = 0; i < 8; ++i) y[rg][i] = (f32x4){0.f, 0.f, 0.f, 0.f};
  float lsum[2] = {0.f, 0.f};  // q = l15 uniform per lane (S^T layout)
  const float C2 = -10.f * LOG2E;
  const int tbeg = half * 512;
  for (int t0 = tbeg; t0 < tbeg + 512; t0 += 64) {
    __syncthreads();  // prev tile's readers done
#pragma unroll
    for (int u = 0; u < 4; ++u) {
      gl16(ksrc[u] + (size_t)t0 * 128, kdst[u]);
      gl16(vsrc[u] + t0, vdst[u]);
    }
    __syncthreads();  // vmcnt drained by compiler before barrier
    // --- swapped QK^T: K frag read ONCE, used for both row-groups ---
    f32x4 acc[2][4];
#pragma unroll
    for (int rg = 0; rg < 2; ++rg)
#pragma unroll
      for (int nb = 0; nb < 4; ++nb) acc[rg][nb] = (f32x4){0.f, 0.f, 0.f, 0.f};
    __builtin_amdgcn_s_setprio(1);
#pragma unroll
    for (int kc = 0; kc < 4; ++kc)
#pragma unroll
      for (int nb = 0; nb < 4; ++nb) {
        short8 kf = *(const short8*)&Ks[KSW(nb * 16 + l15, kc * 32 + l4 * 8)];
        acc[0][nb] = __builtin_amdgcn_mfma_f32_16x16x32_bf16(kf, qf[0][kc], acc[0][nb], 0, 0, 0);
        acc[1][nb] = __builtin_amdgcn_mfma_f32_16x16x32_bf16(kf, qf[1][kc], acc[1][nb], 0, 0, 0);
      }
    __builtin_amdgcn_s_setprio(0);
    // --- softcap + fixed-shift softmax (base-2); cvt_pk pack ---
#pragma unroll
    for (int rg = 0; rg < 2; ++rg)
#pragma unroll
      for (int nb = 0; nb < 4; ++nb) {
        float bias = pb2[(((size_t)b * 128 + (s0 >> 4) + wid * 2 + rg) * 128 + (t0 >> 4) + nb) * 2 + grp];
        float p[4];
#pragma unroll
        for (int r = 0; r < 4; ++r) {
          float e = exp2f(acc[rg][nb][r] + bias);
          p[r] = exp2f(C2 * __builtin_amdgcn_rcpf(e + 1.f));
        }
        lsum[rg] += (p[0] + p[1]) + (p[2] + p[3]);
        uint2 pk;
        pk.x = cvt_pk_bf16(p[0], p[1]);
        pk.y = cvt_pk_bf16(p[2], p[3]);
        *(uint2*)&Ps[PSW2(wid, rg * 16 + l15, nb * 16 + l4 * 4)] = pk;
      }
    // --- PV: V frag read ONCE, used for both row-groups ---
    __builtin_amdgcn_s_setprio(1);
#pragma unroll
    for (int ks = 0; ks < 2; ++ks) {
      short8 pa0 = *(const short8*)&Ps[PSW2(wid, l15, ks * 32 + l4 * 8)];
      short8 pa1 = *(const short8*)&Ps[PSW2(wid, 16 + l15, ks * 32 + l4 * 8)];
#pragma unroll
      for (int nbd = 0; nbd < 8; ++nbd) {
        short8 vf = *(const short8*)&Vt[VTW(nbd * 16 + l15, ks * 32 + l4 * 8)];
        y[0][nbd] = __builtin_amdgcn_mfma_f32_16x16x32_bf16(pa0, vf, y[0][nbd], 0, 0, 0);
        y[1][nbd] = __builtin_amdgcn_mfma_f32_16x16x32_bf16(pa1, vf, y[1][nbd], 0, 0, 0);
      }
    }
    __builtin_amdgcn_s_setprio(0);
  }
  // --- partial row sums + unnormalized y out ---
#pragma unroll
  for (int rg = 0; rg < 2; ++rg) {
    float ls = lsum[rg];
    ls += __shfl_xor(ls, 16);
    ls += __shfl_xor(ls, 32);
    if (l4 == 0) part_l[(size_t)(half * 16 + bh) * Sn + qr0 + rg * 16 + l15] = ls;
    ushort* pybase = part_y + ((size_t)(half * 16 + bh) * Sn + qr0 + rg * 16) * 128;
#pragma unroll
    for (int nbd = 0; nbd < 8; ++nbd)
#pragma unroll
      for (int r = 0; r < 4; ++r)
        pybase[(size_t)(l4 * 4 + r) * 128 + nbd * 16 + l15] = f2bf(y[rg][nbd][r]);
  }
}

// ---- combine: attn = (y0+y1+y2+y3) / (l0+l1+l2+l3), bf16 ----
__global__ void combine_k(const ushort* __restrict__ part_y, const float* __restrict__ part_l,
                          ushort* __restrict__ attn_b) {
  int t = blockIdx.x * 256 + threadIdx.x;  // 524288 threads, 8 d each
  int row = t >> 4;                        // bh*2048 + s
  size_t o0 = (size_t)row * 128 + (t & 15) * 8;
  float acc[8] = {};
#pragma unroll
  for (int hf = 0; hf < 4; ++hf) {
    union { short8 s8; ushort us[8]; } u;
    u.s8 = *(const short8*)&part_y[o0 + (size_t)hf * 4194304];
#pragma unroll
    for (int j = 0; j < 8; ++j) acc[j] += bf2f(u.us[j]);
  }
  float rcp = 1.f / (part_l[row] + part_l[row + 32768] + part_l[row + 65536] + part_l[row + 98304]);
  union { short8 s8; ushort us[8]; } o;
#pragma unroll
  for (int j = 0; j < 8; ++j) o.us[j] = f2bf(acc[j] * rcp);
  *(short8*)&attn_b[o0] = o.s8;
}

// ---- out = base + delta*rsqrt(sums/4096+eps)*g ; optional out-sumsq accumulate ----
template <bool SUMSQ>
__global__ void add_scale_k(const float* __restrict__ base, const float* __restrict__ delta,
                            const float* __restrict__ sums, const float* __restrict__ g,
                            float* __restrict__ out, float* __restrict__ ssq) {
  const int c = threadIdx.x;
  const float sc = rsqrtf(sums[c] * INV_BS + EPS) * g[c];
  const int r0 = blockIdx.x * 16;
  float sq = 0.f;
  for (int r = 0; r < 16; ++r) {
    size_t idx = (size_t)(r0 + r) * 768 + c;
    float v = base[idx] + delta[idx] * sc;
    out[idx] = v;
    if (SUMSQ) sq += v * v;
  }
  if (SUMSQ) atomicAdd(&ssq[c], sq);
}

}  // namespace

extern "C" void kernel_launch(void* const* d_in, const int* in_sizes, int n_in,
                              void* d_out, int out_size, void* d_ws, size_t ws_size,
                              hipStream_t stream) {
  const float* x       = (const float*)d_in[0];
  const float* pair_x  = (const float*)d_in[1];
  const float* ab_bn_g = (const float*)d_in[2];
  const float* ab_fc_w = (const float*)d_in[3];
  const float* bn1_g   = (const float*)d_in[4];
  const float* wq      = (const float*)d_in[5];
  const float* wk      = (const float*)d_in[6];
  const float* wv      = (const float*)d_in[7];
  const float* qn_g    = (const float*)d_in[8];
  const float* qn_b    = (const float*)d_in[9];
  const float* kn_g    = (const float*)d_in[10];
  const float* kn_b    = (const float*)d_in[11];
  const float* vn_g    = (const float*)d_in[12];
  const float* vn_b    = (const float*)d_in[13];
  const float* wo      = (const float*)d_in[14];
  const float* bo      = (const float*)d_in[15];
  const float* bn2_g   = (const float*)d_in[16];
  const float* mbn1_g  = (const float*)d_in[17];
  const float* w1      = (const float*)d_in[18];
  const float* b1      = (const float*)d_in[19];
  const float* w2      = (const float*)d_in[20];
  const float* b2      = (const float*)d_in[21];
  const float* mbn2_g  = (const float*)d_in[22];
  float* out = (float*)d_out;
  float* ws = (float*)d_ws;

  // ws layout (f32 units), liveness-verified (round-12 proven offsets)
  float* ps    = ws + 0;
  float* xs    = ws + 256;
  float* es    = ws + 1024;
  float* x2s   = ws + 2048;
  float* fs    = ws + 3072;
  float* pb2   = ws + 4096;                   // 65,536
  ushort* wall_b = (ushort*)(ws + 69632);     // wq|wk|wv|wo|w1|w2 bf16 -> 2428928
  ushort* wo_b = (ushort*)(ws + 856064);
  ushort* w1_b = (ushort*)(ws + 1249280);
  ushort* w2_b = (ushort*)(ws + 1839104);
  ushort* xn_b = (ushort*)(ws + 2428928);     // 1,572,864 f (dead after qkv gemm)
  float* qkvtmp = ws + 4001792;               // 8,388,608 f (dead after ln_rope)
  ushort* q_b  = (ushort*)(ws + 12390400);    // 2,097,152 f (dead after flash)
  ushort* k_b  = (ushort*)(ws + 14487552);    // 1,048,576 f (dead after flash)
  ushort* v_b  = (ushort*)(ws + 15536128);    // 1,048,576 f (dead after vtrans)
  float2* rtab = (float2*)(ws + 16584704);    // 262,144 f (cos/sin table, live thru ln_rope)
  // overlays:
  ushort* v_tt = (ushort*)(ws + 2428928);     // 1,048,576 f over dead xn_b
  ushort* part_y = (ushort*)(ws + 3477504);   // 8,388,608 f over dead qkvtmp (4 x 4M shorts)
  float* part_l = ws + 11866112;              // 131,072 f over dead qkvtmp tail
  ushort* attn_b = (ushort*)(ws + 11997184);  // 2,097,152 f over dead qkvtmp/q_b (post-flash)
  float* proj  = ws + 3477504;                // 3,145,728 f over dead part_y (post-combine)
  float* x2    = ws + 6623232;                // 3,145,728 f over dead part_y
  ushort* x2n_b = (ushort*)(ws + 9768960);    // 1,572,864 f over dead part_y
  ushort* hbuf_b = (ushort*)(ws + 3477504);   // 3,145,728 f over dead proj (post add_scale)
  float* proj2 = ws + 11341824;               // 3,145,728 f over dead attn_b/q_b tail

  (void)hipMemsetAsync(ws, 0, 4096 * sizeof(float), stream);

  castall_k<<<2304, 256, 0, stream>>>(wq, wk, wv, wo, w1, w2, wall_b);
  rope_tab_k<<<512, 256, 0, stream>>>(rtab);

  pair_sumsq_k<<<256, 128, 0, stream>>>(pair_x, ps);
  // pair bias + fused pair_x passthrough into the output tail
  pair_bias_k<<<1024, 256, 0, stream>>>(pair_x, ps, ab_bn_g, ab_fc_w, pb2, out + 3145728);
  ch_sumsq768_k<<<256, 768, 0, stream>>>(x, xs);
  scale_cast_k<<<1536, 256, 0, stream>>>(x, xs, bn1_g, xn_b);
  gemm_bf16_k<false, false><<<dim3(16, 32), 256, 0, stream>>>(xn_b, wall_b, qkvtmp, 4096, 2048, 768, nullptr);
  ln_rope_k<<<dim3(2048, 16), 256, 0, stream>>>(qkvtmp, rtab, qn_g, qn_b, kn_g, kn_b,
                                                vn_g, vn_b, q_b, k_b, v_b);
  vtrans_k<<<dim3(32, 8), 256, 0, stream>>>(v_b, v_tt);
  flash_v13_k<<<dim3(16, 16, 4), 256, 0, stream>>>(q_b, k_b, v_tt, pb2, part_y, part_l);
  combine_k<<<2048, 256, 0, stream>>>(part_y, part_l, attn_b);
  gemm64_bf16_k<true><<<dim3(6, 64), 256, 0, stream>>>(attn_b, wo_b, proj, 4096, 768, 1024, bo, es);
  add_scale_k<true><<<256, 768, 0, stream>>>(x, proj, es, bn2_g, x2, x2s);
  scale_cast_k<<<1536, 256, 0, stream>>>(x2, x2s, mbn1_g, x2n_b);
  gemm_bf16_k<true, true><<<dim3(12, 32), 256, 0, stream>>>(x2n_b, w1_b, hbuf_b, 4096, 1536, 768, b1);
  gemm64_bf16_k<true><<<dim3(6, 64), 256, 0, stream>>>(hbuf_b, w2_b, proj2, 4096, 768, 1536, b2, fs);
  add_scale_k<false><<<256, 768, 0, stream>>>(x2, proj2, fs, mbn2_g, out, nullptr);
}

// Round 17
// 254.040 us; speedup vs baseline: 1.1614x; 1.0499x over previous
//
#include <hip/hip_runtime.h>
#include <math.h>

#define EPS 1e-5f

typedef __attribute__((ext_vector_type(8))) short short8;
typedef __attribute__((ext_vector_type(4))) float f32x4;

namespace {

constexpr int Bn = 2, Sn = 2048, Cn = 768;
constexpr float INV_BS = 1.0f / 4096.0f;     // B*S
constexpr float INV_PAIR = 1.0f / 32768.0f;  // B*SP*SP
constexpr float LOG2E = 1.4426950408889634f;

__device__ __forceinline__ ushort f2bf(float f) {
  uint u = __float_as_uint(f);
  u = (u + 0x7fffu + ((u >> 16) & 1u)) >> 16;
  return (ushort)u;
}
__device__ __forceinline__ float bf2f(ushort u) {
  return __uint_as_float(((uint)u) << 16);
}
__device__ __forceinline__ uint cvt_pk_bf16(float lo, float hi) {
  uint r;
  asm("v_cvt_pk_bf16_f32 %0, %1, %2" : "=v"(r) : "v"(lo), "v"(hi));
  return r;
}
// async global->LDS, 16B per lane; LDS dest is wave-uniform base (+lane*16 by HW)
__device__ __forceinline__ void gl16(const ushort* g, ushort* l) {
  __builtin_amdgcn_global_load_lds(
      (const __attribute__((address_space(1))) unsigned int*)(unsigned long long)(size_t)g,
      (__attribute__((address_space(3))) unsigned int*)(unsigned int)(size_t)l, 16, 0, 0);
}

// swizzled LDS index helpers (ushort units; XOR swaps 16B slots within a row)
#define KSW(r, c) ((((r) * 128) + (c)) ^ (((r) & 7) * 8))
#define VTW(d, t) ((((d) * 64) + (t)) ^ (((d) & 7) * 8))
#define PSW2(w, q, c) ((w) * 2048 + ((((q) * 64) + (c)) ^ (((q) & 7) * 8)))

// ---- unified prep: castall | rope_tab | pair_sumsq | ch_sumsq768(x), one launch ----
__global__ __launch_bounds__(256) void prep_k(
    const float* __restrict__ wq, const float* __restrict__ wk,
    const float* __restrict__ wv, const float* __restrict__ wo,
    const float* __restrict__ w1, const float* __restrict__ w2,
    ushort* __restrict__ wdst, float2* __restrict__ rtab,
    const float* __restrict__ pair, float* __restrict__ ps,
    const float* __restrict__ x, float* __restrict__ xs) {
  const int blk = blockIdx.x;
  const int tid = threadIdx.x;
  if (blk < 2304) {
    // weight casts (589824 units of 8 floats)
    int u = blk * 256 + tid;
    const float* src; int local;
    if (u < 98304)       { src = wq; local = u; }
    else if (u < 147456) { src = wk; local = u - 98304; }
    else if (u < 196608) { src = wv; local = u - 147456; }
    else if (u < 294912) { src = wo; local = u - 196608; }
    else if (u < 442368) { src = w1; local = u - 294912; }
    else                 { src = w2; local = u - 442368; }
    int i = local * 8;
    float4 a = *(const float4*)&src[i];
    float4 b = *(const float4*)&src[i + 4];
    union { short8 s8; ushort us[8]; } o;
    o.us[0] = f2bf(a.x); o.us[1] = f2bf(a.y); o.us[2] = f2bf(a.z); o.us[3] = f2bf(a.w);
    o.us[4] = f2bf(b.x); o.us[5] = f2bf(b.y); o.us[6] = f2bf(b.z); o.us[7] = f2bf(b.w);
    *(short8*)&wdst[u * 8] = o.s8;
  } else if (blk < 2816) {
    // RoPE cos/sin table (131072 entries)
    int idx = (blk - 2304) * 256 + tid;
    int s = idx >> 6, i = idx & 63;
    const float kGeo = logf(1985.0f) * (1.0f / 63.0f);
    float inv = 1.0f / ((float)i + expf((float)i * kGeo));
    float th = (float)s * inv;
    rtab[idx] = make_float2(cosf(th), sinf(th));
  } else if (blk < 2944) {
    // pair_x per-channel sumsq: 128 blocks x 256 rows
    int c = tid & 127;
    int r0 = (blk - 2816) * 256 + (tid >> 7) * 128;
    float acc = 0.f;
    for (int r = 0; r < 128; ++r) {
      float v = pair[(size_t)(r0 + r) * 128 + c];
      acc += v * v;
    }
    atomicAdd(&ps[c], acc);
  } else {
    // x per-channel sumsq: 256 blocks x 16 rows, 3 cols/thread
    int r0 = (blk - 2944) * 16;
    float a0 = 0.f, a1 = 0.f, a2 = 0.f;
    for (int r = 0; r < 16; ++r) {
      const float* row = x + (size_t)(r0 + r) * 768;
      float v0 = row[tid], v1 = row[tid + 256], v2 = row[tid + 512];
      a0 += v0 * v0; a1 += v1 * v1; a2 += v2 * v2;
    }
    atomicAdd(&xs[tid], a0);
    atomicAdd(&xs[tid + 256], a1);
    atomicAdd(&xs[tid + 512], a2);
  }
}

// ---- rms_bn scale + bf16 cast ----
__global__ void scale_cast_k(const float* __restrict__ a, const float* __restrict__ sums,
                             const float* __restrict__ g, ushort* __restrict__ o) {
  int idx = blockIdx.x * 256 + threadIdx.x;
  int c0 = (idx % 96) * 8;
  int base = idx * 8;
  float4 v0 = *(const float4*)&a[base];
  float4 v1 = *(const float4*)&a[base + 4];
  union { short8 s8; ushort us[8]; } r;
  float vv[8] = {v0.x, v0.y, v0.z, v0.w, v1.x, v1.y, v1.z, v1.w};
#pragma unroll
  for (int j = 0; j < 8; ++j) {
    float sc = rsqrtf(sums[c0 + j] * INV_BS + EPS) * g[c0 + j];
    r.us[j] = f2bf(vv[j] * sc);
  }
  *(short8*)&o[base] = r.s8;
}

// ---- per-channel sum of squares, 768-ch ----
__global__ void ch_sumsq768_k(const float* __restrict__ a, float* __restrict__ out) {
  int r0 = blockIdx.x * 16;
  int c = threadIdx.x;
  float acc = 0.f;
  for (int r = 0; r < 16; ++r) {
    float v = a[(size_t)(r0 + r) * 768 + c];
    acc += v * v;
  }
  atomicAdd(&out[c], acc);
}

// ---- pair bias v2: coalesced float4, half-wave per row, fused pair_x passthrough ----
__global__ __launch_bounds__(256) void pair_bias_k(
    const float* __restrict__ p, const float* __restrict__ ps,
    const float* __restrict__ g, const float* __restrict__ w,
    float* __restrict__ pb2, float* __restrict__ pcopy) {
  const int tid = threadIdx.x;
  const int lane32 = tid & 31;
  const int sub = tid >> 5;                 // 0..7 half-wave id
  const int c0 = lane32 * 4;
  float4 gv = *(const float4*)&g[c0];
  float4 psv = *(const float4*)&ps[c0];
  float4 w0 = *(const float4*)&w[c0];
  float4 w1v = *(const float4*)&w[128 + c0];
  float sc[4] = {rsqrtf(psv.x * INV_PAIR + EPS) * gv.x,
                 rsqrtf(psv.y * INV_PAIR + EPS) * gv.y,
                 rsqrtf(psv.z * INV_PAIR + EPS) * gv.z,
                 rsqrtf(psv.w * INV_PAIR + EPS) * gv.w};
  float wa[4] = {w0.x, w0.y, w0.z, w0.w};
  float wb[4] = {w1v.x, w1v.y, w1v.z, w1v.w};
#pragma unroll
  for (int it = 0; it < 4; ++it) {
    int row = blockIdx.x * 32 + it * 8 + sub;
    float4 v = *(const float4*)&p[(size_t)row * 128 + c0];
    *(float4*)&pcopy[(size_t)row * 128 + c0] = v;  // passthrough output
    float vv[4] = {v.x, v.y, v.z, v.w};
    float a0 = 0.f, a1 = 0.f;
#pragma unroll
    for (int j = 0; j < 4; ++j) {
      float x = vv[j] * sc[j];
      float ge = 0.5f * x * (1.f + erff(x * 0.70710678118654752f));
      a0 += ge * wa[j];
      a1 += ge * wb[j];
    }
#pragma unroll
    for (int o = 1; o <= 16; o <<= 1) {
      a0 += __shfl_xor(a0, o);
      a1 += __shfl_xor(a1, o);
    }
    if (lane32 == 0) {
      pb2[(size_t)row * 2 + 0] = a0 * (0.4f * LOG2E);
      pb2[(size_t)row * 2 + 1] = a1 * (0.4f * LOG2E);
    }
  }
}

// ---- bf16 NT MFMA GEMM, 128x128 tile: gload_lds staging, linear LDS + XOR swizzle ----
template <bool RELU, bool OUT_BF16>
__global__ __launch_bounds__(256) void gemm_bf16_k(
    const ushort* __restrict__ A, const ushort* __restrict__ B,
    void* __restrict__ Cv, int M, int N, int K,
    const float* __restrict__ bias) {
  __shared__ __align__(16) ushort As[128 * 64];
  __shared__ __align__(16) ushort Bs[128 * 64];
  const int m0 = blockIdx.y * 128, n0 = blockIdx.x * 128;
  const int tid = threadIdx.x;
  const int lane = tid & 63;
  const int wid = tid >> 6;
  const int l15 = lane & 15, l4 = lane >> 4;
  const int wm = (wid >> 1) * 64, wn = (wid & 1) * 64;
  const ushort* asrc[4]; const ushort* bsrc[4];
  ushort* adst[4]; ushort* bdst[4];
#pragma unroll
  for (int u = 0; u < 4; ++u) {
    int ci = u * 256 + tid;
    int r = ci >> 3, s = ci & 7, g = s ^ (r & 7);
    asrc[u] = A + (size_t)(m0 + r) * K + g * 8;
    bsrc[u] = B + (size_t)(n0 + r) * K + g * 8;
    adst[u] = &As[(u * 256 + wid * 64) * 8];  // wave-uniform base
    bdst[u] = &Bs[(u * 256 + wid * 64) * 8];
  }
  f32x4 acc[4][4];
#pragma unroll
  for (int i = 0; i < 4; ++i)
#pragma unroll
    for (int j = 0; j < 4; ++j) acc[i][j] = (f32x4){0.f, 0.f, 0.f, 0.f};
  for (int k0 = 0; k0 < K; k0 += 64) {
#pragma unroll
    for (int u = 0; u < 4; ++u) {
      gl16(asrc[u] + k0, adst[u]);
      gl16(bsrc[u] + k0, bdst[u]);
    }
    __syncthreads();
#pragma unroll
    for (int ks = 0; ks < 2; ++ks) {
      const int sw = ((ks * 4 + l4) ^ (l15 & 7)) * 8;
      short8 af[4], bf[4];
#pragma unroll
      for (int i = 0; i < 4; ++i) af[i] = *(const short8*)&As[(wm + i * 16 + l15) * 64 + sw];
#pragma unroll
      for (int j = 0; j < 4; ++j) bf[j] = *(const short8*)&Bs[(wn + j * 16 + l15) * 64 + sw];
#pragma unroll
      for (int i = 0; i < 4; ++i)
#pragma unroll
        for (int j = 0; j < 4; ++j)
          acc[i][j] = __builtin_amdgcn_mfma_f32_16x16x32_bf16(af[i], bf[j], acc[i][j], 0, 0, 0);
    }
    __syncthreads();
  }
  float* Cf = (float*)Cv;
  ushort* Cb = (ushort*)Cv;
#pragma unroll
  for (int j = 0; j < 4; ++j) {
    int col = n0 + wn + j * 16 + l15;
    float bv = bias ? bias[col] : 0.f;
#pragma unroll
    for (int i = 0; i < 4; ++i) {
      int row = m0 + wm + i * 16 + l4 * 4;
#pragma unroll
      for (int r = 0; r < 4; ++r) {
        float v = acc[i][j][r] + bv;
        if (RELU) v = fmaxf(v, 0.f);
        if (OUT_BF16) Cb[(size_t)(row + r) * N + col] = f2bf(v);
        else Cf[(size_t)(row + r) * N + col] = v;
      }
    }
  }
}

// ---- bf16 NT MFMA GEMM, 64x128 tile (skinny N: wo, w2); optional column-sumsq. ----
template <bool SUMSQ>
__global__ __launch_bounds__(256) void gemm64_bf16_k(
    const ushort* __restrict__ A, const ushort* __restrict__ B,
    float* __restrict__ Cf, int M, int N, int K,
    const float* __restrict__ bias, float* __restrict__ ssq) {
  __shared__ __align__(16) ushort As[64 * 64];
  __shared__ __align__(16) ushort Bs[128 * 64];
  const int m0 = blockIdx.y * 64, n0 = blockIdx.x * 128;
  const int tid = threadIdx.x;
  const int lane = tid & 63;
  const int wid = tid >> 6;
  const int l15 = lane & 15, l4 = lane >> 4;
  const int wn = wid * 32;
  const ushort* asrc[2]; ushort* adst[2];
  const ushort* bsrc[4]; ushort* bdst[4];
#pragma unroll
  for (int u = 0; u < 2; ++u) {
    int ci = u * 256 + tid;
    int r = ci >> 3, s = ci & 7, g = s ^ (r & 7);
    asrc[u] = A + (size_t)(m0 + r) * K + g * 8;
    adst[u] = &As[(u * 256 + wid * 64) * 8];
  }
#pragma unroll
  for (int u = 0; u < 4; ++u) {
    int ci = u * 256 + tid;
    int r = ci >> 3, s = ci & 7, g = s ^ (r & 7);
    bsrc[u] = B + (size_t)(n0 + r) * K + g * 8;
    bdst[u] = &Bs[(u * 256 + wid * 64) * 8];
  }
  f32x4 acc[4][2];
#pragma unroll
  for (int i = 0; i < 4; ++i)
#pragma unroll
    for (int j = 0; j < 2; ++j) acc[i][j] = (f32x4){0.f, 0.f, 0.f, 0.f};
  for (int k0 = 0; k0 < K; k0 += 64) {
#pragma unroll
    for (int u = 0; u < 2; ++u) gl16(asrc[u] + k0, adst[u]);
#pragma unroll
    for (int u = 0; u < 4; ++u) gl16(bsrc[u] + k0, bdst[u]);
    __syncthreads();
#pragma unroll
    for (int ks = 0; ks < 2; ++ks) {
      const int sw = ((ks * 4 + l4) ^ (l15 & 7)) * 8;
      short8 af[4], bf[2];
#pragma unroll
      for (int i = 0; i < 4; ++i) af[i] = *(const short8*)&As[(i * 16 + l15) * 64 + sw];
#pragma unroll
      for (int j = 0; j < 2; ++j) bf[j] = *(const short8*)&Bs[(wn + j * 16 + l15) * 64 + sw];
#pragma unroll
      for (int i = 0; i < 4; ++i)
#pragma unroll
        for (int j = 0; j < 2; ++j)
          acc[i][j] = __builtin_amdgcn_mfma_f32_16x16x32_bf16(af[i], bf[j], acc[i][j], 0, 0, 0);
    }
    __syncthreads();
  }
#pragma unroll
  for (int j = 0; j < 2; ++j) {
    int col = n0 + wn + j * 16 + l15;
    float bv = bias ? bias[col] : 0.f;
    float sq = 0.f;
#pragma unroll
    for (int i = 0; i < 4; ++i) {
      int row = m0 + i * 16 + l4 * 4;
#pragma unroll
      for (int r = 0; r < 4; ++r) {
        float v = acc[i][j][r] + bv;
        if (SUMSQ) sq += v * v;
        Cf[(size_t)(row + r) * N + col] = v;
      }
    }
    if (SUMSQ) {
      sq += __shfl_xor(sq, 16);
      sq += __shfl_xor(sq, 32);
      if (l4 == 0) atomicAdd(&ssq[col], sq);
    }
  }
}

// ---- per-head LayerNorm + RoPE (table-driven); 256 thd = 2 rows ----
__global__ __launch_bounds__(256) void ln_rope_k(
    const float* __restrict__ qkv, const float2* __restrict__ rtab,
    const float* __restrict__ qg, const float* __restrict__ qb,
    const float* __restrict__ kg, const float* __restrict__ kb,
    const float* __restrict__ vg, const float* __restrict__ vb,
    ushort* __restrict__ q_b, ushort* __restrict__ k_b, ushort* __restrict__ v_b) {
  const int half = threadIdx.x >> 7;
  const int tid = threadIdx.x & 127;
  const int bs = blockIdx.x * 2 + half;
  const int slot = blockIdx.y;
  const int s = bs & (Sn - 1);
  const int b = bs >> 11;
  const float* src; const float* g; const float* be; ushort* dst; bool dorope; bool isq = false;
  if (slot < 8) {
    src = qkv + (size_t)bs * 2048 + slot * 128;
    g = qg; be = qb;
    dst = q_b + ((size_t)(b * 8 + slot) * Sn + s) * 128;
    dorope = true; isq = true;
  } else if (slot < 12) {
    int h = slot - 8;
    src = qkv + (size_t)bs * 2048 + 1024 + h * 128;
    g = kg; be = kb;
    dst = k_b + ((size_t)(b * 4 + h) * Sn + s) * 128;
    dorope = true;
  } else {
    int h = slot - 12;
    src = qkv + (size_t)bs * 2048 + 1536 + h * 128;
    g = vg; be = vb;
    dst = v_b + ((size_t)(b * 4 + h) * Sn + s) * 128;
    dorope = false;
  }
  __shared__ float sh[2][128];
  __shared__ float red[2][4];
  float v = src[tid];
  float sum = v;
#pragma unroll
  for (int o = 32; o >= 1; o >>= 1) sum += __shfl_xor(sum, o);
  if ((tid & 63) == 0) red[half][tid >> 6] = sum;
  __syncthreads();
  float mean = (red[half][0] + red[half][1]) * (1.f / 128.f);
  float d = v - mean;
  float s2 = d * d;
#pragma unroll
  for (int o = 32; o >= 1; o >>= 1) s2 += __shfl_xor(s2, o);
  if ((tid & 63) == 0) red[half][2 + (tid >> 6)] = s2;
  __syncthreads();
  float var = (red[half][2] + red[half][3]) * (1.f / 128.f);
  float val = d * rsqrtf(var + EPS) * g[tid] + be[tid];
  if (dorope) {
    sh[half][tid] = val;
    __syncthreads();
    float2 cssn = rtab[(s << 6) | (tid >> 1)];
    float rot = (tid & 1) ? sh[half][tid - 1] : -sh[half][tid + 1];
    val = val * cssn.x + rot * cssn.y;
  }
  if (isq) val *= 0.035355339059327376f * LOG2E;  // 0.4/sqrt(128)*log2e fold
  dst[tid] = f2bf(val);
}

// ---- transpose V: [hv][2048][128] bf16 -> [hv][128][2048] bf16 ----
__global__ __launch_bounds__(256) void vtrans_k(const ushort* __restrict__ vb,
                                                ushort* __restrict__ vtt) {
  __shared__ __align__(16) ushort T[64][136];
  const int hv = blockIdx.y, s0 = blockIdx.x * 64;
  const int tid = threadIdx.x;
  const ushort* src = vb + ((size_t)hv * Sn + s0) * 128;
#pragma unroll
  for (int u = 0; u < 4; ++u) {
    int fi = u * 256 + tid;
    int r = fi >> 4, c = (fi & 15) * 8;
    *(float4*)&T[r][c] = *(const float4*)&src[(size_t)r * 128 + c];
  }
  __syncthreads();
  ushort* dst = vtt + (size_t)hv * 128 * Sn + s0;
#pragma unroll
  for (int u = 0; u < 4; ++u) {
    int fi = u * 256 + tid;
    int d = fi >> 3, t8 = (fi & 7) * 8;
    union { float4 f4; ushort us[8]; } o;
#pragma unroll
    for (int j = 0; j < 8; ++j) o.us[j] = T[t8 + j][d];
    *(float4*)&dst[(size_t)d * Sn + t8] = o.f4;
  }
}

// ---- flash v14: v7 body, split-KV(2) -> grid 512 = one packed round at 2 blk/CU ----
__global__ __launch_bounds__(256, 2) void flash_v14_k(
    const ushort* __restrict__ qb, const ushort* __restrict__ kb,
    const ushort* __restrict__ vtt, const float* __restrict__ pb2,
    ushort* __restrict__ part_y, float* __restrict__ part_l) {
  __shared__ __align__(16) ushort Ks[64 * 128];    // [t][d] swizzled, 16KB
  __shared__ __align__(16) ushort Vt[128 * 64];    // [d][t] swizzled, 16KB
  __shared__ __align__(16) ushort Ps[4 * 32 * 64]; // per-wave P [q=32][t=64] swz, 16KB
  const int s0 = blockIdx.x * 128;
  const int bh = blockIdx.y;
  const int half = blockIdx.z;                     // 0..1
  const int b = bh >> 3, h = bh & 7;
  const int kv = h & 3, grp = h >> 2;
  const int tid = threadIdx.x;
  const int wid = tid >> 6, lane = tid & 63;
  const int l15 = lane & 15, l4 = lane >> 4;
  const ushort* kbase = kb + (size_t)(b * 4 + kv) * Sn * 128;
  const ushort* vbase = vtt + (size_t)(b * 4 + kv) * 128 * Sn;
  const int qr0 = s0 + wid * 32;
  short8 qf[2][4];
#pragma unroll
  for (int rg = 0; rg < 2; ++rg)
#pragma unroll
    for (int kc = 0; kc < 4; ++kc)
      qf[rg][kc] = *(const short8*)&qb[((size_t)bh * Sn + qr0 + rg * 16 + l15) * 128 + kc * 32 + l4 * 8];
  // staging geometry (pre-swizzled global source, linear LDS dest)
  const ushort* ksrc[4]; const ushort* vsrc[4];
  ushort* kdst[4]; ushort* vdst[4];
#pragma unroll
  for (int u = 0; u < 4; ++u) {
    int ci = u * 256 + tid;
    int kr = ci >> 4, kg = (ci & 15) ^ (kr & 7);
    ksrc[u] = kbase + (size_t)kr * 128 + kg * 8;
    kdst[u] = &Ks[(u * 256 + wid * 64) * 8];
    int vd = ci >> 3, vg = (ci & 7) ^ (vd & 7);
    vsrc[u] = vbase + (size_t)vd * Sn + vg * 8;
    vdst[u] = &Vt[(u * 256 + wid * 64) * 8];
  }
  f32x4 y[2][8];
#pragma unroll
  for (int rg = 0; rg < 2; ++rg)
#pragma unroll
    for (int i = 0; i < 8; ++i) y[rg][i] = (f32x4){0.f, 0.f, 0.f, 0.f};
  float lsum[2] = {0.f, 0.f};  // q = l15 uniform per lane (S^T layout)
  const float C2 = -10.f * LOG2E;
  const int tbeg = half * 1024;
  for (int t0 = tbeg; t0 < tbeg + 1024; t0 += 64) {
    __syncthreads();  // prev tile's readers done
#pragma unroll
    for (int u = 0; u < 4; ++u) {
      gl16(ksrc[u] + (size_t)t0 * 128, kdst[u]);
      gl16(vsrc[u] + t0, vdst[u]);
    }
    __syncthreads();  // vmcnt drained by compiler before barrier
    // --- swapped QK^T: K frag read ONCE, used for both row-groups ---
    f32x4 acc[2][4];
#pragma unroll
    for (int rg = 0; rg < 2; ++rg)
#pragma unroll
      for (int nb = 0; nb < 4; ++nb) acc[rg][nb] = (f32x4){0.f, 0.f, 0.f, 0.f};
    __builtin_amdgcn_s_setprio(1);
#pragma unroll
    for (int kc = 0; kc < 4; ++kc)
#pragma unroll
      for (int nb = 0; nb < 4; ++nb) {
        short8 kf = *(const short8*)&Ks[KSW(nb * 16 + l15, kc * 32 + l4 * 8)];
        acc[0][nb] = __builtin_amdgcn_mfma_f32_16x16x32_bf16(kf, qf[0][kc], acc[0][nb], 0, 0, 0);
        acc[1][nb] = __builtin_amdgcn_mfma_f32_16x16x32_bf16(kf, qf[1][kc], acc[1][nb], 0, 0, 0);
      }
    __builtin_amdgcn_s_setprio(0);
    // --- softcap + fixed-shift softmax (base-2); cvt_pk pack ---
#pragma unroll
    for (int rg = 0; rg < 2; ++rg)
#pragma unroll
      for (int nb = 0; nb < 4; ++nb) {
        float bias = pb2[(((size_t)b * 128 + (s0 >> 4) + wid * 2 + rg) * 128 + (t0 >> 4) + nb) * 2 + grp];
        float p[4];
#pragma unroll
        for (int r = 0; r < 4; ++r) {
          float e = exp2f(acc[rg][nb][r] + bias);
          p[r] = exp2f(C2 * __builtin_amdgcn_rcpf(e + 1.f));
        }
        lsum[rg] += (p[0] + p[1]) + (p[2] + p[3]);
        uint2 pk;
        pk.x = cvt_pk_bf16(p[0], p[1]);
        pk.y = cvt_pk_bf16(p[2], p[3]);
        *(uint2*)&Ps[PSW2(wid, rg * 16 + l15, nb * 16 + l4 * 4)] = pk;
      }
    // --- PV: V frag read ONCE, used for both row-groups ---
    __builtin_amdgcn_s_setprio(1);
#pragma unroll
    for (int ks = 0; ks < 2; ++ks) {
      short8 pa0 = *(const short8*)&Ps[PSW2(wid, l15, ks * 32 + l4 * 8)];
      short8 pa1 = *(const short8*)&Ps[PSW2(wid, 16 + l15, ks * 32 + l4 * 8)];
#pragma unroll
      for (int nbd = 0; nbd < 8; ++nbd) {
        short8 vf = *(const short8*)&Vt[VTW(nbd * 16 + l15, ks * 32 + l4 * 8)];
        y[0][nbd] = __builtin_amdgcn_mfma_f32_16x16x32_bf16(pa0, vf, y[0][nbd], 0, 0, 0);
        y[1][nbd] = __builtin_amdgcn_mfma_f32_16x16x32_bf16(pa1, vf, y[1][nbd], 0, 0, 0);
      }
    }
    __builtin_amdgcn_s_setprio(0);
  }
  // --- partial row sums + unnormalized y out ---
#pragma unroll
  for (int rg = 0; rg < 2; ++rg) {
    float ls = lsum[rg];
    ls += __shfl_xor(ls, 16);
    ls += __shfl_xor(ls, 32);
    if (l4 == 0) part_l[(size_t)(half * 16 + bh) * Sn + qr0 + rg * 16 + l15] = ls;
    ushort* pybase = part_y + ((size_t)(half * 16 + bh) * Sn + qr0 + rg * 16) * 128;
#pragma unroll
    for (int nbd = 0; nbd < 8; ++nbd)
#pragma unroll
      for (int r = 0; r < 4; ++r)
        pybase[(size_t)(l4 * 4 + r) * 128 + nbd * 16 + l15] = f2bf(y[rg][nbd][r]);
  }
}

// ---- combine: attn = (y0+y1) / (l0+l1), bf16 ----
__global__ void combine_k(const ushort* __restrict__ part_y, const float* __restrict__ part_l,
                          ushort* __restrict__ attn_b) {
  int t = blockIdx.x * 256 + threadIdx.x;  // 524288 threads, 8 d each
  int row = t >> 4;                        // bh*2048 + s
  size_t o0 = (size_t)row * 128 + (t & 15) * 8;
  float acc[8] = {};
#pragma unroll
  for (int hf = 0; hf < 2; ++hf) {
    union { short8 s8; ushort us[8]; } u;
    u.s8 = *(const short8*)&part_y[o0 + (size_t)hf * 4194304];
#pragma unroll
    for (int j = 0; j < 8; ++j) acc[j] += bf2f(u.us[j]);
  }
  float rcp = 1.f / (part_l[row] + part_l[row + 32768]);
  union { short8 s8; ushort us[8]; } o;
#pragma unroll
  for (int j = 0; j < 8; ++j) o.us[j] = f2bf(acc[j] * rcp);
  *(short8*)&attn_b[o0] = o.s8;
}

// ---- out = base + delta*rsqrt(sums/4096+eps)*g ; optional out-sumsq accumulate ----
template <bool SUMSQ>
__global__ void add_scale_k(const float* __restrict__ base, const float* __restrict__ delta,
                            const float* __restrict__ sums, const float* __restrict__ g,
                            float* __restrict__ out, float* __restrict__ ssq) {
  const int c = threadIdx.x;
  const float sc = rsqrtf(sums[c] * INV_BS + EPS) * g[c];
  const int r0 = blockIdx.x * 16;
  float sq = 0.f;
  for (int r = 0; r < 16; ++r) {
    size_t idx = (size_t)(r0 + r) * 768 + c;
    float v = base[idx] + delta[idx] * sc;
    out[idx] = v;
    if (SUMSQ) sq += v * v;
  }
  if (SUMSQ) atomicAdd(&ssq[c], sq);
}

}  // namespace

extern "C" void kernel_launch(void* const* d_in, const int* in_sizes, int n_in,
                              void* d_out, int out_size, void* d_ws, size_t ws_size,
                              hipStream_t stream) {
  const float* x       = (const float*)d_in[0];
  const float* pair_x  = (const float*)d_in[1];
  const float* ab_bn_g = (const float*)d_in[2];
  const float* ab_fc_w = (const float*)d_in[3];
  const float* bn1_g   = (const float*)d_in[4];
  const float* wq      = (const float*)d_in[5];
  const float* wk      = (const float*)d_in[6];
  const float* wv      = (const float*)d_in[7];
  const float* qn_g    = (const float*)d_in[8];
  const float* qn_b    = (const float*)d_in[9];
  const float* kn_g    = (const float*)d_in[10];
  const float* kn_b    = (const float*)d_in[11];
  const float* vn_g    = (const float*)d_in[12];
  const float* vn_b    = (const float*)d_in[13];
  const float* wo      = (const float*)d_in[14];
  const float* bo      = (const float*)d_in[15];
  const float* bn2_g   = (const float*)d_in[16];
  const float* mbn1_g  = (const float*)d_in[17];
  const float* w1      = (const float*)d_in[18];
  const float* b1      = (const float*)d_in[19];
  const float* w2      = (const float*)d_in[20];
  const float* b2      = (const float*)d_in[21];
  const float* mbn2_g  = (const float*)d_in[22];
  float* out = (float*)d_out;
  float* ws = (float*)d_ws;

  // ws layout (f32 units), liveness-verified (round-12 proven offsets)
  float* ps    = ws + 0;
  float* xs    = ws + 256;
  float* es    = ws + 1024;
  float* x2s   = ws + 2048;
  float* fs    = ws + 3072;
  float* pb2   = ws + 4096;                   // 65,536
  ushort* wall_b = (ushort*)(ws + 69632);     // wq|wk|wv|wo|w1|w2 bf16 -> 2428928
  ushort* wo_b = (ushort*)(ws + 856064);
  ushort* w1_b = (ushort*)(ws + 1249280);
  ushort* w2_b = (ushort*)(ws + 1839104);
  ushort* xn_b = (ushort*)(ws + 2428928);     // 1,572,864 f (dead after qkv gemm)
  float* qkvtmp = ws + 4001792;               // 8,388,608 f (dead after ln_rope)
  ushort* q_b  = (ushort*)(ws + 12390400);    // 2,097,152 f (dead after flash)
  ushort* k_b  = (ushort*)(ws + 14487552);    // 1,048,576 f (dead after flash)
  ushort* v_b  = (ushort*)(ws + 15536128);    // 1,048,576 f (dead after vtrans)
  float2* rtab = (float2*)(ws + 16584704);    // 262,144 f (cos/sin table, live thru ln_rope)
  // overlays:
  ushort* v_tt = (ushort*)(ws + 2428928);     // 1,048,576 f over dead xn_b
  ushort* part_y = (ushort*)(ws + 3477504);   // 4,194,304 f over dead qkvtmp (2 x 4M shorts)
  float* part_l = ws + 11866112;              // 65,536 f over dead qkvtmp tail
  ushort* attn_b = (ushort*)(ws + 11997184);  // 2,097,152 f over dead qkvtmp/q_b (post-flash)
  float* proj  = ws + 3477504;                // 3,145,728 f over dead part_y (post-combine)
  float* x2    = ws + 6623232;                // 3,145,728 f over dead part_y
  ushort* x2n_b = (ushort*)(ws + 9768960);    // 1,572,864 f over dead part_y
  ushort* hbuf_b = (ushort*)(ws + 3477504);   // 3,145,728 f over dead proj (post add_scale)
  float* proj2 = ws + 11341824;               // 3,145,728 f over dead attn_b/q_b tail

  (void)hipMemsetAsync(ws, 0, 4096 * sizeof(float), stream);

  // unified prep: weight casts | rope table | pair sumsq | x sumsq
  prep_k<<<3200, 256, 0, stream>>>(wq, wk, wv, wo, w1, w2, wall_b, rtab,
                                   pair_x, ps, x, xs);
  // pair bias + fused pair_x passthrough into the output tail
  pair_bias_k<<<1024, 256, 0, stream>>>(pair_x, ps, ab_bn_g, ab_fc_w, pb2, out + 3145728);
  scale_cast_k<<<1536, 256, 0, stream>>>(x, xs, bn1_g, xn_b);
  gemm_bf16_k<false, false><<<dim3(16, 32), 256, 0, stream>>>(xn_b, wall_b, qkvtmp, 4096, 2048, 768, nullptr);
  ln_rope_k<<<dim3(2048, 16), 256, 0, stream>>>(qkvtmp, rtab, qn_g, qn_b, kn_g, kn_b,
                                                vn_g, vn_b, q_b, k_b, v_b);
  vtrans_k<<<dim3(32, 8), 256, 0, stream>>>(v_b, v_tt);
  flash_v14_k<<<dim3(16, 16, 2), 256, 0, stream>>>(q_b, k_b, v_tt, pb2, part_y, part_l);
  combine_k<<<2048, 256, 0, stream>>>(part_y, part_l, attn_b);
  gemm64_bf16_k<true><<<dim3(6, 64), 256, 0, stream>>>(attn_b, wo_b, proj, 4096, 768, 1024, bo, es);
  add_scale_k<true><<<256, 768, 0, stream>>>(x, proj, es, bn2_g, x2, x2s);
  scale_cast_k<<<1536, 256, 0, stream>>>(x2, x2s, mbn1_g, x2n_b);
  gemm_bf16_k<true, true><<<dim3(12, 32), 256, 0, stream>>>(x2n_b, w1_b, hbuf_b, 4096, 1536, 768, b1);
  gemm64_bf16_k<true><<<dim3(6, 64), 256, 0, stream>>>(hbuf_b, w2_b, proj2, 4096, 768, 1536, b2, fs);
  add_scale_k<false><<<256, 768, 0, stream>>>(x2, proj2, fs, mbn2_g, out, nullptr);
}

// Round 18
// 239.560 us; speedup vs baseline: 1.2315x; 1.0604x over previous
//
#include <hip/hip_runtime.h>
#include <math.h>

#define EPS 1e-5f

typedef __attribute__((ext_vector_type(8))) short short8;
typedef __attribute__((ext_vector_type(4))) float f32x4;

namespace {

constexpr int Bn = 2, Sn = 2048, Cn = 768;
constexpr float INV_BS = 1.0f / 4096.0f;     // B*S
constexpr float INV_PAIR = 1.0f / 32768.0f;  // B*SP*SP
constexpr float LOG2E = 1.4426950408889634f;

__device__ __forceinline__ ushort f2bf(float f) {
  uint u = __float_as_uint(f);
  u = (u + 0x7fffu + ((u >> 16) & 1u)) >> 16;
  return (ushort)u;
}
__device__ __forceinline__ float bf2f(ushort u) {
  return __uint_as_float(((uint)u) << 16);
}
__device__ __forceinline__ uint cvt_pk_bf16(float lo, float hi) {
  uint r;
  asm("v_cvt_pk_bf16_f32 %0, %1, %2" : "=v"(r) : "v"(lo), "v"(hi));
  return r;
}
// async global->LDS, 16B per lane; LDS dest is wave-uniform base (+lane*16 by HW)
__device__ __forceinline__ void gl16(const ushort* g, ushort* l) {
  __builtin_amdgcn_global_load_lds(
      (const __attribute__((address_space(1))) unsigned int*)(unsigned long long)(size_t)g,
      (__attribute__((address_space(3))) unsigned int*)(unsigned int)(size_t)l, 16, 0, 0);
}

// swizzled LDS index helpers (ushort units; XOR swaps 16B slots within a row)
#define KSW(r, c) ((((r) * 128) + (c)) ^ (((r) & 7) * 8))
#define VTW(d, t) ((((d) * 64) + (t)) ^ (((d) & 7) * 8))
#define PSW2(w, q, c) ((w) * 2048 + ((((q) * 64) + (c)) ^ (((q) & 7) * 8)))

// ---- unified prep: castall | rope_tab | pair_sumsq | ch_sumsq768(x), one launch ----
__global__ __launch_bounds__(256) void prep_k(
    const float* __restrict__ wq, const float* __restrict__ wk,
    const float* __restrict__ wv, const float* __restrict__ wo,
    const float* __restrict__ w1, const float* __restrict__ w2,
    ushort* __restrict__ wdst, float2* __restrict__ rtab,
    const float* __restrict__ pair, float* __restrict__ ps,
    const float* __restrict__ x, float* __restrict__ xs) {
  const int blk = blockIdx.x;
  const int tid = threadIdx.x;
  if (blk < 2304) {
    int u = blk * 256 + tid;
    const float* src; int local;
    if (u < 98304)       { src = wq; local = u; }
    else if (u < 147456) { src = wk; local = u - 98304; }
    else if (u < 196608) { src = wv; local = u - 147456; }
    else if (u < 294912) { src = wo; local = u - 196608; }
    else if (u < 442368) { src = w1; local = u - 294912; }
    else                 { src = w2; local = u - 442368; }
    int i = local * 8;
    float4 a = *(const float4*)&src[i];
    float4 b = *(const float4*)&src[i + 4];
    union { short8 s8; ushort us[8]; } o;
    o.us[0] = f2bf(a.x); o.us[1] = f2bf(a.y); o.us[2] = f2bf(a.z); o.us[3] = f2bf(a.w);
    o.us[4] = f2bf(b.x); o.us[5] = f2bf(b.y); o.us[6] = f2bf(b.z); o.us[7] = f2bf(b.w);
    *(short8*)&wdst[u * 8] = o.s8;
  } else if (blk < 2816) {
    int idx = (blk - 2304) * 256 + tid;
    int s = idx >> 6, i = idx & 63;
    const float kGeo = logf(1985.0f) * (1.0f / 63.0f);
    float inv = 1.0f / ((float)i + expf((float)i * kGeo));
    float th = (float)s * inv;
    rtab[idx] = make_float2(cosf(th), sinf(th));
  } else if (blk < 2944) {
    int c = tid & 127;
    int r0 = (blk - 2816) * 256 + (tid >> 7) * 128;
    float acc = 0.f;
    for (int r = 0; r < 128; ++r) {
      float v = pair[(size_t)(r0 + r) * 128 + c];
      acc += v * v;
    }
    atomicAdd(&ps[c], acc);
  } else {
    int r0 = (blk - 2944) * 16;
    float a0 = 0.f, a1 = 0.f, a2 = 0.f;
    for (int r = 0; r < 16; ++r) {
      const float* row = x + (size_t)(r0 + r) * 768;
      float v0 = row[tid], v1 = row[tid + 256], v2 = row[tid + 512];
      a0 += v0 * v0; a1 += v1 * v1; a2 += v2 * v2;
    }
    atomicAdd(&xs[tid], a0);
    atomicAdd(&xs[tid + 256], a1);
    atomicAdd(&xs[tid + 512], a2);
  }
}

// ---- rms_bn scale + bf16 cast ----
__global__ void scale_cast_k(const float* __restrict__ a, const float* __restrict__ sums,
                             const float* __restrict__ g, ushort* __restrict__ o) {
  int idx = blockIdx.x * 256 + threadIdx.x;
  int c0 = (idx % 96) * 8;
  int base = idx * 8;
  float4 v0 = *(const float4*)&a[base];
  float4 v1 = *(const float4*)&a[base + 4];
  union { short8 s8; ushort us[8]; } r;
  float vv[8] = {v0.x, v0.y, v0.z, v0.w, v1.x, v1.y, v1.z, v1.w};
#pragma unroll
  for (int j = 0; j < 8; ++j) {
    float sc = rsqrtf(sums[c0 + j] * INV_BS + EPS) * g[c0 + j];
    r.us[j] = f2bf(vv[j] * sc);
  }
  *(short8*)&o[base] = r.s8;
}

// ---- pair bias v2: coalesced float4, half-wave per row, fused pair_x passthrough ----
__global__ __launch_bounds__(256) void pair_bias_k(
    const float* __restrict__ p, const float* __restrict__ ps,
    const float* __restrict__ g, const float* __restrict__ w,
    float* __restrict__ pb2, float* __restrict__ pcopy) {
  const int tid = threadIdx.x;
  const int lane32 = tid & 31;
  const int sub = tid >> 5;
  const int c0 = lane32 * 4;
  float4 gv = *(const float4*)&g[c0];
  float4 psv = *(const float4*)&ps[c0];
  float4 w0 = *(const float4*)&w[c0];
  float4 w1v = *(const float4*)&w[128 + c0];
  float sc[4] = {rsqrtf(psv.x * INV_PAIR + EPS) * gv.x,
                 rsqrtf(psv.y * INV_PAIR + EPS) * gv.y,
                 rsqrtf(psv.z * INV_PAIR + EPS) * gv.z,
                 rsqrtf(psv.w * INV_PAIR + EPS) * gv.w};
  float wa[4] = {w0.x, w0.y, w0.z, w0.w};
  float wb[4] = {w1v.x, w1v.y, w1v.z, w1v.w};
#pragma unroll
  for (int it = 0; it < 4; ++it) {
    int row = blockIdx.x * 32 + it * 8 + sub;
    float4 v = *(const float4*)&p[(size_t)row * 128 + c0];
    *(float4*)&pcopy[(size_t)row * 128 + c0] = v;
    float vv[4] = {v.x, v.y, v.z, v.w};
    float a0 = 0.f, a1 = 0.f;
#pragma unroll
    for (int j = 0; j < 4; ++j) {
      float x = vv[j] * sc[j];
      float ge = 0.5f * x * (1.f + erff(x * 0.70710678118654752f));
      a0 += ge * wa[j];
      a1 += ge * wb[j];
    }
#pragma unroll
    for (int o = 1; o <= 16; o <<= 1) {
      a0 += __shfl_xor(a0, o);
      a1 += __shfl_xor(a1, o);
    }
    if (lane32 == 0) {
      pb2[(size_t)row * 2 + 0] = a0 * (0.4f * LOG2E);
      pb2[(size_t)row * 2 + 1] = a1 * (0.4f * LOG2E);
    }
  }
}

// ---- fused QKV GEMM + LayerNorm + RoPE + V-transpose epilogue ----
// tile 128x128, slot = blockIdx.x (= head slot; LN dim == tile width).
__global__ __launch_bounds__(256) void gemm_qkv_k(
    const ushort* __restrict__ A, const ushort* __restrict__ B, int K,
    const float* __restrict__ qn_g, const float* __restrict__ qn_b,
    const float* __restrict__ kn_g, const float* __restrict__ kn_b,
    const float* __restrict__ vn_g, const float* __restrict__ vn_b,
    const float2* __restrict__ rtab,
    ushort* __restrict__ q_b, ushort* __restrict__ k_b, ushort* __restrict__ v_tt) {
  __shared__ __align__(16) ushort As[128 * 64];
  __shared__ __align__(16) ushort Bs[128 * 64];
  __shared__ float2 redS[128][2];
  const int m0 = blockIdx.y * 128, n0 = blockIdx.x * 128;
  const int tid = threadIdx.x;
  const int lane = tid & 63;
  const int wid = tid >> 6;
  const int l15 = lane & 15, l4 = lane >> 4;
  const int wm = (wid >> 1) * 64, wn = (wid & 1) * 64;
  const ushort* asrc[4]; const ushort* bsrc[4];
  ushort* adst[4]; ushort* bdst[4];
#pragma unroll
  for (int u = 0; u < 4; ++u) {
    int ci = u * 256 + tid;
    int r = ci >> 3, s = ci & 7, g = s ^ (r & 7);
    asrc[u] = A + (size_t)(m0 + r) * K + g * 8;
    bsrc[u] = B + (size_t)(n0 + r) * K + g * 8;
    adst[u] = &As[(u * 256 + wid * 64) * 8];
    bdst[u] = &Bs[(u * 256 + wid * 64) * 8];
  }
  f32x4 acc[4][4];
#pragma unroll
  for (int i = 0; i < 4; ++i)
#pragma unroll
    for (int j = 0; j < 4; ++j) acc[i][j] = (f32x4){0.f, 0.f, 0.f, 0.f};
  for (int k0 = 0; k0 < K; k0 += 64) {
#pragma unroll
    for (int u = 0; u < 4; ++u) {
      gl16(asrc[u] + k0, adst[u]);
      gl16(bsrc[u] + k0, bdst[u]);
    }
    __syncthreads();
#pragma unroll
    for (int ks = 0; ks < 2; ++ks) {
      const int sw = ((ks * 4 + l4) ^ (l15 & 7)) * 8;
      short8 af[4], bf[4];
#pragma unroll
      for (int i = 0; i < 4; ++i) af[i] = *(const short8*)&As[(wm + i * 16 + l15) * 64 + sw];
#pragma unroll
      for (int j = 0; j < 4; ++j) bf[j] = *(const short8*)&Bs[(wn + j * 16 + l15) * 64 + sw];
#pragma unroll
      for (int i = 0; i < 4; ++i)
#pragma unroll
        for (int j = 0; j < 4; ++j)
          acc[i][j] = __builtin_amdgcn_mfma_f32_16x16x32_bf16(af[i], bf[j], acc[i][j], 0, 0, 0);
    }
    __syncthreads();
  }
  // ---- LN epilogue: row stats (rows = LN vectors; slot width = tile width) ----
  const int slot = blockIdx.x;
  const float* gvec; const float* bvec; int mode;
  if (slot < 8)       { gvec = qn_g; bvec = qn_b; mode = 0; }
  else if (slot < 12) { gvec = kn_g; bvec = kn_b; mode = 1; }
  else                { gvec = vn_g; bvec = vn_b; mode = 2; }
  float rsum[4][4], rsq[4][4];
#pragma unroll
  for (int i = 0; i < 4; ++i)
#pragma unroll
    for (int r = 0; r < 4; ++r) {
      float s1 = 0.f, s2 = 0.f;
#pragma unroll
      for (int j = 0; j < 4; ++j) {
        float a = acc[i][j][r];
        s1 += a; s2 += a * a;
      }
#pragma unroll
      for (int o = 1; o <= 8; o <<= 1) {
        s1 += __shfl_xor(s1, o);
        s2 += __shfl_xor(s2, o);
      }
      rsum[i][r] = s1; rsq[i][r] = s2;
    }
  if (l15 == 0) {
#pragma unroll
    for (int i = 0; i < 4; ++i)
#pragma unroll
      for (int r = 0; r < 4; ++r)
        redS[wm + i * 16 + l4 * 4 + r][wn >> 6] = make_float2(rsum[i][r], rsq[i][r]);
  }
  __syncthreads();
  float gv4[4], bv4[4];
#pragma unroll
  for (int j = 0; j < 4; ++j) {
    int c = wn + j * 16 + l15;
    gv4[j] = gvec[c]; bv4[j] = bvec[c];
  }
  const float QS = 0.035355339059327376f * LOG2E;  // 0.4/sqrt(128)*log2e
#pragma unroll
  for (int i = 0; i < 4; ++i) {
    // row stats for this i (4 rows)
    float mean[4], rstd[4];
#pragma unroll
    for (int r = 0; r < 4; ++r) {
      int row = wm + i * 16 + l4 * 4 + r;
      float2 h0 = redS[row][0], h1 = redS[row][1];
      float m = (h0.x + h1.x) * (1.f / 128.f);
      float v = (h0.y + h1.y) * (1.f / 128.f) - m * m;
      mean[r] = m; rstd[r] = rsqrtf(v + EPS);
    }
    const int row0 = wm + i * 16 + l4 * 4;
    const int bs0 = m0 + row0;
    const int s0v = bs0 & (Sn - 1);
    const int bb = bs0 >> 11;
#pragma unroll
    for (int j = 0; j < 4; ++j) {
      int c = wn + j * 16 + l15;
      union { unsigned long long u64; ushort us[4]; } pk;
#pragma unroll
      for (int r = 0; r < 4; ++r) {
        float val = (acc[i][j][r] - mean[r]) * rstd[r] * gv4[j] + bv4[j];
        if (mode < 2) {
          float sx = __shfl_xor(val, 1);
          float rot = (c & 1) ? sx : -sx;
          float2 cssn = rtab[((s0v + r) << 6) | (c >> 1)];
          val = val * cssn.x + rot * cssn.y;
          if (mode == 0) {
            val *= QS;
            q_b[((size_t)(bb * 8 + slot) * Sn + s0v + r) * 128 + c] = f2bf(val);
          } else {
            k_b[((size_t)(bb * 4 + slot - 8) * Sn + s0v + r) * 128 + c] = f2bf(val);
          }
        } else {
          pk.us[r] = f2bf(val);
        }
      }
      if (mode == 2) {
        // V^T: [b*4+h][d=c][t=s0v..s0v+3], 8B store
        *(unsigned long long*)&v_tt[((size_t)(bb * 4 + slot - 12) * 128 + c) * Sn + s0v] = pk.u64;
      }
    }
  }
}

// ---- bf16 NT MFMA GEMM, 128x128 tile: gload_lds staging, linear LDS + XOR swizzle ----
template <bool RELU, bool OUT_BF16>
__global__ __launch_bounds__(256) void gemm_bf16_k(
    const ushort* __restrict__ A, const ushort* __restrict__ B,
    void* __restrict__ Cv, int M, int N, int K,
    const float* __restrict__ bias) {
  __shared__ __align__(16) ushort As[128 * 64];
  __shared__ __align__(16) ushort Bs[128 * 64];
  const int m0 = blockIdx.y * 128, n0 = blockIdx.x * 128;
  const int tid = threadIdx.x;
  const int lane = tid & 63;
  const int wid = tid >> 6;
  const int l15 = lane & 15, l4 = lane >> 4;
  const int wm = (wid >> 1) * 64, wn = (wid & 1) * 64;
  const ushort* asrc[4]; const ushort* bsrc[4];
  ushort* adst[4]; ushort* bdst[4];
#pragma unroll
  for (int u = 0; u < 4; ++u) {
    int ci = u * 256 + tid;
    int r = ci >> 3, s = ci & 7, g = s ^ (r & 7);
    asrc[u] = A + (size_t)(m0 + r) * K + g * 8;
    bsrc[u] = B + (size_t)(n0 + r) * K + g * 8;
    adst[u] = &As[(u * 256 + wid * 64) * 8];
    bdst[u] = &Bs[(u * 256 + wid * 64) * 8];
  }
  f32x4 acc[4][4];
#pragma unroll
  for (int i = 0; i < 4; ++i)
#pragma unroll
    for (int j = 0; j < 4; ++j) acc[i][j] = (f32x4){0.f, 0.f, 0.f, 0.f};
  for (int k0 = 0; k0 < K; k0 += 64) {
#pragma unroll
    for (int u = 0; u < 4; ++u) {
      gl16(asrc[u] + k0, adst[u]);
      gl16(bsrc[u] + k0, bdst[u]);
    }
    __syncthreads();
#pragma unroll
    for (int ks = 0; ks < 2; ++ks) {
      const int sw = ((ks * 4 + l4) ^ (l15 & 7)) * 8;
      short8 af[4], bf[4];
#pragma unroll
      for (int i = 0; i < 4; ++i) af[i] = *(const short8*)&As[(wm + i * 16 + l15) * 64 + sw];
#pragma unroll
      for (int j = 0; j < 4; ++j) bf[j] = *(const short8*)&Bs[(wn + j * 16 + l15) * 64 + sw];
#pragma unroll
      for (int i = 0; i < 4; ++i)
#pragma unroll
        for (int j = 0; j < 4; ++j)
          acc[i][j] = __builtin_amdgcn_mfma_f32_16x16x32_bf16(af[i], bf[j], acc[i][j], 0, 0, 0);
    }
    __syncthreads();
  }
  float* Cf = (float*)Cv;
  ushort* Cb = (ushort*)Cv;
#pragma unroll
  for (int j = 0; j < 4; ++j) {
    int col = n0 + wn + j * 16 + l15;
    float bv = bias ? bias[col] : 0.f;
#pragma unroll
    for (int i = 0; i < 4; ++i) {
      int row = m0 + wm + i * 16 + l4 * 4;
#pragma unroll
      for (int r = 0; r < 4; ++r) {
        float v = acc[i][j][r] + bv;
        if (RELU) v = fmaxf(v, 0.f);
        if (OUT_BF16) Cb[(size_t)(row + r) * N + col] = f2bf(v);
        else Cf[(size_t)(row + r) * N + col] = v;
      }
    }
  }
}

// ---- bf16 NT MFMA GEMM, 64x128 tile (skinny N: wo, w2); optional column-sumsq. ----
template <bool SUMSQ>
__global__ __launch_bounds__(256) void gemm64_bf16_k(
    const ushort* __restrict__ A, const ushort* __restrict__ B,
    float* __restrict__ Cf, int M, int N, int K,
    const float* __restrict__ bias, float* __restrict__ ssq) {
  __shared__ __align__(16) ushort As[64 * 64];
  __shared__ __align__(16) ushort Bs[128 * 64];
  const int m0 = blockIdx.y * 64, n0 = blockIdx.x * 128;
  const int tid = threadIdx.x;
  const int lane = tid & 63;
  const int wid = tid >> 6;
  const int l15 = lane & 15, l4 = lane >> 4;
  const int wn = wid * 32;
  const ushort* asrc[2]; ushort* adst[2];
  const ushort* bsrc[4]; ushort* bdst[4];
#pragma unroll
  for (int u = 0; u < 2; ++u) {
    int ci = u * 256 + tid;
    int r = ci >> 3, s = ci & 7, g = s ^ (r & 7);
    asrc[u] = A + (size_t)(m0 + r) * K + g * 8;
    adst[u] = &As[(u * 256 + wid * 64) * 8];
  }
#pragma unroll
  for (int u = 0; u < 4; ++u) {
    int ci = u * 256 + tid;
    int r = ci >> 3, s = ci & 7, g = s ^ (r & 7);
    bsrc[u] = B + (size_t)(n0 + r) * K + g * 8;
    bdst[u] = &Bs[(u * 256 + wid * 64) * 8];
  }
  f32x4 acc[4][2];
#pragma unroll
  for (int i = 0; i < 4; ++i)
#pragma unroll
    for (int j = 0; j < 2; ++j) acc[i][j] = (f32x4){0.f, 0.f, 0.f, 0.f};
  for (int k0 = 0; k0 < K; k0 += 64) {
#pragma unroll
    for (int u = 0; u < 2; ++u) gl16(asrc[u] + k0, adst[u]);
#pragma unroll
    for (int u = 0; u < 4; ++u) gl16(bsrc[u] + k0, bdst[u]);
    __syncthreads();
#pragma unroll
    for (int ks = 0; ks < 2; ++ks) {
      const int sw = ((ks * 4 + l4) ^ (l15 & 7)) * 8;
      short8 af[4], bf[2];
#pragma unroll
      for (int i = 0; i < 4; ++i) af[i] = *(const short8*)&As[(i * 16 + l15) * 64 + sw];
#pragma unroll
      for (int j = 0; j < 2; ++j) bf[j] = *(const short8*)&Bs[(wn + j * 16 + l15) * 64 + sw];
#pragma unroll
      for (int i = 0; i < 4; ++i)
#pragma unroll
        for (int j = 0; j < 2; ++j)
          acc[i][j] = __builtin_amdgcn_mfma_f32_16x16x32_bf16(af[i], bf[j], acc[i][j], 0, 0, 0);
    }
    __syncthreads();
  }
#pragma unroll
  for (int j = 0; j < 2; ++j) {
    int col = n0 + wn + j * 16 + l15;
    float bv = bias ? bias[col] : 0.f;
    float sq = 0.f;
#pragma unroll
    for (int i = 0; i < 4; ++i) {
      int row = m0 + i * 16 + l4 * 4;
#pragma unroll
      for (int r = 0; r < 4; ++r) {
        float v = acc[i][j][r] + bv;
        if (SUMSQ) sq += v * v;
        Cf[(size_t)(row + r) * N + col] = v;
      }
    }
    if (SUMSQ) {
      sq += __shfl_xor(sq, 16);
      sq += __shfl_xor(sq, 32);
      if (l4 == 0) atomicAdd(&ssq[col], sq);
    }
  }
}

// ---- flash v14: 4 waves x 32 q-rows, split-KV(2) (512-block packed round) ----
__global__ __launch_bounds__(256, 2) void flash_v14_k(
    const ushort* __restrict__ qb, const ushort* __restrict__ kb,
    const ushort* __restrict__ vtt, const float* __restrict__ pb2,
    ushort* __restrict__ part_y, float* __restrict__ part_l) {
  __shared__ __align__(16) ushort Ks[64 * 128];
  __shared__ __align__(16) ushort Vt[128 * 64];
  __shared__ __align__(16) ushort Ps[4 * 32 * 64];
  const int s0 = blockIdx.x * 128;
  const int bh = blockIdx.y;
  const int half = blockIdx.z;
  const int b = bh >> 3, h = bh & 7;
  const int kv = h & 3, grp = h >> 2;
  const int tid = threadIdx.x;
  const int wid = tid >> 6, lane = tid & 63;
  const int l15 = lane & 15, l4 = lane >> 4;
  const ushort* kbase = kb + (size_t)(b * 4 + kv) * Sn * 128;
  const ushort* vbase = vtt + (size_t)(b * 4 + kv) * 128 * Sn;
  const int qr0 = s0 + wid * 32;
  short8 qf[2][4];
#pragma unroll
  for (int rg = 0; rg < 2; ++rg)
#pragma unroll
    for (int kc = 0; kc < 4; ++kc)
      qf[rg][kc] = *(const short8*)&qb[((size_t)bh * Sn + qr0 + rg * 16 + l15) * 128 + kc * 32 + l4 * 8];
  const ushort* ksrc[4]; const ushort* vsrc[4];
  ushort* kdst[4]; ushort* vdst[4];
#pragma unroll
  for (int u = 0; u < 4; ++u) {
    int ci = u * 256 + tid;
    int kr = ci >> 4, kg = (ci & 15) ^ (kr & 7);
    ksrc[u] = kbase + (size_t)kr * 128 + kg * 8;
    kdst[u] = &Ks[(u * 256 + wid * 64) * 8];
    int vd = ci >> 3, vg = (ci & 7) ^ (vd & 7);
    vsrc[u] = vbase + (size_t)vd * Sn + vg * 8;
    vdst[u] = &Vt[(u * 256 + wid * 64) * 8];
  }
  f32x4 y[2][8];
#pragma unroll
  for (int rg = 0; rg < 2; ++rg)
#pragma unroll
    for (int i = 0; i < 8; ++i) y[rg][i] = (f32x4){0.f, 0.f, 0.f, 0.f};
  float lsum[2] = {0.f, 0.f};
  const float C2 = -10.f * LOG2E;
  const int tbeg = half * 1024;
  for (int t0 = tbeg; t0 < tbeg + 1024; t0 += 64) {
    __syncthreads();
#pragma unroll
    for (int u = 0; u < 4; ++u) {
      gl16(ksrc[u] + (size_t)t0 * 128, kdst[u]);
      gl16(vsrc[u] + t0, vdst[u]);
    }
    __syncthreads();
    f32x4 acc[2][4];
#pragma unroll
    for (int rg = 0; rg < 2; ++rg)
#pragma unroll
      for (int nb = 0; nb < 4; ++nb) acc[rg][nb] = (f32x4){0.f, 0.f, 0.f, 0.f};
    __builtin_amdgcn_s_setprio(1);
#pragma unroll
    for (int kc = 0; kc < 4; ++kc)
#pragma unroll
      for (int nb = 0; nb < 4; ++nb) {
        short8 kf = *(const short8*)&Ks[KSW(nb * 16 + l15, kc * 32 + l4 * 8)];
        acc[0][nb] = __builtin_amdgcn_mfma_f32_16x16x32_bf16(kf, qf[0][kc], acc[0][nb], 0, 0, 0);
        acc[1][nb] = __builtin_amdgcn_mfma_f32_16x16x32_bf16(kf, qf[1][kc], acc[1][nb], 0, 0, 0);
      }
    __builtin_amdgcn_s_setprio(0);
#pragma unroll
    for (int rg = 0; rg < 2; ++rg)
#pragma unroll
      for (int nb = 0; nb < 4; ++nb) {
        float bias = pb2[(((size_t)b * 128 + (s0 >> 4) + wid * 2 + rg) * 128 + (t0 >> 4) + nb) * 2 + grp];
        float p[4];
#pragma unroll
        for (int r = 0; r < 4; ++r) {
          float e = exp2f(acc[rg][nb][r] + bias);
          p[r] = exp2f(C2 * __builtin_amdgcn_rcpf(e + 1.f));
        }
        lsum[rg] += (p[0] + p[1]) + (p[2] + p[3]);
        uint2 pk;
        pk.x = cvt_pk_bf16(p[0], p[1]);
        pk.y = cvt_pk_bf16(p[2], p[3]);
        *(uint2*)&Ps[PSW2(wid, rg * 16 + l15, nb * 16 + l4 * 4)] = pk;
      }
    __builtin_amdgcn_s_setprio(1);
#pragma unroll
    for (int ks = 0; ks < 2; ++ks) {
      short8 pa0 = *(const short8*)&Ps[PSW2(wid, l15, ks * 32 + l4 * 8)];
      short8 pa1 = *(const short8*)&Ps[PSW2(wid, 16 + l15, ks * 32 + l4 * 8)];
#pragma unroll
      for (int nbd = 0; nbd < 8; ++nbd) {
        short8 vf = *(const short8*)&Vt[VTW(nbd * 16 + l15, ks * 32 + l4 * 8)];
        y[0][nbd] = __builtin_amdgcn_mfma_f32_16x16x32_bf16(pa0, vf, y[0][nbd], 0, 0, 0);
        y[1][nbd] = __builtin_amdgcn_mfma_f32_16x16x32_bf16(pa1, vf, y[1][nbd], 0, 0, 0);
      }
    }
    __builtin_amdgcn_s_setprio(0);
  }
#pragma unroll
  for (int rg = 0; rg < 2; ++rg) {
    float ls = lsum[rg];
    ls += __shfl_xor(ls, 16);
    ls += __shfl_xor(ls, 32);
    if (l4 == 0) part_l[(size_t)(half * 16 + bh) * Sn + qr0 + rg * 16 + l15] = ls;
    ushort* pybase = part_y + ((size_t)(half * 16 + bh) * Sn + qr0 + rg * 16) * 128;
#pragma unroll
    for (int nbd = 0; nbd < 8; ++nbd)
#pragma unroll
      for (int r = 0; r < 4; ++r)
        pybase[(size_t)(l4 * 4 + r) * 128 + nbd * 16 + l15] = f2bf(y[rg][nbd][r]);
  }
}

// ---- combine: attn = (y0+y1) / (l0+l1), bf16 ----
__global__ void combine_k(const ushort* __restrict__ part_y, const float* __restrict__ part_l,
                          ushort* __restrict__ attn_b) {
  int t = blockIdx.x * 256 + threadIdx.x;
  int row = t >> 4;
  size_t o0 = (size_t)row * 128 + (t & 15) * 8;
  float acc[8] = {};
#pragma unroll
  for (int hf = 0; hf < 2; ++hf) {
    union { short8 s8; ushort us[8]; } u;
    u.s8 = *(const short8*)&part_y[o0 + (size_t)hf * 4194304];
#pragma unroll
    for (int j = 0; j < 8; ++j) acc[j] += bf2f(u.us[j]);
  }
  float rcp = 1.f / (part_l[row] + part_l[row + 32768]);
  union { short8 s8; ushort us[8]; } o;
#pragma unroll
  for (int j = 0; j < 8; ++j) o.us[j] = f2bf(acc[j] * rcp);
  *(short8*)&attn_b[o0] = o.s8;
}

// ---- out = base + delta*rsqrt(sums/4096+eps)*g ; optional out-sumsq accumulate ----
template <bool SUMSQ>
__global__ void add_scale_k(const float* __restrict__ base, const float* __restrict__ delta,
                            const float* __restrict__ sums, const float* __restrict__ g,
                            float* __restrict__ out, float* __restrict__ ssq) {
  const int c = threadIdx.x;
  const float sc = rsqrtf(sums[c] * INV_BS + EPS) * g[c];
  const int r0 = blockIdx.x * 16;
  float sq = 0.f;
  for (int r = 0; r < 16; ++r) {
    size_t idx = (size_t)(r0 + r) * 768 + c;
    float v = base[idx] + delta[idx] * sc;
    out[idx] = v;
    if (SUMSQ) sq += v * v;
  }
  if (SUMSQ) atomicAdd(&ssq[c], sq);
}

}  // namespace

extern "C" void kernel_launch(void* const* d_in, const int* in_sizes, int n_in,
                              void* d_out, int out_size, void* d_ws, size_t ws_size,
                              hipStream_t stream) {
  const float* x       = (const float*)d_in[0];
  const float* pair_x  = (const float*)d_in[1];
  const float* ab_bn_g = (const float*)d_in[2];
  const float* ab_fc_w = (const float*)d_in[3];
  const float* bn1_g   = (const float*)d_in[4];
  const float* wq      = (const float*)d_in[5];
  const float* wk      = (const float*)d_in[6];
  const float* wv      = (const float*)d_in[7];
  const float* qn_g    = (const float*)d_in[8];
  const float* qn_b    = (const float*)d_in[9];
  const float* kn_g    = (const float*)d_in[10];
  const float* kn_b    = (const float*)d_in[11];
  const float* vn_g    = (const float*)d_in[12];
  const float* vn_b    = (const float*)d_in[13];
  const float* wo      = (const float*)d_in[14];
  const float* bo      = (const float*)d_in[15];
  const float* bn2_g   = (const float*)d_in[16];
  const float* mbn1_g  = (const float*)d_in[17];
  const float* w1      = (const float*)d_in[18];
  const float* b1      = (const float*)d_in[19];
  const float* w2      = (const float*)d_in[20];
  const float* b2      = (const float*)d_in[21];
  const float* mbn2_g  = (const float*)d_in[22];
  float* out = (float*)d_out;
  float* ws = (float*)d_ws;

  // ws layout (f32 units), liveness-verified
  float* ps    = ws + 0;
  float* xs    = ws + 256;
  float* es    = ws + 1024;
  float* x2s   = ws + 2048;
  float* fs    = ws + 3072;
  float* pb2   = ws + 4096;                   // 65,536
  ushort* wall_b = (ushort*)(ws + 69632);     // wq|wk|wv|wo|w1|w2 bf16 -> 2428928
  ushort* wo_b = (ushort*)(ws + 856064);
  ushort* w1_b = (ushort*)(ws + 1249280);
  ushort* w2_b = (ushort*)(ws + 1839104);
  ushort* xn_b = (ushort*)(ws + 2428928);     // 1,572,864 f (live thru qkv gemm)
  ushort* q_b  = (ushort*)(ws + 12390400);    // 2,097,152 f (dead after flash)
  ushort* k_b  = (ushort*)(ws + 14487552);    // 1,048,576 f (dead after flash)
  ushort* v_tt = (ushort*)(ws + 7671808);     // 1,048,576 f (written by qkv gemm, read by flash)
  float2* rtab = (float2*)(ws + 16584704);    // 262,144 f (cos/sin table)
  // overlays:
  ushort* part_y = (ushort*)(ws + 3477504);   // 4,194,304 f (2 x 4M shorts) — free region
  float* part_l = ws + 11866112;              // 65,536 f
  ushort* attn_b = (ushort*)(ws + 11997184);  // 2,097,152 f (post-flash; over dead region/q_b ok later)
  float* proj  = ws + 3477504;                // over dead part_y (post-combine)
  float* x2    = ws + 6623232;                // over dead part_y/v_tt (post-flash)
  ushort* x2n_b = (ushort*)(ws + 9768960);    // over free region
  ushort* hbuf_b = (ushort*)(ws + 3477504);   // over dead proj (post add_scale)
  float* proj2 = ws + 11341824;               // over dead attn_b/q_b tail

  (void)hipMemsetAsync(ws, 0, 4096 * sizeof(float), stream);

  // unified prep: weight casts | rope table | pair sumsq | x sumsq
  prep_k<<<3200, 256, 0, stream>>>(wq, wk, wv, wo, w1, w2, wall_b, rtab,
                                   pair_x, ps, x, xs);
  // pair bias + fused pair_x passthrough into the output tail
  pair_bias_k<<<1024, 256, 0, stream>>>(pair_x, ps, ab_bn_g, ab_fc_w, pb2, out + 3145728);
  scale_cast_k<<<1536, 256, 0, stream>>>(x, xs, bn1_g, xn_b);
  // fused QKV GEMM + LN + RoPE + V-transpose
  gemm_qkv_k<<<dim3(16, 32), 256, 0, stream>>>(xn_b, wall_b, 768,
                                               qn_g, qn_b, kn_g, kn_b, vn_g, vn_b,
                                               rtab, q_b, k_b, v_tt);
  flash_v14_k<<<dim3(16, 16, 2), 256, 0, stream>>>(q_b, k_b, v_tt, pb2, part_y, part_l);
  combine_k<<<2048, 256, 0, stream>>>(part_y, part_l, attn_b);
  gemm64_bf16_k<true><<<dim3(6, 64), 256, 0, stream>>>(attn_b, wo_b, proj, 4096, 768, 1024, bo, es);
  add_scale_k<true><<<256, 768, 0, stream>>>(x, proj, es, bn2_g, x2, x2s);
  scale_cast_k<<<1536, 256, 0, stream>>>(x2, x2s, mbn1_g, x2n_b);
  gemm_bf16_k<true, true><<<dim3(12, 32), 256, 0, stream>>>(x2n_b, w1_b, hbuf_b, 4096, 1536, 768, b1);
  gemm64_bf16_k<true><<<dim3(6, 64), 256, 0, stream>>>(hbuf_b, w2_b, proj2, 4096, 768, 1536, b2, fs);
  add_scale_k<false><<<256, 768, 0, stream>>>(x2, proj2, fs, mbn2_g, out, nullptr);
}

// Round 19
// 239.501 us; speedup vs baseline: 1.2318x; 1.0002x over previous
//
#include <hip/hip_runtime.h>
#include <math.h>

#define EPS 1e-5f

typedef __attribute__((ext_vector_type(8))) short short8;
typedef __attribute__((ext_vector_type(4))) float f32x4;

namespace {

constexpr int Bn = 2, Sn = 2048, Cn = 768;
constexpr float INV_BS = 1.0f / 4096.0f;     // B*S
constexpr float INV_PAIR = 1.0f / 32768.0f;  // B*SP*SP
constexpr float LOG2E = 1.4426950408889634f;

__device__ __forceinline__ ushort f2bf(float f) {
  uint u = __float_as_uint(f);
  u = (u + 0x7fffu + ((u >> 16) & 1u)) >> 16;
  return (ushort)u;
}
__device__ __forceinline__ float bf2f(ushort u) {
  return __uint_as_float(((uint)u) << 16);
}
__device__ __forceinline__ uint cvt_pk_bf16(float lo, float hi) {
  uint r;
  asm("v_cvt_pk_bf16_f32 %0, %1, %2" : "=v"(r) : "v"(lo), "v"(hi));
  return r;
}
// async global->LDS, 16B per lane; LDS dest is wave-uniform base (+lane*16 by HW)
__device__ __forceinline__ void gl16(const ushort* g, ushort* l) {
  __builtin_amdgcn_global_load_lds(
      (const __attribute__((address_space(1))) unsigned int*)(unsigned long long)(size_t)g,
      (__attribute__((address_space(3))) unsigned int*)(unsigned int)(size_t)l, 16, 0, 0);
}

// swizzled LDS index helpers (ushort units; XOR swaps 16B slots within a row)
#define KSW(r, c) ((((r) * 128) + (c)) ^ (((r) & 7) * 8))
#define VTW(d, t) ((((d) * 64) + (t)) ^ (((d) & 7) * 8))
#define PSW2(w, q, c) ((w) * 2048 + ((((q) * 64) + (c)) ^ (((q) & 7) * 8)))

// ---- unified prep: castall | rope_tab | pair_sumsq | ch_sumsq768(x), one launch ----
__global__ __launch_bounds__(256) void prep_k(
    const float* __restrict__ wq, const float* __restrict__ wk,
    const float* __restrict__ wv, const float* __restrict__ wo,
    const float* __restrict__ w1, const float* __restrict__ w2,
    ushort* __restrict__ wdst, float2* __restrict__ rtab,
    const float* __restrict__ pair, float* __restrict__ ps,
    const float* __restrict__ x, float* __restrict__ xs) {
  const int blk = blockIdx.x;
  const int tid = threadIdx.x;
  if (blk < 2304) {
    int u = blk * 256 + tid;
    const float* src; int local;
    if (u < 98304)       { src = wq; local = u; }
    else if (u < 147456) { src = wk; local = u - 98304; }
    else if (u < 196608) { src = wv; local = u - 147456; }
    else if (u < 294912) { src = wo; local = u - 196608; }
    else if (u < 442368) { src = w1; local = u - 294912; }
    else                 { src = w2; local = u - 442368; }
    int i = local * 8;
    float4 a = *(const float4*)&src[i];
    float4 b = *(const float4*)&src[i + 4];
    union { short8 s8; ushort us[8]; } o;
    o.us[0] = f2bf(a.x); o.us[1] = f2bf(a.y); o.us[2] = f2bf(a.z); o.us[3] = f2bf(a.w);
    o.us[4] = f2bf(b.x); o.us[5] = f2bf(b.y); o.us[6] = f2bf(b.z); o.us[7] = f2bf(b.w);
    *(short8*)&wdst[u * 8] = o.s8;
  } else if (blk < 2816) {
    int idx = (blk - 2304) * 256 + tid;
    int s = idx >> 6, i = idx & 63;
    const float kGeo = logf(1985.0f) * (1.0f / 63.0f);
    float inv = 1.0f / ((float)i + expf((float)i * kGeo));
    float th = (float)s * inv;
    rtab[idx] = make_float2(cosf(th), sinf(th));
  } else if (blk < 2944) {
    int c = tid & 127;
    int r0 = (blk - 2816) * 256 + (tid >> 7) * 128;
    float acc = 0.f;
    for (int r = 0; r < 128; ++r) {
      float v = pair[(size_t)(r0 + r) * 128 + c];
      acc += v * v;
    }
    atomicAdd(&ps[c], acc);
  } else {
    int r0 = (blk - 2944) * 16;
    float a0 = 0.f, a1 = 0.f, a2 = 0.f;
    for (int r = 0; r < 16; ++r) {
      const float* row = x + (size_t)(r0 + r) * 768;
      float v0 = row[tid], v1 = row[tid + 256], v2 = row[tid + 512];
      a0 += v0 * v0; a1 += v1 * v1; a2 += v2 * v2;
    }
    atomicAdd(&xs[tid], a0);
    atomicAdd(&xs[tid + 256], a1);
    atomicAdd(&xs[tid + 512], a2);
  }
}

// ---- rms_bn scale + bf16 cast ----
__global__ void scale_cast_k(const float* __restrict__ a, const float* __restrict__ sums,
                             const float* __restrict__ g, ushort* __restrict__ o) {
  int idx = blockIdx.x * 256 + threadIdx.x;
  int c0 = (idx % 96) * 8;
  int base = idx * 8;
  float4 v0 = *(const float4*)&a[base];
  float4 v1 = *(const float4*)&a[base + 4];
  union { short8 s8; ushort us[8]; } r;
  float vv[8] = {v0.x, v0.y, v0.z, v0.w, v1.x, v1.y, v1.z, v1.w};
#pragma unroll
  for (int j = 0; j < 8; ++j) {
    float sc = rsqrtf(sums[c0 + j] * INV_BS + EPS) * g[c0 + j];
    r.us[j] = f2bf(vv[j] * sc);
  }
  *(short8*)&o[base] = r.s8;
}

// ---- pair bias v2: coalesced float4, half-wave per row, fused pair_x passthrough ----
__global__ __launch_bounds__(256) void pair_bias_k(
    const float* __restrict__ p, const float* __restrict__ ps,
    const float* __restrict__ g, const float* __restrict__ w,
    float* __restrict__ pb2, float* __restrict__ pcopy) {
  const int tid = threadIdx.x;
  const int lane32 = tid & 31;
  const int sub = tid >> 5;
  const int c0 = lane32 * 4;
  float4 gv = *(const float4*)&g[c0];
  float4 psv = *(const float4*)&ps[c0];
  float4 w0 = *(const float4*)&w[c0];
  float4 w1v = *(const float4*)&w[128 + c0];
  float sc[4] = {rsqrtf(psv.x * INV_PAIR + EPS) * gv.x,
                 rsqrtf(psv.y * INV_PAIR + EPS) * gv.y,
                 rsqrtf(psv.z * INV_PAIR + EPS) * gv.z,
                 rsqrtf(psv.w * INV_PAIR + EPS) * gv.w};
  float wa[4] = {w0.x, w0.y, w0.z, w0.w};
  float wb[4] = {w1v.x, w1v.y, w1v.z, w1v.w};
#pragma unroll
  for (int it = 0; it < 4; ++it) {
    int row = blockIdx.x * 32 + it * 8 + sub;
    float4 v = *(const float4*)&p[(size_t)row * 128 + c0];
    *(float4*)&pcopy[(size_t)row * 128 + c0] = v;
    float vv[4] = {v.x, v.y, v.z, v.w};
    float a0 = 0.f, a1 = 0.f;
#pragma unroll
    for (int j = 0; j < 4; ++j) {
      float x = vv[j] * sc[j];
      float ge = 0.5f * x * (1.f + erff(x * 0.70710678118654752f));
      a0 += ge * wa[j];
      a1 += ge * wb[j];
    }
#pragma unroll
    for (int o = 1; o <= 16; o <<= 1) {
      a0 += __shfl_xor(a0, o);
      a1 += __shfl_xor(a1, o);
    }
    if (lane32 == 0) {
      pb2[(size_t)row * 2 + 0] = a0 * (0.4f * LOG2E);
      pb2[(size_t)row * 2 + 1] = a1 * (0.4f * LOG2E);
    }
  }
}

// ---- fused QKV GEMM + LayerNorm + RoPE + V-transpose epilogue ----
__global__ __launch_bounds__(256) void gemm_qkv_k(
    const ushort* __restrict__ A, const ushort* __restrict__ B, int K,
    const float* __restrict__ qn_g, const float* __restrict__ qn_b,
    const float* __restrict__ kn_g, const float* __restrict__ kn_b,
    const float* __restrict__ vn_g, const float* __restrict__ vn_b,
    const float2* __restrict__ rtab,
    ushort* __restrict__ q_b, ushort* __restrict__ k_b, ushort* __restrict__ v_tt) {
  __shared__ __align__(16) ushort As[128 * 64];
  __shared__ __align__(16) ushort Bs[128 * 64];
  __shared__ float2 redS[128][2];
  const int m0 = blockIdx.y * 128, n0 = blockIdx.x * 128;
  const int tid = threadIdx.x;
  const int lane = tid & 63;
  const int wid = tid >> 6;
  const int l15 = lane & 15, l4 = lane >> 4;
  const int wm = (wid >> 1) * 64, wn = (wid & 1) * 64;
  const ushort* asrc[4]; const ushort* bsrc[4];
  ushort* adst[4]; ushort* bdst[4];
#pragma unroll
  for (int u = 0; u < 4; ++u) {
    int ci = u * 256 + tid;
    int r = ci >> 3, s = ci & 7, g = s ^ (r & 7);
    asrc[u] = A + (size_t)(m0 + r) * K + g * 8;
    bsrc[u] = B + (size_t)(n0 + r) * K + g * 8;
    adst[u] = &As[(u * 256 + wid * 64) * 8];
    bdst[u] = &Bs[(u * 256 + wid * 64) * 8];
  }
  f32x4 acc[4][4];
#pragma unroll
  for (int i = 0; i < 4; ++i)
#pragma unroll
    for (int j = 0; j < 4; ++j) acc[i][j] = (f32x4){0.f, 0.f, 0.f, 0.f};
  for (int k0 = 0; k0 < K; k0 += 64) {
#pragma unroll
    for (int u = 0; u < 4; ++u) {
      gl16(asrc[u] + k0, adst[u]);
      gl16(bsrc[u] + k0, bdst[u]);
    }
    __syncthreads();
#pragma unroll
    for (int ks = 0; ks < 2; ++ks) {
      const int sw = ((ks * 4 + l4) ^ (l15 & 7)) * 8;
      short8 af[4], bf[4];
#pragma unroll
      for (int i = 0; i < 4; ++i) af[i] = *(const short8*)&As[(wm + i * 16 + l15) * 64 + sw];
#pragma unroll
      for (int j = 0; j < 4; ++j) bf[j] = *(const short8*)&Bs[(wn + j * 16 + l15) * 64 + sw];
#pragma unroll
      for (int i = 0; i < 4; ++i)
#pragma unroll
        for (int j = 0; j < 4; ++j)
          acc[i][j] = __builtin_amdgcn_mfma_f32_16x16x32_bf16(af[i], bf[j], acc[i][j], 0, 0, 0);
    }
    __syncthreads();
  }
  // ---- LN epilogue ----
  const int slot = blockIdx.x;
  const float* gvec; const float* bvec; int mode;
  if (slot < 8)       { gvec = qn_g; bvec = qn_b; mode = 0; }
  else if (slot < 12) { gvec = kn_g; bvec = kn_b; mode = 1; }
  else                { gvec = vn_g; bvec = vn_b; mode = 2; }
  float rsum[4][4], rsq[4][4];
#pragma unroll
  for (int i = 0; i < 4; ++i)
#pragma unroll
    for (int r = 0; r < 4; ++r) {
      float s1 = 0.f, s2 = 0.f;
#pragma unroll
      for (int j = 0; j < 4; ++j) {
        float a = acc[i][j][r];
        s1 += a; s2 += a * a;
      }
#pragma unroll
      for (int o = 1; o <= 8; o <<= 1) {
        s1 += __shfl_xor(s1, o);
        s2 += __shfl_xor(s2, o);
      }
      rsum[i][r] = s1; rsq[i][r] = s2;
    }
  if (l15 == 0) {
#pragma unroll
    for (int i = 0; i < 4; ++i)
#pragma unroll
      for (int r = 0; r < 4; ++r)
        redS[wm + i * 16 + l4 * 4 + r][wn >> 6] = make_float2(rsum[i][r], rsq[i][r]);
  }
  __syncthreads();
  float gv4[4], bv4[4];
#pragma unroll
  for (int j = 0; j < 4; ++j) {
    int c = wn + j * 16 + l15;
    gv4[j] = gvec[c]; bv4[j] = bvec[c];
  }
  const float QS = 0.035355339059327376f * LOG2E;
#pragma unroll
  for (int i = 0; i < 4; ++i) {
    float mean[4], rstd[4];
#pragma unroll
    for (int r = 0; r < 4; ++r) {
      int row = wm + i * 16 + l4 * 4 + r;
      float2 h0 = redS[row][0], h1 = redS[row][1];
      float m = (h0.x + h1.x) * (1.f / 128.f);
      float v = (h0.y + h1.y) * (1.f / 128.f) - m * m;
      mean[r] = m; rstd[r] = rsqrtf(v + EPS);
    }
    const int row0 = wm + i * 16 + l4 * 4;
    const int bs0 = m0 + row0;
    const int s0v = bs0 & (Sn - 1);
    const int bb = bs0 >> 11;
#pragma unroll
    for (int j = 0; j < 4; ++j) {
      int c = wn + j * 16 + l15;
      union { unsigned long long u64; ushort us[4]; } pk;
#pragma unroll
      for (int r = 0; r < 4; ++r) {
        float val = (acc[i][j][r] - mean[r]) * rstd[r] * gv4[j] + bv4[j];
        if (mode < 2) {
          float sx = __shfl_xor(val, 1);
          float rot = (c & 1) ? sx : -sx;
          float2 cssn = rtab[((s0v + r) << 6) | (c >> 1)];
          val = val * cssn.x + rot * cssn.y;
          if (mode == 0) {
            val *= QS;
            q_b[((size_t)(bb * 8 + slot) * Sn + s0v + r) * 128 + c] = f2bf(val);
          } else {
            k_b[((size_t)(bb * 4 + slot - 8) * Sn + s0v + r) * 128 + c] = f2bf(val);
          }
        } else {
          pk.us[r] = f2bf(val);
        }
      }
      if (mode == 2) {
        *(unsigned long long*)&v_tt[((size_t)(bb * 4 + slot - 12) * 128 + c) * Sn + s0v] = pk.u64;
      }
    }
  }
}

// ---- bf16 NT MFMA GEMM, 128x128 tile: gload_lds staging, linear LDS + XOR swizzle ----
template <bool RELU, bool OUT_BF16>
__global__ __launch_bounds__(256) void gemm_bf16_k(
    const ushort* __restrict__ A, const ushort* __restrict__ B,
    void* __restrict__ Cv, int M, int N, int K,
    const float* __restrict__ bias) {
  __shared__ __align__(16) ushort As[128 * 64];
  __shared__ __align__(16) ushort Bs[128 * 64];
  const int m0 = blockIdx.y * 128, n0 = blockIdx.x * 128;
  const int tid = threadIdx.x;
  const int lane = tid & 63;
  const int wid = tid >> 6;
  const int l15 = lane & 15, l4 = lane >> 4;
  const int wm = (wid >> 1) * 64, wn = (wid & 1) * 64;
  const ushort* asrc[4]; const ushort* bsrc[4];
  ushort* adst[4]; ushort* bdst[4];
#pragma unroll
  for (int u = 0; u < 4; ++u) {
    int ci = u * 256 + tid;
    int r = ci >> 3, s = ci & 7, g = s ^ (r & 7);
    asrc[u] = A + (size_t)(m0 + r) * K + g * 8;
    bsrc[u] = B + (size_t)(n0 + r) * K + g * 8;
    adst[u] = &As[(u * 256 + wid * 64) * 8];
    bdst[u] = &Bs[(u * 256 + wid * 64) * 8];
  }
  f32x4 acc[4][4];
#pragma unroll
  for (int i = 0; i < 4; ++i)
#pragma unroll
    for (int j = 0; j < 4; ++j) acc[i][j] = (f32x4){0.f, 0.f, 0.f, 0.f};
  for (int k0 = 0; k0 < K; k0 += 64) {
#pragma unroll
    for (int u = 0; u < 4; ++u) {
      gl16(asrc[u] + k0, adst[u]);
      gl16(bsrc[u] + k0, bdst[u]);
    }
    __syncthreads();
#pragma unroll
    for (int ks = 0; ks < 2; ++ks) {
      const int sw = ((ks * 4 + l4) ^ (l15 & 7)) * 8;
      short8 af[4], bf[4];
#pragma unroll
      for (int i = 0; i < 4; ++i) af[i] = *(const short8*)&As[(wm + i * 16 + l15) * 64 + sw];
#pragma unroll
      for (int j = 0; j < 4; ++j) bf[j] = *(const short8*)&Bs[(wn + j * 16 + l15) * 64 + sw];
#pragma unroll
      for (int i = 0; i < 4; ++i)
#pragma unroll
        for (int j = 0; j < 4; ++j)
          acc[i][j] = __builtin_amdgcn_mfma_f32_16x16x32_bf16(af[i], bf[j], acc[i][j], 0, 0, 0);
    }
    __syncthreads();
  }
  float* Cf = (float*)Cv;
  ushort* Cb = (ushort*)Cv;
#pragma unroll
  for (int j = 0; j < 4; ++j) {
    int col = n0 + wn + j * 16 + l15;
    float bv = bias ? bias[col] : 0.f;
#pragma unroll
    for (int i = 0; i < 4; ++i) {
      int row = m0 + wm + i * 16 + l4 * 4;
#pragma unroll
      for (int r = 0; r < 4; ++r) {
        float v = acc[i][j][r] + bv;
        if (RELU) v = fmaxf(v, 0.f);
        if (OUT_BF16) Cb[(size_t)(row + r) * N + col] = f2bf(v);
        else Cf[(size_t)(row + r) * N + col] = v;
      }
    }
  }
}

// ---- wo GEMM with FUSED split-KV combine on the A-path + column-sumsq ----
// A[m][k] = (part_y0[f] + part_y1[f]) / (l0+l1),  f = m*1024+k (flat [b,h,s,d])
__global__ __launch_bounds__(256) void gemm64c_k(
    const ushort* __restrict__ py, const float* __restrict__ pl,
    const ushort* __restrict__ B,
    float* __restrict__ Cf, int M, int N, int K,
    const float* __restrict__ bias, float* __restrict__ ssq) {
  __shared__ __align__(16) ushort As[64 * 64];
  __shared__ __align__(16) ushort Bs[128 * 64];
  const int m0 = blockIdx.y * 64, n0 = blockIdx.x * 128;
  const int tid = threadIdx.x;
  const int lane = tid & 63;
  const int wid = tid >> 6;
  const int l15 = lane & 15, l4 = lane >> 4;
  const int wn = wid * 32;
  size_t afl[2];
#pragma unroll
  for (int u = 0; u < 2; ++u) {
    int ci = u * 256 + tid;
    int r = ci >> 3, s = ci & 7, g = s ^ (r & 7);
    afl[u] = (size_t)(m0 + r) * K + g * 8;  // + k0 in loop
  }
  const ushort* bsrc[4]; ushort* bdst[4];
#pragma unroll
  for (int u = 0; u < 4; ++u) {
    int ci = u * 256 + tid;
    int r = ci >> 3, s = ci & 7, g = s ^ (r & 7);
    bsrc[u] = B + (size_t)(n0 + r) * K + g * 8;
    bdst[u] = &Bs[(u * 256 + wid * 64) * 8];
  }
  f32x4 acc[4][2];
#pragma unroll
  for (int i = 0; i < 4; ++i)
#pragma unroll
    for (int j = 0; j < 2; ++j) acc[i][j] = (f32x4){0.f, 0.f, 0.f, 0.f};
  for (int k0 = 0; k0 < K; k0 += 64) {
#pragma unroll
    for (int u = 0; u < 4; ++u) gl16(bsrc[u] + k0, bdst[u]);
#pragma unroll
    for (int u = 0; u < 2; ++u) {
      size_t f = afl[u] + k0;
      int lidx = (int)(f >> 7);
      float rl = 1.f / (pl[lidx] + pl[lidx + 32768]);
      union { short8 s8; ushort us[8]; } a0, a1, o;
      a0.s8 = *(const short8*)&py[f];
      a1.s8 = *(const short8*)&py[f + 4194304];
#pragma unroll
      for (int j = 0; j < 8; ++j)
        o.us[j] = f2bf((bf2f(a0.us[j]) + bf2f(a1.us[j])) * rl);
      *(short8*)&As[(u * 256 + tid) * 8] = o.s8;
    }
    __syncthreads();
#pragma unroll
    for (int ks = 0; ks < 2; ++ks) {
      const int sw = ((ks * 4 + l4) ^ (l15 & 7)) * 8;
      short8 af[4], bf[2];
#pragma unroll
      for (int i = 0; i < 4; ++i) af[i] = *(const short8*)&As[(i * 16 + l15) * 64 + sw];
#pragma unroll
      for (int j = 0; j < 2; ++j) bf[j] = *(const short8*)&Bs[(wn + j * 16 + l15) * 64 + sw];
#pragma unroll
      for (int i = 0; i < 4; ++i)
#pragma unroll
        for (int j = 0; j < 2; ++j)
          acc[i][j] = __builtin_amdgcn_mfma_f32_16x16x32_bf16(af[i], bf[j], acc[i][j], 0, 0, 0);
    }
    __syncthreads();
  }
#pragma unroll
  for (int j = 0; j < 2; ++j) {
    int col = n0 + wn + j * 16 + l15;
    float bv = bias ? bias[col] : 0.f;
    float sq = 0.f;
#pragma unroll
    for (int i = 0; i < 4; ++i) {
      int row = m0 + i * 16 + l4 * 4;
#pragma unroll
      for (int r = 0; r < 4; ++r) {
        float v = acc[i][j][r] + bv;
        sq += v * v;
        Cf[(size_t)(row + r) * N + col] = v;
      }
    }
    sq += __shfl_xor(sq, 16);
    sq += __shfl_xor(sq, 32);
    if (l4 == 0) atomicAdd(&ssq[col], sq);
  }
}

// ---- bf16 NT MFMA GEMM, 64x128 tile (w2); column-sumsq ----
__global__ __launch_bounds__(256) void gemm64_bf16_k(
    const ushort* __restrict__ A, const ushort* __restrict__ B,
    float* __restrict__ Cf, int M, int N, int K,
    const float* __restrict__ bias, float* __restrict__ ssq) {
  __shared__ __align__(16) ushort As[64 * 64];
  __shared__ __align__(16) ushort Bs[128 * 64];
  const int m0 = blockIdx.y * 64, n0 = blockIdx.x * 128;
  const int tid = threadIdx.x;
  const int lane = tid & 63;
  const int wid = tid >> 6;
  const int l15 = lane & 15, l4 = lane >> 4;
  const int wn = wid * 32;
  const ushort* asrc[2]; ushort* adst[2];
  const ushort* bsrc[4]; ushort* bdst[4];
#pragma unroll
  for (int u = 0; u < 2; ++u) {
    int ci = u * 256 + tid;
    int r = ci >> 3, s = ci & 7, g = s ^ (r & 7);
    asrc[u] = A + (size_t)(m0 + r) * K + g * 8;
    adst[u] = &As[(u * 256 + wid * 64) * 8];
  }
#pragma unroll
  for (int u = 0; u < 4; ++u) {
    int ci = u * 256 + tid;
    int r = ci >> 3, s = ci & 7, g = s ^ (r & 7);
    bsrc[u] = B + (size_t)(n0 + r) * K + g * 8;
    bdst[u] = &Bs[(u * 256 + wid * 64) * 8];
  }
  f32x4 acc[4][2];
#pragma unroll
  for (int i = 0; i < 4; ++i)
#pragma unroll
    for (int j = 0; j < 2; ++j) acc[i][j] = (f32x4){0.f, 0.f, 0.f, 0.f};
  for (int k0 = 0; k0 < K; k0 += 64) {
#pragma unroll
    for (int u = 0; u < 2; ++u) gl16(asrc[u] + k0, adst[u]);
#pragma unroll
    for (int u = 0; u < 4; ++u) gl16(bsrc[u] + k0, bdst[u]);
    __syncthreads();
#pragma unroll
    for (int ks = 0; ks < 2; ++ks) {
      const int sw = ((ks * 4 + l4) ^ (l15 & 7)) * 8;
      short8 af[4], bf[2];
#pragma unroll
      for (int i = 0; i < 4; ++i) af[i] = *(const short8*)&As[(i * 16 + l15) * 64 + sw];
#pragma unroll
      for (int j = 0; j < 2; ++j) bf[j] = *(const short8*)&Bs[(wn + j * 16 + l15) * 64 + sw];
#pragma unroll
      for (int i = 0; i < 4; ++i)
#pragma unroll
        for (int j = 0; j < 2; ++j)
          acc[i][j] = __builtin_amdgcn_mfma_f32_16x16x32_bf16(af[i], bf[j], acc[i][j], 0, 0, 0);
    }
    __syncthreads();
  }
#pragma unroll
  for (int j = 0; j < 2; ++j) {
    int col = n0 + wn + j * 16 + l15;
    float bv = bias ? bias[col] : 0.f;
    float sq = 0.f;
#pragma unroll
    for (int i = 0; i < 4; ++i) {
      int row = m0 + i * 16 + l4 * 4;
#pragma unroll
      for (int r = 0; r < 4; ++r) {
        float v = acc[i][j][r] + bv;
        sq += v * v;
        Cf[(size_t)(row + r) * N + col] = v;
      }
    }
    sq += __shfl_xor(sq, 16);
    sq += __shfl_xor(sq, 32);
    if (l4 == 0) atomicAdd(&ssq[col], sq);
  }
}

// ---- flash v14: 4 waves x 32 q-rows, split-KV(2) (512-block packed round) ----
__global__ __launch_bounds__(256, 2) void flash_v14_k(
    const ushort* __restrict__ qb, const ushort* __restrict__ kb,
    const ushort* __restrict__ vtt, const float* __restrict__ pb2,
    ushort* __restrict__ part_y, float* __restrict__ part_l) {
  __shared__ __align__(16) ushort Ks[64 * 128];
  __shared__ __align__(16) ushort Vt[128 * 64];
  __shared__ __align__(16) ushort Ps[4 * 32 * 64];
  const int s0 = blockIdx.x * 128;
  const int bh = blockIdx.y;
  const int half = blockIdx.z;
  const int b = bh >> 3, h = bh & 7;
  const int kv = h & 3, grp = h >> 2;
  const int tid = threadIdx.x;
  const int wid = tid >> 6, lane = tid & 63;
  const int l15 = lane & 15, l4 = lane >> 4;
  const ushort* kbase = kb + (size_t)(b * 4 + kv) * Sn * 128;
  const ushort* vbase = vtt + (size_t)(b * 4 + kv) * 128 * Sn;
  const int qr0 = s0 + wid * 32;
  short8 qf[2][4];
#pragma unroll
  for (int rg = 0; rg < 2; ++rg)
#pragma unroll
    for (int kc = 0; kc < 4; ++kc)
      qf[rg][kc] = *(const short8*)&qb[((size_t)bh * Sn + qr0 + rg * 16 + l15) * 128 + kc * 32 + l4 * 8];
  const ushort* ksrc[4]; const ushort* vsrc[4];
  ushort* kdst[4]; ushort* vdst[4];
#pragma unroll
  for (int u = 0; u < 4; ++u) {
    int ci = u * 256 + tid;
    int kr = ci >> 4, kg = (ci & 15) ^ (kr & 7);
    ksrc[u] = kbase + (size_t)kr * 128 + kg * 8;
    kdst[u] = &Ks[(u * 256 + wid * 64) * 8];
    int vd = ci >> 3, vg = (ci & 7) ^ (vd & 7);
    vsrc[u] = vbase + (size_t)vd * Sn + vg * 8;
    vdst[u] = &Vt[(u * 256 + wid * 64) * 8];
  }
  f32x4 y[2][8];
#pragma unroll
  for (int rg = 0; rg < 2; ++rg)
#pragma unroll
    for (int i = 0; i < 8; ++i) y[rg][i] = (f32x4){0.f, 0.f, 0.f, 0.f};
  float lsum[2] = {0.f, 0.f};
  const float C2 = -10.f * LOG2E;
  const int tbeg = half * 1024;
  for (int t0 = tbeg; t0 < tbeg + 1024; t0 += 64) {
    __syncthreads();
#pragma unroll
    for (int u = 0; u < 4; ++u) {
      gl16(ksrc[u] + (size_t)t0 * 128, kdst[u]);
      gl16(vsrc[u] + t0, vdst[u]);
    }
    __syncthreads();
    f32x4 acc[2][4];
#pragma unroll
    for (int rg = 0; rg < 2; ++rg)
#pragma unroll
      for (int nb = 0; nb < 4; ++nb) acc[rg][nb] = (f32x4){0.f, 0.f, 0.f, 0.f};
    __builtin_amdgcn_s_setprio(1);
#pragma unroll
    for (int kc = 0; kc < 4; ++kc)
#pragma unroll
      for (int nb = 0; nb < 4; ++nb) {
        short8 kf = *(const short8*)&Ks[KSW(nb * 16 + l15, kc * 32 + l4 * 8)];
        acc[0][nb] = __builtin_amdgcn_mfma_f32_16x16x32_bf16(kf, qf[0][kc], acc[0][nb], 0, 0, 0);
        acc[1][nb] = __builtin_amdgcn_mfma_f32_16x16x32_bf16(kf, qf[1][kc], acc[1][nb], 0, 0, 0);
      }
    __builtin_amdgcn_s_setprio(0);
#pragma unroll
    for (int rg = 0; rg < 2; ++rg)
#pragma unroll
      for (int nb = 0; nb < 4; ++nb) {
        float bias = pb2[(((size_t)b * 128 + (s0 >> 4) + wid * 2 + rg) * 128 + (t0 >> 4) + nb) * 2 + grp];
        float p[4];
#pragma unroll
        for (int r = 0; r < 4; ++r) {
          float e = exp2f(acc[rg][nb][r] + bias);
          p[r] = exp2f(C2 * __builtin_amdgcn_rcpf(e + 1.f));
        }
        lsum[rg] += (p[0] + p[1]) + (p[2] + p[3]);
        uint2 pk;
        pk.x = cvt_pk_bf16(p[0], p[1]);
        pk.y = cvt_pk_bf16(p[2], p[3]);
        *(uint2*)&Ps[PSW2(wid, rg * 16 + l15, nb * 16 + l4 * 4)] = pk;
      }
    __builtin_amdgcn_s_setprio(1);
#pragma unroll
    for (int ks = 0; ks < 2; ++ks) {
      short8 pa0 = *(const short8*)&Ps[PSW2(wid, l15, ks * 32 + l4 * 8)];
      short8 pa1 = *(const short8*)&Ps[PSW2(wid, 16 + l15, ks * 32 + l4 * 8)];
#pragma unroll
      for (int nbd = 0; nbd < 8; ++nbd) {
        short8 vf = *(const short8*)&Vt[VTW(nbd * 16 + l15, ks * 32 + l4 * 8)];
        y[0][nbd] = __builtin_amdgcn_mfma_f32_16x16x32_bf16(pa0, vf, y[0][nbd], 0, 0, 0);
        y[1][nbd] = __builtin_amdgcn_mfma_f32_16x16x32_bf16(pa1, vf, y[1][nbd], 0, 0, 0);
      }
    }
    __builtin_amdgcn_s_setprio(0);
  }
#pragma unroll
  for (int rg = 0; rg < 2; ++rg) {
    float ls = lsum[rg];
    ls += __shfl_xor(ls, 16);
    ls += __shfl_xor(ls, 32);
    if (l4 == 0) part_l[(size_t)(half * 16 + bh) * Sn + qr0 + rg * 16 + l15] = ls;
    ushort* pybase = part_y + ((size_t)(half * 16 + bh) * Sn + qr0 + rg * 16) * 128;
#pragma unroll
    for (int nbd = 0; nbd < 8; ++nbd)
#pragma unroll
      for (int r = 0; r < 4; ++r)
        pybase[(size_t)(l4 * 4 + r) * 128 + nbd * 16 + l15] = f2bf(y[rg][nbd][r]);
  }
}

// ---- out = base + delta*rsqrt(sums/4096+eps)*g ; optional out-sumsq accumulate ----
template <bool SUMSQ>
__global__ void add_scale_k(const float* __restrict__ base, const float* __restrict__ delta,
                            const float* __restrict__ sums, const float* __restrict__ g,
                            float* __restrict__ out, float* __restrict__ ssq) {
  const int c = threadIdx.x;
  const float sc = rsqrtf(sums[c] * INV_BS + EPS) * g[c];
  const int r0 = blockIdx.x * 16;
  float sq = 0.f;
  for (int r = 0; r < 16; ++r) {
    size_t idx = (size_t)(r0 + r) * 768 + c;
    float v = base[idx] + delta[idx] * sc;
    out[idx] = v;
    if (SUMSQ) sq += v * v;
  }
  if (SUMSQ) atomicAdd(&ssq[c], sq);
}

}  // namespace

extern "C" void kernel_launch(void* const* d_in, const int* in_sizes, int n_in,
                              void* d_out, int out_size, void* d_ws, size_t ws_size,
                              hipStream_t stream) {
  const float* x       = (const float*)d_in[0];
  const float* pair_x  = (const float*)d_in[1];
  const float* ab_bn_g = (const float*)d_in[2];
  const float* ab_fc_w = (const float*)d_in[3];
  const float* bn1_g   = (const float*)d_in[4];
  const float* wq      = (const float*)d_in[5];
  const float* wk      = (const float*)d_in[6];
  const float* wv      = (const float*)d_in[7];
  const float* qn_g    = (const float*)d_in[8];
  const float* qn_b    = (const float*)d_in[9];
  const float* kn_g    = (const float*)d_in[10];
  const float* kn_b    = (const float*)d_in[11];
  const float* vn_g    = (const float*)d_in[12];
  const float* vn_b    = (const float*)d_in[13];
  const float* wo      = (const float*)d_in[14];
  const float* bo      = (const float*)d_in[15];
  const float* bn2_g   = (const float*)d_in[16];
  const float* mbn1_g  = (const float*)d_in[17];
  const float* w1      = (const float*)d_in[18];
  const float* b1      = (const float*)d_in[19];
  const float* w2      = (const float*)d_in[20];
  const float* b2      = (const float*)d_in[21];
  const float* mbn2_g  = (const float*)d_in[22];
  float* out = (float*)d_out;
  float* ws = (float*)d_ws;

  // ws layout (f32 units), liveness-verified this round:
  //  part_y 3477504..7671808 (live until wo gemm done)
  //  part_l 11866112..11931648 (live until wo gemm done)
  //  proj   7671808..10817536 (written by wo gemm; dead part_y NOT overlapped)
  //  x2     3477504..6623232 (after wo gemm, part_y dead)
  //  x2n_b  6623232..8196096 (after add_scale; over dead proj head ok — proj read done)
  //  hbuf_b 8196096..11341824 (after w1 gemm reads x2n_b; over dead proj tail)
  //  proj2  11341824..14487552 (over dead part_l/q_b)
  float* ps    = ws + 0;
  float* xs    = ws + 256;
  float* es    = ws + 1024;
  float* x2s   = ws + 2048;
  float* fs    = ws + 3072;
  float* pb2   = ws + 4096;                   // 65,536
  ushort* wall_b = (ushort*)(ws + 69632);
  ushort* wo_b = (ushort*)(ws + 856064);
  ushort* w1_b = (ushort*)(ws + 1249280);
  ushort* w2_b = (ushort*)(ws + 1839104);
  ushort* xn_b = (ushort*)(ws + 2428928);     // 1,572,864 f (live thru qkv gemm)
  ushort* q_b  = (ushort*)(ws + 12390400);    // dead after flash
  ushort* k_b  = (ushort*)(ws + 14487552);    // dead after flash
  ushort* v_tt = (ushort*)(ws + 15536128);    // 1,048,576 f (qkv gemm -> flash)
  float2* rtab = (float2*)(ws + 16584704);    // 262,144 f
  ushort* part_y = (ushort*)(ws + 3477504);   // 4,194,304 f (2 halves)
  float* part_l = ws + 11866112;              // 65,536 f
  float* proj  = ws + 7671808;                // 3,145,728 f
  float* x2    = ws + 3477504;                // 3,145,728 f (over dead part_y)
  ushort* x2n_b = (ushort*)(ws + 6623232);    // 1,572,864 f (over dead part_y tail/proj head)
  ushort* hbuf_b = (ushort*)(ws + 8196096);   // 3,145,728 f (over dead proj tail)
  float* proj2 = ws + 11341824;               // 3,145,728 f (over dead part_l/q_b)

  (void)hipMemsetAsync(ws, 0, 4096 * sizeof(float), stream);

  // unified prep: weight casts | rope table | pair sumsq | x sumsq
  prep_k<<<3200, 256, 0, stream>>>(wq, wk, wv, wo, w1, w2, wall_b, rtab,
                                   pair_x, ps, x, xs);
  // pair bias + fused pair_x passthrough into the output tail
  pair_bias_k<<<1024, 256, 0, stream>>>(pair_x, ps, ab_bn_g, ab_fc_w, pb2, out + 3145728);
  scale_cast_k<<<1536, 256, 0, stream>>>(x, xs, bn1_g, xn_b);
  // fused QKV GEMM + LN + RoPE + V-transpose
  gemm_qkv_k<<<dim3(16, 32), 256, 0, stream>>>(xn_b, wall_b, 768,
                                               qn_g, qn_b, kn_g, kn_b, vn_g, vn_b,
                                               rtab, q_b, k_b, v_tt);
  flash_v14_k<<<dim3(16, 16, 2), 256, 0, stream>>>(q_b, k_b, v_tt, pb2, part_y, part_l);
  // wo GEMM with fused split-KV combine + es sumsq
  gemm64c_k<<<dim3(6, 64), 256, 0, stream>>>(part_y, part_l, wo_b, proj, 4096, 768, 1024, bo, es);
  add_scale_k<true><<<256, 768, 0, stream>>>(x, proj, es, bn2_g, x2, x2s);
  scale_cast_k<<<1536, 256, 0, stream>>>(x2, x2s, mbn1_g, x2n_b);
  gemm_bf16_k<true, true><<<dim3(12, 32), 256, 0, stream>>>(x2n_b, w1_b, hbuf_b, 4096, 1536, 768, b1);
  gemm64_bf16_k<<<dim3(6, 64), 256, 0, stream>>>(hbuf_b, w2_b, proj2, 4096, 768, 1536, b2, fs);
  add_scale_k<false><<<256, 768, 0, stream>>>(x2, proj2, fs, mbn2_g, out, nullptr);
}